// Round 1
// baseline (2912.109 us; speedup 1.0000x reference)
//
#include <hip/hip_runtime.h>
#include <hip/hip_bf16.h>

// Shapes (fixed): B=8,C=256,H=64,W=128,P=4,E=DM=128,N=512,DI=256,DS=16,DC=4,DR=8,NG=128,S=2
#define HW2 32768   // 128*256 output spatial per (b,channel)

__device__ __forceinline__ float siluf(float x){ return x / (1.f + __expf(-x)); }
__device__ __forceinline__ float geluf(float v){
  // tanh-approx gelu (jax.nn.gelu approximate=True)
  float t = 0.7978845608028654f * fmaf(0.044715f*v*v, v, v);
  t = fminf(fmaxf(t, -15.f), 15.f);
  float e = __expf(2.f*t);
  return 0.5f*v*(1.f + (e-1.f)/(e+1.f));
}

// ---------------- t init with patch bias ----------------
__global__ __launch_bounds__(256) void k_init_t(float* __restrict__ t, const float* __restrict__ pb){
  int i = blockIdx.x*256 + threadIdx.x;   // 524288 total
  t[i] = pb[i & 127];
}

// ---------------- patch-embed GEMM (im2col, split-K=4, atomic) ----------------
// t[m][e] += sum_k X(m,k)*pw[e][k];  m=(b,hp,wp), k=(c,i,j)
__global__ __launch_bounds__(256) void k_patch(const float* __restrict__ x, const float* __restrict__ pw,
                                               float* __restrict__ t){
  __shared__ __align__(16) float As[16][68];
  __shared__ __align__(16) float Bs[16][68];
  int m0 = blockIdx.x * 64;
  int n0 = blockIdx.y * 64;
  int kbase = blockIdx.z * 1024;
  int tid = threadIdx.x;
  int tm = tid >> 4, tn = tid & 15;
  int lm = tid >> 2, kq = tid & 3;
  float acc[4][4] = {};
  int m = m0 + lm;
  int bb = m >> 9;
  int l  = m & 511;
  int hp = l >> 5, wp = l & 31;
  const float* wbase = pw + (n0 + lm)*4096 + kq*4;
  for (int k0 = kbase; k0 < kbase + 1024; k0 += 16) {
    int k  = k0 + kq*4;
    int c  = k >> 4;
    int i2 = (k >> 2) & 3;
    float4 av = *reinterpret_cast<const float4*>(x + (((bb*256 + c)*64 + hp*4 + i2)*128 + wp*4));
    float4 bv = *reinterpret_cast<const float4*>(wbase + k0);
    As[kq*4+0][lm]=av.x; As[kq*4+1][lm]=av.y; As[kq*4+2][lm]=av.z; As[kq*4+3][lm]=av.w;
    Bs[kq*4+0][lm]=bv.x; Bs[kq*4+1][lm]=bv.y; Bs[kq*4+2][lm]=bv.z; Bs[kq*4+3][lm]=bv.w;
    __syncthreads();
    #pragma unroll
    for (int kk = 0; kk < 16; ++kk) {
      float4 a = *reinterpret_cast<const float4*>(&As[kk][tm*4]);
      float4 b = *reinterpret_cast<const float4*>(&Bs[kk][tn*4]);
      float ar[4] = {a.x,a.y,a.z,a.w};
      float br[4] = {b.x,b.y,b.z,b.w};
      #pragma unroll
      for (int i = 0; i < 4; ++i)
        #pragma unroll
        for (int j = 0; j < 4; ++j)
          acc[i][j] = fmaf(ar[i], br[j], acc[i][j]);
    }
    __syncthreads();
  }
  #pragma unroll
  for (int i = 0; i < 4; ++i)
    #pragma unroll
    for (int j = 0; j < 4; ++j)
      atomicAdd(&t[(m0 + tm*4 + i)*128 + (n0 + tn*4 + j)], acc[i][j]);
}

// ---------------- generic tiled GEMM: C(M,N) = A(M,K) @ W(N,K)^T ----------------
__global__ __launch_bounds__(256) void k_gemm(const float* __restrict__ A, const float* __restrict__ W,
                                              float* __restrict__ C, int M, int N, int K){
  __shared__ __align__(16) float As[16][68];
  __shared__ __align__(16) float Bs[16][68];
  int m0 = blockIdx.x * 64, n0 = blockIdx.y * 64;
  int tid = threadIdx.x;
  int tm = tid >> 4, tn = tid & 15;
  int lm = tid >> 2, kq = tid & 3;
  float acc[4][4] = {};
  const float* Abase = A + (size_t)(m0 + lm)*K + kq*4;
  const float* Wbase = W + (size_t)(n0 + lm)*K + kq*4;
  for (int k0 = 0; k0 < K; k0 += 16) {
    float4 av = *reinterpret_cast<const float4*>(Abase + k0);
    float4 bv = *reinterpret_cast<const float4*>(Wbase + k0);
    As[kq*4+0][lm]=av.x; As[kq*4+1][lm]=av.y; As[kq*4+2][lm]=av.z; As[kq*4+3][lm]=av.w;
    Bs[kq*4+0][lm]=bv.x; Bs[kq*4+1][lm]=bv.y; Bs[kq*4+2][lm]=bv.z; Bs[kq*4+3][lm]=bv.w;
    __syncthreads();
    #pragma unroll
    for (int kk = 0; kk < 16; ++kk) {
      float4 a = *reinterpret_cast<const float4*>(&As[kk][tm*4]);
      float4 b = *reinterpret_cast<const float4*>(&Bs[kk][tn*4]);
      float ar[4] = {a.x,a.y,a.z,a.w};
      float br[4] = {b.x,b.y,b.z,b.w};
      #pragma unroll
      for (int i = 0; i < 4; ++i)
        #pragma unroll
        for (int j = 0; j < 4; ++j)
          acc[i][j] = fmaf(ar[i], br[j], acc[i][j]);
    }
    __syncthreads();
  }
  #pragma unroll
  for (int i = 0; i < 4; ++i) {
    float4 ov = make_float4(acc[i][0], acc[i][1], acc[i][2], acc[i][3]);
    *reinterpret_cast<float4*>(C + (size_t)(m0 + tm*4 + i)*N + n0 + tn*4) = ov;
  }
}

// ---------------- causal conv1d (DC=4) + silu ----------------
__global__ __launch_bounds__(256) void k_conv1d(const float* __restrict__ xz, const float* __restrict__ w,
                                                const float* __restrict__ bias, float* __restrict__ xc){
  int idx = blockIdx.x*256 + threadIdx.x;   // over 8*512*256
  int d = idx & 255;
  int l = (idx >> 8) & 511;
  int bb = idx >> 17;
  const float* base = xz + (size_t)bb*512*512 + d;   // xin = xz[...,:256]
  float s = bias[d];
  #pragma unroll
  for (int k = 0; k < 4; ++k) {
    int ls = l - 3 + k;
    if (ls >= 0) s = fmaf(base[(size_t)ls*512], w[d*4+k], s);
  }
  xc[idx] = s / (1.f + __expf(-s));
}

// ---------------- x_proj (40 outs) + dt_proj + softplus ----------------
__global__ __launch_bounds__(256) void k_xproj(const float* __restrict__ xc, const float* __restrict__ xpw,
                                               const float* __restrict__ dtw, const float* __restrict__ dtb,
                                               float* __restrict__ dbl, float* __restrict__ dt){
  __shared__ __align__(16) float sxc[256];
  __shared__ float sdbl[40];
  int bl = blockIdx.x;         // (b,l) 0..4095
  int tid = threadIdx.x;
  sxc[tid] = xc[(size_t)bl*256 + tid];
  __syncthreads();
  if (tid < 40) {
    const float4* wr = reinterpret_cast<const float4*>(xpw + tid*256);
    const float4* xr = reinterpret_cast<const float4*>(sxc);
    float s = 0.f;
    #pragma unroll 8
    for (int i = 0; i < 64; ++i) {
      float4 w = wr[i], xv = xr[i];
      s += w.x*xv.x + w.y*xv.y + w.z*xv.z + w.w*xv.w;
    }
    sdbl[tid] = s;
    dbl[(size_t)bl*40 + tid] = s;
  }
  __syncthreads();
  float s = dtb[tid];
  const float* wr = dtw + tid*8;
  #pragma unroll
  for (int r = 0; r < 8; ++r) s = fmaf(sdbl[r], wr[r], s);
  float sp = (s > 20.f) ? s : log1pf(__expf(s));
  dt[(size_t)bl*256 + tid] = sp;
}

// ---------------- selective scan + D*xc + *silu(z) ----------------
__global__ __launch_bounds__(256) void k_scan(const float* __restrict__ dt, const float* __restrict__ dbl,
                                              const float* __restrict__ xc, const float* __restrict__ xz,
                                              const float* __restrict__ A_log, const float* __restrict__ Dp,
                                              float* __restrict__ y){
  int tid = threadIdx.x;
  int n = tid & 15, dloc = tid >> 4;
  int bb = blockIdx.x >> 4, dgrp = blockIdx.x & 15;
  int d = dgrp*16 + dloc;
  float Ac = -__expf(A_log[d*16 + n]);
  float Dv = Dp[d];
  float h = 0.f;
  for (int l = 0; l < 512; ++l) {
    int base = bb*512 + l;
    float dtv = dt[(size_t)base*256 + d];
    float xcv = xc[(size_t)base*256 + d];
    float Bv  = dbl[(size_t)base*40 + 8  + n];
    float Cv  = dbl[(size_t)base*40 + 24 + n];
    float dA = __expf(dtv*Ac);
    h = fmaf(dA, h, dtv*Bv*xcv);
    float yp = h*Cv;
    yp += __shfl_xor(yp, 1, 16);
    yp += __shfl_xor(yp, 2, 16);
    yp += __shfl_xor(yp, 4, 16);
    yp += __shfl_xor(yp, 8, 16);
    if (n == 0) {
      float zv = xz[(size_t)base*512 + 256 + d];
      y[(size_t)base*256 + d] = (yp + Dv*xcv) * (zv / (1.f + __expf(-zv)));
    }
  }
}

// ---------------- lin GEMM (1024 x 8192 x 512) + bias + pixel-shuffle scatter ----------------
__global__ __launch_bounds__(256) void k_lin(const float* __restrict__ yo, const float* __restrict__ lw,
                                             const float* __restrict__ lb, float* __restrict__ u){
  __shared__ __align__(16) float As[16][68];
  __shared__ __align__(16) float Bs[16][68];
  int r0 = blockIdx.x * 64;     // rows = (b,e)
  int n0 = blockIdx.y * 64;     // m
  int tid = threadIdx.x;
  int tm = tid >> 4, tn = tid & 15;
  int rl = tid & 63, ks = tid >> 6;
  int lm = tid >> 2, kq = tid & 3;
  float acc[4][4] = {};
  int arow = r0 + rl;
  int ab = arow >> 7, ae = arow & 127;
  const float* Wbase = lw + (size_t)(n0 + lm)*512 + kq*4;
  for (int k0 = 0; k0 < 512; k0 += 16) {
    #pragma unroll
    for (int s = 0; s < 4; ++s) {
      int kk = ks*4 + s;
      As[kk][rl] = yo[((size_t)ab*512 + k0 + kk)*128 + ae];
    }
    float4 bv = *reinterpret_cast<const float4*>(Wbase + k0);
    Bs[kq*4+0][lm]=bv.x; Bs[kq*4+1][lm]=bv.y; Bs[kq*4+2][lm]=bv.z; Bs[kq*4+3][lm]=bv.w;
    __syncthreads();
    #pragma unroll
    for (int kk = 0; kk < 16; ++kk) {
      float4 a = *reinterpret_cast<const float4*>(&As[kk][tm*4]);
      float4 b = *reinterpret_cast<const float4*>(&Bs[kk][tn*4]);
      float ar[4] = {a.x,a.y,a.z,a.w};
      float br[4] = {b.x,b.y,b.z,b.w};
      #pragma unroll
      for (int i = 0; i < 4; ++i)
        #pragma unroll
        for (int j = 0; j < 4; ++j)
          acc[i][j] = fmaf(ar[i], br[j], acc[i][j]);
    }
    __syncthreads();
  }
  #pragma unroll
  for (int i = 0; i < 4; ++i) {
    int rr = r0 + tm*4 + i;
    int bb = rr >> 7, e = rr & 127;
    int mm = n0 + tn*4;                    // m, m+1, m+2, m+3 share hp,wp,p1
    int p1 = (mm >> 2) & 3, wp = (mm >> 4) & 31, hp = mm >> 9;
    int hh = hp*4 + p1, wwp = wp*4;
    float4 ov = make_float4(acc[i][0]+lb[mm], acc[i][1]+lb[mm+1], acc[i][2]+lb[mm+2], acc[i][3]+lb[mm+3]);
    *reinterpret_cast<float4*>(u + (((size_t)bb*128 + e)*64 + hh)*128 + wwp) = ov;
  }
}

// ---------------- conv3x3 + bias + pixel-shuffle + gelu -> d_out ----------------
// block: h row, 128-o chunk, full width 128; thread tile 8o x 8w (split groups of 4, offset 64)
__global__ __launch_bounds__(256) void k_conv3(const float* __restrict__ u, const float* __restrict__ cw,
                                               const float* __restrict__ cb, float* __restrict__ out){
  extern __shared__ float sm[];
  float* wt = sm;                 // [144][132] : (el*9+k9)*132 + o
  float* ut = sm + 144*132;       // [48][132]  : (el*3+r)*132 + c, c in [0,130)
  int h  = blockIdx.x;            // 0..63
  int bz = blockIdx.y;            // b*4 + oc
  int bb = bz >> 2, oc = bz & 3;
  int o0 = oc * 128;
  int tid = threadIdx.x;
  int og = tid >> 4, wg = tid & 15;
  float acc[2][2][4][4] = {};     // [oh][wh][oi][wi]
  for (int e0 = 0; e0 < 128; e0 += 16) {
    __syncthreads();
    for (int idx = tid; idx < 128*144; idx += 256) {
      int o = idx / 144;
      int rem = idx - o*144;      // el*9 + k9
      wt[rem*132 + o] = cw[((size_t)(o0 + o)*128 + e0)*9 + rem];
    }
    for (int idx = tid; idx < 48*130; idx += 256) {
      int row = idx / 130;        // el*3 + r
      int c = idx - row*130;
      int el = row / 3, r = row - el*3;
      int hh = h - 1 + r;
      int ww = c - 1;
      float v = 0.f;
      if ((unsigned)hh < 64u && (unsigned)ww < 128u)
        v = u[(((size_t)bb*128 + e0 + el)*64 + hh)*128 + ww];
      ut[row*132 + c] = v;
    }
    __syncthreads();
    for (int el = 0; el < 16; ++el) {
      #pragma unroll
      for (int ki = 0; ki < 3; ++ki) {
        const float* urow = &ut[(el*3 + ki)*132];
        float uv[2][8];
        #pragma unroll
        for (int wh = 0; wh < 2; ++wh) {
          float4 u0 = *reinterpret_cast<const float4*>(&urow[wg*4 + wh*64]);
          float4 u1 = *reinterpret_cast<const float4*>(&urow[wg*4 + wh*64 + 4]);
          uv[wh][0]=u0.x; uv[wh][1]=u0.y; uv[wh][2]=u0.z; uv[wh][3]=u0.w;
          uv[wh][4]=u1.x; uv[wh][5]=u1.y; uv[wh][6]=u1.z; uv[wh][7]=u1.w;
        }
        #pragma unroll
        for (int kj = 0; kj < 3; ++kj) {
          const float* wrow = &wt[(el*9 + ki*3 + kj)*132];
          #pragma unroll
          for (int oh = 0; oh < 2; ++oh) {
            float4 wv = *reinterpret_cast<const float4*>(&wrow[og*4 + oh*64]);
            float wa[4] = {wv.x, wv.y, wv.z, wv.w};
            #pragma unroll
            for (int oi = 0; oi < 4; ++oi)
              #pragma unroll
              for (int wh = 0; wh < 2; ++wh)
                #pragma unroll
                for (int wi = 0; wi < 4; ++wi)
                  acc[oh][wh][oi][wi] = fmaf(wa[oi], uv[wh][wi + kj], acc[oh][wh][oi][wi]);
          }
        }
      }
    }
  }
  // epilogue: bias + gelu -> LDS, then coalesced shuffled store
  __syncthreads();
  float* smo = sm;                // [128][128] (o_local, w)
  #pragma unroll
  for (int oh = 0; oh < 2; ++oh)
    #pragma unroll
    for (int oi = 0; oi < 4; ++oi) {
      int o = og*4 + oh*64 + oi;
      float bias = cb[o0 + o];
      #pragma unroll
      for (int wh = 0; wh < 2; ++wh)
        #pragma unroll
        for (int wi = 0; wi < 4; ++wi) {
          int w = wg*4 + wh*64 + wi;
          smo[o*128 + w] = geluf(acc[oh][wh][oi][wi] + bias);
        }
    }
  __syncthreads();
  int gbase = o0 >> 2;
  for (int it = 0; it < 64; ++it) {
    int flat = tid + it*256;        // 0..16383
    int col2 = flat & 255;          // 2w+s2
    int rowsel = flat >> 8;         // g_local*2 + s1
    int gl = rowsel >> 1, s1 = rowsel & 1;
    int w = col2 >> 1, s2 = col2 & 1;
    float v = smo[(gl*4 + s1*2 + s2)*128 + w];
    out[(((size_t)bb*128 + gbase + gl)*128 + (2*h + s1))*256 + col2] = v;
  }
}

// ---------------- fused FFN: io = c + W2 @ gelu(W1 @ c + b1) + b2 (in-place on d_out) ----------------
__global__ __launch_bounds__(256) void k_ffn(const float* __restrict__ w1, const float* __restrict__ b1,
                                             const float* __restrict__ w2, const float* __restrict__ b2,
                                             float* __restrict__ io){
  extern __shared__ float sm[];
  float* smA = sm;                // [128][132]  c tile, then f1 tile
  float* smB = sm + 128*132;      // [128][132]  W1 then W2
  int pix0 = blockIdx.x * 128;
  int bb = pix0 >> 15;
  int hw0 = pix0 & 32767;
  int tid = threadIdx.x;
  int pg = tid & 15, jg = tid >> 4;
  for (int idx = tid; idx < 16384; idx += 256) {
    int ch = idx >> 7, p = idx & 127;
    smA[p*132 + ch] = io[((size_t)bb*128 + ch)*HW2 + hw0 + p];
  }
  for (int idx = tid; idx < 16384; idx += 256)
    smB[(idx >> 7)*132 + (idx & 127)] = w1[idx];
  __syncthreads();
  float acc[8][8];
  #pragma unroll
  for (int p = 0; p < 8; ++p)
    #pragma unroll
    for (int j = 0; j < 8; ++j) acc[p][j] = 0.f;
  for (int i = 0; i < 128; i += 4) {
    float4 cv[8], wv[8];
    #pragma unroll
    for (int p = 0; p < 8; ++p) cv[p] = *reinterpret_cast<const float4*>(&smA[(pg + p*16)*132 + i]);
    #pragma unroll
    for (int j = 0; j < 8; ++j) wv[j] = *reinterpret_cast<const float4*>(&smB[(jg + j*16)*132 + i]);
    #pragma unroll
    for (int p = 0; p < 8; ++p)
      #pragma unroll
      for (int j = 0; j < 8; ++j)
        acc[p][j] += cv[p].x*wv[j].x + cv[p].y*wv[j].y + cv[p].z*wv[j].z + cv[p].w*wv[j].w;
  }
  __syncthreads();
  // f1 = gelu(acc + b1) -> smA (c no longer needed; residual re-read from global); W2 -> smB
  #pragma unroll
  for (int j = 0; j < 8; ++j) {
    float bj = b1[jg + j*16];
    #pragma unroll
    for (int p = 0; p < 8; ++p)
      smA[(pg + p*16)*132 + (jg + j*16)] = geluf(acc[p][j] + bj);
  }
  for (int idx = tid; idx < 16384; idx += 256)
    smB[(idx >> 7)*132 + (idx & 127)] = w2[idx];
  __syncthreads();
  #pragma unroll
  for (int p = 0; p < 8; ++p)
    #pragma unroll
    for (int j = 0; j < 8; ++j) acc[p][j] = 0.f;
  for (int i = 0; i < 128; i += 4) {
    float4 cv[8], wv[8];
    #pragma unroll
    for (int p = 0; p < 8; ++p) cv[p] = *reinterpret_cast<const float4*>(&smA[(pg + p*16)*132 + i]);
    #pragma unroll
    for (int j = 0; j < 8; ++j) wv[j] = *reinterpret_cast<const float4*>(&smB[(jg + j*16)*132 + i]);
    #pragma unroll
    for (int p = 0; p < 8; ++p)
      #pragma unroll
      for (int j = 0; j < 8; ++j)
        acc[p][j] += cv[p].x*wv[j].x + cv[p].y*wv[j].y + cv[p].z*wv[j].z + cv[p].w*wv[j].w;
  }
  #pragma unroll
  for (int j = 0; j < 8; ++j) {
    int ch = jg + j*16;
    float bj = b2[ch];
    #pragma unroll
    for (int p = 0; p < 8; ++p) {
      size_t g = ((size_t)bb*128 + ch)*HW2 + hw0 + (pg + p*16);
      io[g] += acc[p][j] + bj;   // residual: io still holds gelu'd conv output c
    }
  }
}

extern "C" void kernel_launch(void* const* d_in, const int* in_sizes, int n_in,
                              void* d_out, int out_size, void* d_ws, size_t ws_size,
                              hipStream_t stream) {
  const float* x          = (const float*)d_in[0];
  const float* patch_w    = (const float*)d_in[1];
  const float* patch_b    = (const float*)d_in[2];
  const float* in_proj_w  = (const float*)d_in[3];
  const float* conv1d_w   = (const float*)d_in[4];
  const float* conv1d_b   = (const float*)d_in[5];
  const float* x_proj_w   = (const float*)d_in[6];
  const float* dt_proj_w  = (const float*)d_in[7];
  const float* dt_proj_b  = (const float*)d_in[8];
  const float* A_log      = (const float*)d_in[9];
  const float* D_param    = (const float*)d_in[10];
  const float* out_proj_w = (const float*)d_in[11];
  const float* lin_w      = (const float*)d_in[12];
  const float* lin_b      = (const float*)d_in[13];
  const float* conv_w     = (const float*)d_in[14];
  const float* conv_b     = (const float*)d_in[15];
  const float* ffn_w1     = (const float*)d_in[16];
  const float* ffn_b1     = (const float*)d_in[17];
  const float* ffn_w2     = (const float*)d_in[18];
  const float* ffn_b2     = (const float*)d_in[19];
  float* out = (float*)d_out;
  float* ws  = (float*)d_ws;

  float* t   = ws;                 // 524288   (B*N, E)
  float* xz  = t   + 524288;       // 2097152  (B*N, 512)
  float* xc  = xz  + 2097152;      // 1048576  (B*N, 256)
  float* dbl = xc  + 1048576;      // 163840   (B*N, 40)
  float* dt  = dbl + 163840;       // 1048576  (B*N, 256)
  float* y   = dt  + 1048576;      // 1048576  (B*N, 256)
  float* yo  = y   + 1048576;      // 524288   (B*N, 128)
  float* u   = yo  + 524288;       // 8388608  (B,128,64,128)

  k_init_t<<<dim3(2048), dim3(256), 0, stream>>>(t, patch_b);
  k_patch <<<dim3(64, 2, 4), dim3(256), 0, stream>>>(x, patch_w, t);
  k_gemm  <<<dim3(64, 8), dim3(256), 0, stream>>>(t, in_proj_w, xz, 4096, 512, 128);
  k_conv1d<<<dim3(4096), dim3(256), 0, stream>>>(xz, conv1d_w, conv1d_b, xc);
  k_xproj <<<dim3(4096), dim3(256), 0, stream>>>(xc, x_proj_w, dt_proj_w, dt_proj_b, dbl, dt);
  k_scan  <<<dim3(128), dim3(256), 0, stream>>>(dt, dbl, xc, xz, A_log, D_param, y);
  k_gemm  <<<dim3(64, 2), dim3(256), 0, stream>>>(y, out_proj_w, yo, 4096, 128, 256);
  k_lin   <<<dim3(16, 128), dim3(256), 0, stream>>>(yo, lin_w, lin_b, u);
  k_conv3 <<<dim3(64, 32), dim3(256), (size_t)(192*132)*sizeof(float), stream>>>(u, conv_w, conv_b, out);
  k_ffn   <<<dim3(2048), dim3(256), (size_t)(2*128*132)*sizeof(float), stream>>>(ffn_w1, ffn_b1, ffn_w2, ffn_b2, out);
}

// Round 2
// 1201.318 us; speedup vs baseline: 2.4241x; 2.4241x over previous
//
#include <hip/hip_runtime.h>
#include <hip/hip_bf16.h>

// Shapes (fixed): B=8,C=256,H=64,W=128,P=4,E=DM=128,N=512,DI=256,DS=16,DC=4,DR=8,NG=128,S=2
#define HW2 32768   // 128*256 output spatial per (b,channel)

typedef __attribute__((ext_vector_type(8))) short short8v;
typedef __attribute__((ext_vector_type(4))) float f32x4;

__device__ __forceinline__ float siluf(float x){ return x / (1.f + __expf(-x)); }
__device__ __forceinline__ float geluf(float v){
  // tanh-approx gelu (jax.nn.gelu approximate=True)
  float t = 0.7978845608028654f * fmaf(0.044715f*v*v, v, v);
  t = fminf(fmaxf(t, -15.f), 15.f);
  float e = __expf(2.f*t);
  return 0.5f*v*(1.f + (e-1.f)/(e+1.f));
}
__device__ __forceinline__ ushort bf16rne(float f){
  unsigned u = __float_as_uint(f);
  unsigned r = (u + 0x7fffu + ((u >> 16) & 1u)) >> 16;
  return (ushort)r;
}

// ---------------- zero-fill (uint4 granularity) ----------------
__global__ __launch_bounds__(256) void k_zero4(uint4* __restrict__ p, int n){
  int i = blockIdx.x*256 + threadIdx.x;
  if (i < n) p[i] = make_uint4(0,0,0,0);
}

// ---------------- conv weights fp32 -> bf16, layout [oc4][ec4][tap9][o128][e32] ----------------
__global__ __launch_bounds__(256) void k_wprep(const float* __restrict__ cw, ushort* __restrict__ wbf){
  int idx = blockIdx.x*256 + threadIdx.x;   // 589824
  int e   = idx & 31;
  int o   = (idx >> 5) & 127;
  int t9  = (idx >> 12) % 9;
  int ece = idx / (4096*9);                 // oc*4+ec
  int oc  = ece >> 2, ec = ece & 3;
  float v = cw[(((size_t)oc*128 + o)*128 + ec*32 + e)*9 + t9];
  wbf[idx] = bf16rne(v);
}

// ---------------- t init with patch bias ----------------
__global__ __launch_bounds__(256) void k_init_t(float* __restrict__ t, const float* __restrict__ pb){
  int i = blockIdx.x*256 + threadIdx.x;   // 524288 total
  t[i] = pb[i & 127];
}

// ---------------- patch-embed GEMM (im2col, split-K=4, atomic) ----------------
__global__ __launch_bounds__(256) void k_patch(const float* __restrict__ x, const float* __restrict__ pw,
                                               float* __restrict__ t){
  __shared__ __align__(16) float As[16][68];
  __shared__ __align__(16) float Bs[16][68];
  int m0 = blockIdx.x * 64;
  int n0 = blockIdx.y * 64;
  int kbase = blockIdx.z * 1024;
  int tid = threadIdx.x;
  int tm = tid >> 4, tn = tid & 15;
  int lm = tid >> 2, kq = tid & 3;
  float acc[4][4] = {};
  int m = m0 + lm;
  int bb = m >> 9;
  int l  = m & 511;
  int hp = l >> 5, wp = l & 31;
  const float* wbase = pw + (n0 + lm)*4096 + kq*4;
  for (int k0 = kbase; k0 < kbase + 1024; k0 += 16) {
    int k  = k0 + kq*4;
    int c  = k >> 4;
    int i2 = (k >> 2) & 3;
    float4 av = *reinterpret_cast<const float4*>(x + (((bb*256 + c)*64 + hp*4 + i2)*128 + wp*4));
    float4 bv = *reinterpret_cast<const float4*>(wbase + k0);
    As[kq*4+0][lm]=av.x; As[kq*4+1][lm]=av.y; As[kq*4+2][lm]=av.z; As[kq*4+3][lm]=av.w;
    Bs[kq*4+0][lm]=bv.x; Bs[kq*4+1][lm]=bv.y; Bs[kq*4+2][lm]=bv.z; Bs[kq*4+3][lm]=bv.w;
    __syncthreads();
    #pragma unroll
    for (int kk = 0; kk < 16; ++kk) {
      float4 a = *reinterpret_cast<const float4*>(&As[kk][tm*4]);
      float4 b = *reinterpret_cast<const float4*>(&Bs[kk][tn*4]);
      float ar[4] = {a.x,a.y,a.z,a.w};
      float br[4] = {b.x,b.y,b.z,b.w};
      #pragma unroll
      for (int i = 0; i < 4; ++i)
        #pragma unroll
        for (int j = 0; j < 4; ++j)
          acc[i][j] = fmaf(ar[i], br[j], acc[i][j]);
    }
    __syncthreads();
  }
  #pragma unroll
  for (int i = 0; i < 4; ++i)
    #pragma unroll
    for (int j = 0; j < 4; ++j)
      atomicAdd(&t[(m0 + tm*4 + i)*128 + (n0 + tn*4 + j)], acc[i][j]);
}

// ---------------- generic tiled GEMM: C(M,N) = A(M,K) @ W(N,K)^T ----------------
__global__ __launch_bounds__(256) void k_gemm(const float* __restrict__ A, const float* __restrict__ W,
                                              float* __restrict__ C, int M, int N, int K){
  __shared__ __align__(16) float As[16][68];
  __shared__ __align__(16) float Bs[16][68];
  int m0 = blockIdx.x * 64, n0 = blockIdx.y * 64;
  int tid = threadIdx.x;
  int tm = tid >> 4, tn = tid & 15;
  int lm = tid >> 2, kq = tid & 3;
  float acc[4][4] = {};
  const float* Abase = A + (size_t)(m0 + lm)*K + kq*4;
  const float* Wbase = W + (size_t)(n0 + lm)*K + kq*4;
  for (int k0 = 0; k0 < K; k0 += 16) {
    float4 av = *reinterpret_cast<const float4*>(Abase + k0);
    float4 bv = *reinterpret_cast<const float4*>(Wbase + k0);
    As[kq*4+0][lm]=av.x; As[kq*4+1][lm]=av.y; As[kq*4+2][lm]=av.z; As[kq*4+3][lm]=av.w;
    Bs[kq*4+0][lm]=bv.x; Bs[kq*4+1][lm]=bv.y; Bs[kq*4+2][lm]=bv.z; Bs[kq*4+3][lm]=bv.w;
    __syncthreads();
    #pragma unroll
    for (int kk = 0; kk < 16; ++kk) {
      float4 a = *reinterpret_cast<const float4*>(&As[kk][tm*4]);
      float4 b = *reinterpret_cast<const float4*>(&Bs[kk][tn*4]);
      float ar[4] = {a.x,a.y,a.z,a.w};
      float br[4] = {b.x,b.y,b.z,b.w};
      #pragma unroll
      for (int i = 0; i < 4; ++i)
        #pragma unroll
        for (int j = 0; j < 4; ++j)
          acc[i][j] = fmaf(ar[i], br[j], acc[i][j]);
    }
    __syncthreads();
  }
  #pragma unroll
  for (int i = 0; i < 4; ++i) {
    float4 ov = make_float4(acc[i][0], acc[i][1], acc[i][2], acc[i][3]);
    *reinterpret_cast<float4*>(C + (size_t)(m0 + tm*4 + i)*N + n0 + tn*4) = ov;
  }
}

// ---------------- causal conv1d (DC=4) + silu ----------------
__global__ __launch_bounds__(256) void k_conv1d(const float* __restrict__ xz, const float* __restrict__ w,
                                                const float* __restrict__ bias, float* __restrict__ xc){
  int idx = blockIdx.x*256 + threadIdx.x;   // over 8*512*256
  int d = idx & 255;
  int l = (idx >> 8) & 511;
  int bb = idx >> 17;
  const float* base = xz + (size_t)bb*512*512 + d;   // xin = xz[...,:256]
  float s = bias[d];
  #pragma unroll
  for (int k = 0; k < 4; ++k) {
    int ls = l - 3 + k;
    if (ls >= 0) s = fmaf(base[(size_t)ls*512], w[d*4+k], s);
  }
  xc[idx] = s / (1.f + __expf(-s));
}

// ---------------- x_proj (40 outs) + dt_proj + softplus ----------------
__global__ __launch_bounds__(256) void k_xproj(const float* __restrict__ xc, const float* __restrict__ xpw,
                                               const float* __restrict__ dtw, const float* __restrict__ dtb,
                                               float* __restrict__ dbl, float* __restrict__ dt){
  __shared__ __align__(16) float sxc[256];
  __shared__ float sdbl[40];
  int bl = blockIdx.x;         // (b,l) 0..4095
  int tid = threadIdx.x;
  sxc[tid] = xc[(size_t)bl*256 + tid];
  __syncthreads();
  if (tid < 40) {
    const float4* wr = reinterpret_cast<const float4*>(xpw + tid*256);
    const float4* xr = reinterpret_cast<const float4*>(sxc);
    float s = 0.f;
    #pragma unroll 8
    for (int i = 0; i < 64; ++i) {
      float4 w = wr[i], xv = xr[i];
      s += w.x*xv.x + w.y*xv.y + w.z*xv.z + w.w*xv.w;
    }
    sdbl[tid] = s;
    dbl[(size_t)bl*40 + tid] = s;
  }
  __syncthreads();
  float s = dtb[tid];
  const float* wr = dtw + tid*8;
  #pragma unroll
  for (int r = 0; r < 8; ++r) s = fmaf(sdbl[r], wr[r], s);
  float sp = (s > 20.f) ? s : log1pf(__expf(s));
  dt[(size_t)bl*256 + tid] = sp;
}

// ---------------- selective scan + D*xc + *silu(z) ----------------
__global__ __launch_bounds__(256) void k_scan(const float* __restrict__ dt, const float* __restrict__ dbl,
                                              const float* __restrict__ xc, const float* __restrict__ xz,
                                              const float* __restrict__ A_log, const float* __restrict__ Dp,
                                              float* __restrict__ y){
  int tid = threadIdx.x;
  int n = tid & 15, dloc = tid >> 4;
  int bb = blockIdx.x >> 4, dgrp = blockIdx.x & 15;
  int d = dgrp*16 + dloc;
  float Ac = -__expf(A_log[d*16 + n]);
  float Dv = Dp[d];
  float h = 0.f;
  for (int l = 0; l < 512; ++l) {
    int base = bb*512 + l;
    float dtv = dt[(size_t)base*256 + d];
    float xcv = xc[(size_t)base*256 + d];
    float Bv  = dbl[(size_t)base*40 + 8  + n];
    float Cv  = dbl[(size_t)base*40 + 24 + n];
    float dA = __expf(dtv*Ac);
    h = fmaf(dA, h, dtv*Bv*xcv);
    float yp = h*Cv;
    yp += __shfl_xor(yp, 1, 16);
    yp += __shfl_xor(yp, 2, 16);
    yp += __shfl_xor(yp, 4, 16);
    yp += __shfl_xor(yp, 8, 16);
    if (n == 0) {
      float zv = xz[(size_t)base*512 + 256 + d];
      y[(size_t)base*256 + d] = (yp + Dv*xcv) * (zv / (1.f + __expf(-zv)));
    }
  }
}

// ---------------- lin GEMM (1024 x 8192 x 512) + bias + pixel-shuffle -> padded bf16 ubf ----------------
// ubf layout: [b][ec=4][h'=66][w'=130][e%32] bf16, borders (h'=0,65; w'=0,129) pre-zeroed.
__global__ __launch_bounds__(256) void k_lin(const float* __restrict__ yo, const float* __restrict__ lw,
                                             const float* __restrict__ lb, ushort* __restrict__ ubf){
  __shared__ __align__(16) float As[16][68];
  __shared__ __align__(16) float Bs[16][68];
  int r0 = blockIdx.x * 64;     // rows = (b,e)
  int n0 = blockIdx.y * 64;     // m
  int tid = threadIdx.x;
  int tm = tid >> 4, tn = tid & 15;
  int rl = tid & 63, ks = tid >> 6;
  int lm = tid >> 2, kq = tid & 3;
  float acc[4][4] = {};
  int arow = r0 + rl;
  int ab = arow >> 7, ae = arow & 127;
  const float* Wbase = lw + (size_t)(n0 + lm)*512 + kq*4;
  for (int k0 = 0; k0 < 512; k0 += 16) {
    #pragma unroll
    for (int s = 0; s < 4; ++s) {
      int kk = ks*4 + s;
      As[kk][rl] = yo[((size_t)ab*512 + k0 + kk)*128 + ae];
    }
    float4 bv = *reinterpret_cast<const float4*>(Wbase + k0);
    Bs[kq*4+0][lm]=bv.x; Bs[kq*4+1][lm]=bv.y; Bs[kq*4+2][lm]=bv.z; Bs[kq*4+3][lm]=bv.w;
    __syncthreads();
    #pragma unroll
    for (int kk = 0; kk < 16; ++kk) {
      float4 a = *reinterpret_cast<const float4*>(&As[kk][tm*4]);
      float4 b = *reinterpret_cast<const float4*>(&Bs[kk][tn*4]);
      float ar[4] = {a.x,a.y,a.z,a.w};
      float br[4] = {b.x,b.y,b.z,b.w};
      #pragma unroll
      for (int i = 0; i < 4; ++i)
        #pragma unroll
        for (int j = 0; j < 4; ++j)
          acc[i][j] = fmaf(ar[i], br[j], acc[i][j]);
    }
    __syncthreads();
  }
  #pragma unroll
  for (int i = 0; i < 4; ++i) {
    int rr = r0 + tm*4 + i;
    int bb = rr >> 7, e = rr & 127;
    int mm = n0 + tn*4;                    // m..m+3 share hp,wp,p1
    int p1 = (mm >> 2) & 3, wp = (mm >> 4) & 31, hp = mm >> 9;
    int hh = hp*4 + p1, wwp = wp*4;
    size_t base = ((((size_t)bb*4 + (e>>5))*66 + (hh+1))*130 + (wwp+1))*32 + (e&31);
    #pragma unroll
    for (int j = 0; j < 4; ++j)
      ubf[base + (size_t)j*32] = bf16rne(acc[i][j] + lb[mm+j]);
  }
}

// ---------------- conv3x3 via bf16 MFMA implicit GEMM + bias + pixel-shuffle + gelu -> d_out ----------------
// grid (h2=32, bz=32: b*4+oc). 512 thr = 8 waves: wave = (wo: o-half, wsp: hr*2 + wseg-half).
__global__ __launch_bounds__(512) void k_conv3m(const ushort* __restrict__ ubf, const ushort* __restrict__ wbf,
                                                const float* __restrict__ cb, float* __restrict__ out){
  extern __shared__ ushort smu[];
  ushort* ubuf = smu;           // [4 rows][130 w'][32 e] stride 4160
  ushort* wlds = smu + 16640;   // [9 tap][128 o][32 e]
  int h2 = blockIdx.x;          // 0..31 (pair of output rows pre-shuffle)
  int bz = blockIdx.y;
  int bb = bz >> 2, oc = bz & 3;
  int tid = threadIdx.x;
  int l   = tid & 63;
  int wv  = tid >> 6;
  int wo  = wv & 1;             // o half (64)
  int wsp = wv >> 1;
  int hr  = wsp >> 1;           // row within pair
  int wseg = (wsp & 1) * 64;    // w half
  int lj = l & 15, lg = l >> 4;

  f32x4 acc[4][4];
  #pragma unroll
  for (int i = 0; i < 4; ++i)
    #pragma unroll
    for (int j = 0; j < 4; ++j)
      acc[i][j] = (f32x4){0.f, 0.f, 0.f, 0.f};

  for (int ec = 0; ec < 4; ++ec) {
    __syncthreads();
    // stage weights: contiguous 36864 bf16 (4608 uint4)
    const uint4* sA = reinterpret_cast<const uint4*>(wbf) + (size_t)(oc*4 + ec)*4608;
    uint4* dA = reinterpret_cast<uint4*>(wlds);
    for (int i = tid; i < 4608; i += 512) dA[i] = sA[i];
    // stage input rows h' = 2*h2 .. 2*h2+3: contiguous 16640 bf16 (2080 uint4)
    const uint4* sB = reinterpret_cast<const uint4*>(ubf) + ((size_t)(bb*4 + ec)*66 + 2*h2)*520;
    uint4* dB = reinterpret_cast<uint4*>(ubuf);
    for (int i = tid; i < 2080; i += 512) dB[i] = sB[i];
    __syncthreads();

    #pragma unroll
    for (int ki = 0; ki < 3; ++ki) {
      const ushort* brow = ubuf + (hr + ki)*4160 + lg*8;
      #pragma unroll
      for (int kj = 0; kj < 3; ++kj) {
        const ushort* wrow = wlds + (ki*3 + kj)*4096 + (wo*64 + lj)*32 + lg*8;
        short8v af[4], bfr[4];
        #pragma unroll
        for (int f = 0; f < 4; ++f)
          af[f] = *reinterpret_cast<const short8v*>(wrow + f*512);
        #pragma unroll
        for (int f = 0; f < 4; ++f)
          bfr[f] = *reinterpret_cast<const short8v*>(brow + (wseg + f*16 + lj + kj)*32);
        #pragma unroll
        for (int fo = 0; fo < 4; ++fo)
          #pragma unroll
          for (int fj = 0; fj < 4; ++fj)
            acc[fo][fj] = __builtin_amdgcn_mfma_f32_16x16x32_bf16(af[fo], bfr[fj], acc[fo][fj], 0, 0, 0);
      }
    }
  }

  // epilogue: bias + gelu + pixel-shuffle (o -> g,s1,s2), coalesced float2 stores
  int row = h2*2 + hr;              // pre-shuffle output row, 0..63
  #pragma unroll
  for (int fo = 0; fo < 4; ++fo) {
    int obase = oc*128 + wo*64 + fo*16 + lg*4;   // + q
    int g = obase >> 2;
    float b0 = cb[obase], b1 = cb[obase+1], b2 = cb[obase+2], b3 = cb[obase+3];
    size_t rbase0 = (((size_t)bb*128 + g)*128 + 2*row)*256;
    size_t rbase1 = rbase0 + 256;
    #pragma unroll
    for (int fj = 0; fj < 4; ++fj) {
      int w = wseg + fj*16 + lj;
      f32x4 a = acc[fo][fj];
      float2 v0 = make_float2(geluf(a.x + b0), geluf(a.y + b1));
      float2 v1 = make_float2(geluf(a.z + b2), geluf(a.w + b3));
      *reinterpret_cast<float2*>(out + rbase0 + 2*w) = v0;
      *reinterpret_cast<float2*>(out + rbase1 + 2*w) = v1;
    }
  }
}

// ---------------- fused FFN: io = c + W2 @ gelu(W1 @ c + b1) + b2 (in-place on d_out) ----------------
__global__ __launch_bounds__(256) void k_ffn(const float* __restrict__ w1, const float* __restrict__ b1,
                                             const float* __restrict__ w2, const float* __restrict__ b2,
                                             float* __restrict__ io){
  extern __shared__ float sm[];
  float* smA = sm;                // [128][132]  c tile, then f1 tile
  float* smB = sm + 128*132;      // [128][132]  W1 then W2
  int pix0 = blockIdx.x * 128;
  int bb = pix0 >> 15;
  int hw0 = pix0 & 32767;
  int tid = threadIdx.x;
  int pg = tid & 15, jg = tid >> 4;
  for (int idx = tid; idx < 16384; idx += 256) {
    int ch = idx >> 7, p = idx & 127;
    smA[p*132 + ch] = io[((size_t)bb*128 + ch)*HW2 + hw0 + p];
  }
  for (int idx = tid; idx < 16384; idx += 256)
    smB[(idx >> 7)*132 + (idx & 127)] = w1[idx];
  __syncthreads();
  float acc[8][8];
  #pragma unroll
  for (int p = 0; p < 8; ++p)
    #pragma unroll
    for (int j = 0; j < 8; ++j) acc[p][j] = 0.f;
  for (int i = 0; i < 128; i += 4) {
    float4 cv[8], wv[8];
    #pragma unroll
    for (int p = 0; p < 8; ++p) cv[p] = *reinterpret_cast<const float4*>(&smA[(pg + p*16)*132 + i]);
    #pragma unroll
    for (int j = 0; j < 8; ++j) wv[j] = *reinterpret_cast<const float4*>(&smB[(jg + j*16)*132 + i]);
    #pragma unroll
    for (int p = 0; p < 8; ++p)
      #pragma unroll
      for (int j = 0; j < 8; ++j)
        acc[p][j] += cv[p].x*wv[j].x + cv[p].y*wv[j].y + cv[p].z*wv[j].z + cv[p].w*wv[j].w;
  }
  __syncthreads();
  #pragma unroll
  for (int j = 0; j < 8; ++j) {
    float bj = b1[jg + j*16];
    #pragma unroll
    for (int p = 0; p < 8; ++p)
      smA[(pg + p*16)*132 + (jg + j*16)] = geluf(acc[p][j] + bj);
  }
  for (int idx = tid; idx < 16384; idx += 256)
    smB[(idx >> 7)*132 + (idx & 127)] = w2[idx];
  __syncthreads();
  #pragma unroll
  for (int p = 0; p < 8; ++p)
    #pragma unroll
    for (int j = 0; j < 8; ++j) acc[p][j] = 0.f;
  for (int i = 0; i < 128; i += 4) {
    float4 cv[8], wv[8];
    #pragma unroll
    for (int p = 0; p < 8; ++p) cv[p] = *reinterpret_cast<const float4*>(&smA[(pg + p*16)*132 + i]);
    #pragma unroll
    for (int j = 0; j < 8; ++j) wv[j] = *reinterpret_cast<const float4*>(&smB[(jg + j*16)*132 + i]);
    #pragma unroll
    for (int p = 0; p < 8; ++p)
      #pragma unroll
      for (int j = 0; j < 8; ++j)
        acc[p][j] += cv[p].x*wv[j].x + cv[p].y*wv[j].y + cv[p].z*wv[j].z + cv[p].w*wv[j].w;
  }
  #pragma unroll
  for (int j = 0; j < 8; ++j) {
    int ch = jg + j*16;
    float bj = b2[ch];
    #pragma unroll
    for (int p = 0; p < 8; ++p) {
      size_t g = ((size_t)bb*128 + ch)*HW2 + hw0 + (pg + p*16);
      io[g] += acc[p][j] + bj;   // residual: io still holds gelu'd conv output c
    }
  }
}

extern "C" void kernel_launch(void* const* d_in, const int* in_sizes, int n_in,
                              void* d_out, int out_size, void* d_ws, size_t ws_size,
                              hipStream_t stream) {
  const float* x          = (const float*)d_in[0];
  const float* patch_w    = (const float*)d_in[1];
  const float* patch_b    = (const float*)d_in[2];
  const float* in_proj_w  = (const float*)d_in[3];
  const float* conv1d_w   = (const float*)d_in[4];
  const float* conv1d_b   = (const float*)d_in[5];
  const float* x_proj_w   = (const float*)d_in[6];
  const float* dt_proj_w  = (const float*)d_in[7];
  const float* dt_proj_b  = (const float*)d_in[8];
  const float* A_log      = (const float*)d_in[9];
  const float* D_param    = (const float*)d_in[10];
  const float* out_proj_w = (const float*)d_in[11];
  const float* lin_w      = (const float*)d_in[12];
  const float* lin_b      = (const float*)d_in[13];
  const float* conv_w     = (const float*)d_in[14];
  const float* conv_b     = (const float*)d_in[15];
  const float* ffn_w1     = (const float*)d_in[16];
  const float* ffn_b1     = (const float*)d_in[17];
  const float* ffn_w2     = (const float*)d_in[18];
  const float* ffn_b2     = (const float*)d_in[19];
  float* out = (float*)d_out;
  float* ws  = (float*)d_ws;

  float* t   = ws;                 // 524288   (B*N, E)
  float* xz  = t   + 524288;       // 2097152  (B*N, 512)
  float* xc  = xz  + 2097152;      // 1048576  (B*N, 256)
  float* dbl = xc  + 1048576;      // 163840   (B*N, 40)
  float* dt  = dbl + 163840;       // 1048576  (B*N, 256)
  float* y   = dt  + 1048576;      // 1048576  (B*N, 256)
  float* yo  = y   + 1048576;      // 524288   (B*N, 128)
  ushort* ubf = (ushort*)(yo + 524288);   // 10982400 bf16: [8][4][66][130][32]
  ushort* wbf = ubf + 10982400;           // 589824 bf16:   [4][4][9][128][32]

  k_zero4 <<<dim3(5363), dim3(256), 0, stream>>>((uint4*)ubf, 1372800);
  k_wprep <<<dim3(2304), dim3(256), 0, stream>>>(conv_w, wbf);
  k_init_t<<<dim3(2048), dim3(256), 0, stream>>>(t, patch_b);
  k_patch <<<dim3(64, 2, 4), dim3(256), 0, stream>>>(x, patch_w, t);
  k_gemm  <<<dim3(64, 8), dim3(256), 0, stream>>>(t, in_proj_w, xz, 4096, 512, 128);
  k_conv1d<<<dim3(4096), dim3(256), 0, stream>>>(xz, conv1d_w, conv1d_b, xc);
  k_xproj <<<dim3(4096), dim3(256), 0, stream>>>(xc, x_proj_w, dt_proj_w, dt_proj_b, dbl, dt);
  k_scan  <<<dim3(128), dim3(256), 0, stream>>>(dt, dbl, xc, xz, A_log, D_param, y);
  k_gemm  <<<dim3(64, 2), dim3(256), 0, stream>>>(y, out_proj_w, yo, 4096, 128, 256);
  k_lin   <<<dim3(16, 128), dim3(256), 0, stream>>>(yo, lin_w, lin_b, ubf);
  k_conv3m<<<dim3(32, 32), dim3(512), (size_t)53504*sizeof(ushort), stream>>>(ubf, wbf, conv_b, out);
  k_ffn   <<<dim3(2048), dim3(256), (size_t)(2*128*132)*sizeof(float), stream>>>(ffn_w1, ffn_b1, ffn_w2, ffn_b2, out);
}

// Round 3
// 873.202 us; speedup vs baseline: 3.3350x; 1.3758x over previous
//
#include <hip/hip_runtime.h>
#include <hip/hip_bf16.h>

// Shapes (fixed): B=8,C=256,H=64,W=128,P=4,E=DM=128,N=512,DI=256,DS=16,DC=4,DR=8,NG=128,S=2
#define HW2 32768   // 128*256 output spatial per (b,channel)

typedef __attribute__((ext_vector_type(8))) short short8v;
typedef __attribute__((ext_vector_type(4))) float f32x4;

__device__ __forceinline__ float siluf(float x){ return x / (1.f + __expf(-x)); }
__device__ __forceinline__ float geluf(float v){
  // tanh-approx gelu (jax.nn.gelu approximate=True)
  float t = 0.7978845608028654f * fmaf(0.044715f*v*v, v, v);
  t = fminf(fmaxf(t, -15.f), 15.f);
  float e = __expf(2.f*t);
  return 0.5f*v*(1.f + (e-1.f)/(e+1.f));
}
__device__ __forceinline__ ushort bf16rne(float f){
  unsigned u = __float_as_uint(f);
  unsigned r = (u + 0x7fffu + ((u >> 16) & 1u)) >> 16;
  return (ushort)r;
}

// ---------------- zero-fill (uint4 granularity) ----------------
__global__ __launch_bounds__(256) void k_zero4(uint4* __restrict__ p, int n){
  int i = blockIdx.x*256 + threadIdx.x;
  if (i < n) p[i] = make_uint4(0,0,0,0);
}

// ---------------- conv weights fp32 -> bf16, layout [oc4][ec4][tap9][o128][e32] ----------------
__global__ __launch_bounds__(256) void k_wprep(const float* __restrict__ cw, ushort* __restrict__ wbf){
  int idx = blockIdx.x*256 + threadIdx.x;   // 589824
  int e   = idx & 31;
  int o   = (idx >> 5) & 127;
  int t9  = (idx >> 12) % 9;
  int ece = idx / (4096*9);                 // oc*4+ec
  int oc  = ece >> 2, ec = ece & 3;
  float v = cw[(((size_t)oc*128 + o)*128 + ec*32 + e)*9 + t9];
  wbf[idx] = bf16rne(v);
}

// ---------------- FFN weights fp32 -> bf16 padded [2][128][136] ----------------
__global__ __launch_bounds__(256) void k_wffn(const float* __restrict__ w1, const float* __restrict__ w2,
                                              ushort* __restrict__ wpad){
  int idx = blockIdx.x*256 + threadIdx.x;   // 34816
  int which = idx / 17408;
  int rem = idx - which*17408;
  int e = rem / 136, k = rem - e*136;
  const float* s = which ? w2 : w1;
  wpad[idx] = (k < 128) ? bf16rne(s[e*128 + k]) : (ushort)0;
}

// ---------------- t init with patch bias ----------------
__global__ __launch_bounds__(256) void k_init_t(float* __restrict__ t, const float* __restrict__ pb){
  int i = blockIdx.x*256 + threadIdx.x;   // 524288 total
  t[i] = pb[i & 127];
}

// ---------------- patch-embed GEMM (im2col, split-K=4, atomic) ----------------
__global__ __launch_bounds__(256) void k_patch(const float* __restrict__ x, const float* __restrict__ pw,
                                               float* __restrict__ t){
  __shared__ __align__(16) float As[16][68];
  __shared__ __align__(16) float Bs[16][68];
  int m0 = blockIdx.x * 64;
  int n0 = blockIdx.y * 64;
  int kbase = blockIdx.z * 1024;
  int tid = threadIdx.x;
  int tm = tid >> 4, tn = tid & 15;
  int lm = tid >> 2, kq = tid & 3;
  float acc[4][4] = {};
  int m = m0 + lm;
  int bb = m >> 9;
  int l  = m & 511;
  int hp = l >> 5, wp = l & 31;
  const float* wbase = pw + (n0 + lm)*4096 + kq*4;
  for (int k0 = kbase; k0 < kbase + 1024; k0 += 16) {
    int k  = k0 + kq*4;
    int c  = k >> 4;
    int i2 = (k >> 2) & 3;
    float4 av = *reinterpret_cast<const float4*>(x + (((bb*256 + c)*64 + hp*4 + i2)*128 + wp*4));
    float4 bv = *reinterpret_cast<const float4*>(wbase + k0);
    As[kq*4+0][lm]=av.x; As[kq*4+1][lm]=av.y; As[kq*4+2][lm]=av.z; As[kq*4+3][lm]=av.w;
    Bs[kq*4+0][lm]=bv.x; Bs[kq*4+1][lm]=bv.y; Bs[kq*4+2][lm]=bv.z; Bs[kq*4+3][lm]=bv.w;
    __syncthreads();
    #pragma unroll
    for (int kk = 0; kk < 16; ++kk) {
      float4 a = *reinterpret_cast<const float4*>(&As[kk][tm*4]);
      float4 b = *reinterpret_cast<const float4*>(&Bs[kk][tn*4]);
      float ar[4] = {a.x,a.y,a.z,a.w};
      float br[4] = {b.x,b.y,b.z,b.w};
      #pragma unroll
      for (int i = 0; i < 4; ++i)
        #pragma unroll
        for (int j = 0; j < 4; ++j)
          acc[i][j] = fmaf(ar[i], br[j], acc[i][j]);
    }
    __syncthreads();
  }
  #pragma unroll
  for (int i = 0; i < 4; ++i)
    #pragma unroll
    for (int j = 0; j < 4; ++j)
      atomicAdd(&t[(m0 + tm*4 + i)*128 + (n0 + tn*4 + j)], acc[i][j]);
}

// ---------------- generic tiled GEMM: C(M,N) = A(M,K) @ W(N,K)^T ----------------
__global__ __launch_bounds__(256) void k_gemm(const float* __restrict__ A, const float* __restrict__ W,
                                              float* __restrict__ C, int M, int N, int K){
  __shared__ __align__(16) float As[16][68];
  __shared__ __align__(16) float Bs[16][68];
  int m0 = blockIdx.x * 64, n0 = blockIdx.y * 64;
  int tid = threadIdx.x;
  int tm = tid >> 4, tn = tid & 15;
  int lm = tid >> 2, kq = tid & 3;
  float acc[4][4] = {};
  const float* Abase = A + (size_t)(m0 + lm)*K + kq*4;
  const float* Wbase = W + (size_t)(n0 + lm)*K + kq*4;
  for (int k0 = 0; k0 < K; k0 += 16) {
    float4 av = *reinterpret_cast<const float4*>(Abase + k0);
    float4 bv = *reinterpret_cast<const float4*>(Wbase + k0);
    As[kq*4+0][lm]=av.x; As[kq*4+1][lm]=av.y; As[kq*4+2][lm]=av.z; As[kq*4+3][lm]=av.w;
    Bs[kq*4+0][lm]=bv.x; Bs[kq*4+1][lm]=bv.y; Bs[kq*4+2][lm]=bv.z; Bs[kq*4+3][lm]=bv.w;
    __syncthreads();
    #pragma unroll
    for (int kk = 0; kk < 16; ++kk) {
      float4 a = *reinterpret_cast<const float4*>(&As[kk][tm*4]);
      float4 b = *reinterpret_cast<const float4*>(&Bs[kk][tn*4]);
      float ar[4] = {a.x,a.y,a.z,a.w};
      float br[4] = {b.x,b.y,b.z,b.w};
      #pragma unroll
      for (int i = 0; i < 4; ++i)
        #pragma unroll
        for (int j = 0; j < 4; ++j)
          acc[i][j] = fmaf(ar[i], br[j], acc[i][j]);
    }
    __syncthreads();
  }
  #pragma unroll
  for (int i = 0; i < 4; ++i) {
    float4 ov = make_float4(acc[i][0], acc[i][1], acc[i][2], acc[i][3]);
    *reinterpret_cast<float4*>(C + (size_t)(m0 + tm*4 + i)*N + n0 + tn*4) = ov;
  }
}

// ---------------- causal conv1d (DC=4) + silu ----------------
__global__ __launch_bounds__(256) void k_conv1d(const float* __restrict__ xz, const float* __restrict__ w,
                                                const float* __restrict__ bias, float* __restrict__ xc){
  int idx = blockIdx.x*256 + threadIdx.x;   // over 8*512*256
  int d = idx & 255;
  int l = (idx >> 8) & 511;
  int bb = idx >> 17;
  const float* base = xz + (size_t)bb*512*512 + d;   // xin = xz[...,:256]
  float s = bias[d];
  #pragma unroll
  for (int k = 0; k < 4; ++k) {
    int ls = l - 3 + k;
    if (ls >= 0) s = fmaf(base[(size_t)ls*512], w[d*4+k], s);
  }
  xc[idx] = s / (1.f + __expf(-s));
}

// ---------------- x_proj (40 outs) + dt_proj + softplus ----------------
__global__ __launch_bounds__(256) void k_xproj(const float* __restrict__ xc, const float* __restrict__ xpw,
                                               const float* __restrict__ dtw, const float* __restrict__ dtb,
                                               float* __restrict__ dbl, float* __restrict__ dt){
  __shared__ __align__(16) float sxc[256];
  __shared__ float sdbl[40];
  int bl = blockIdx.x;         // (b,l) 0..4095
  int tid = threadIdx.x;
  sxc[tid] = xc[(size_t)bl*256 + tid];
  __syncthreads();
  if (tid < 40) {
    const float4* wr = reinterpret_cast<const float4*>(xpw + tid*256);
    const float4* xr = reinterpret_cast<const float4*>(sxc);
    float s = 0.f;
    #pragma unroll 8
    for (int i = 0; i < 64; ++i) {
      float4 w = wr[i], xv = xr[i];
      s += w.x*xv.x + w.y*xv.y + w.z*xv.z + w.w*xv.w;
    }
    sdbl[tid] = s;
    dbl[(size_t)bl*40 + tid] = s;
  }
  __syncthreads();
  float s = dtb[tid];
  const float* wr = dtw + tid*8;
  #pragma unroll
  for (int r = 0; r < 8; ++r) s = fmaf(sdbl[r], wr[r], s);
  float sp = (s > 20.f) ? s : log1pf(__expf(s));
  dt[(size_t)bl*256 + tid] = sp;
}

// ---------------- selective scan + D*xc + *silu(z) ----------------
__global__ __launch_bounds__(256) void k_scan(const float* __restrict__ dt, const float* __restrict__ dbl,
                                              const float* __restrict__ xc, const float* __restrict__ xz,
                                              const float* __restrict__ A_log, const float* __restrict__ Dp,
                                              float* __restrict__ y){
  int tid = threadIdx.x;
  int n = tid & 15, dloc = tid >> 4;
  int bb = blockIdx.x >> 4, dgrp = blockIdx.x & 15;
  int d = dgrp*16 + dloc;
  float Ac = -__expf(A_log[d*16 + n]);
  float Dv = Dp[d];
  float h = 0.f;
  for (int l = 0; l < 512; ++l) {
    int base = bb*512 + l;
    float dtv = dt[(size_t)base*256 + d];
    float xcv = xc[(size_t)base*256 + d];
    float Bv  = dbl[(size_t)base*40 + 8  + n];
    float Cv  = dbl[(size_t)base*40 + 24 + n];
    float dA = __expf(dtv*Ac);
    h = fmaf(dA, h, dtv*Bv*xcv);
    float yp = h*Cv;
    yp += __shfl_xor(yp, 1, 16);
    yp += __shfl_xor(yp, 2, 16);
    yp += __shfl_xor(yp, 4, 16);
    yp += __shfl_xor(yp, 8, 16);
    if (n == 0) {
      float zv = xz[(size_t)base*512 + 256 + d];
      y[(size_t)base*256 + d] = (yp + Dv*xcv) * (zv / (1.f + __expf(-zv)));
    }
  }
}

// ---------------- lin GEMM (1024 x 8192 x 512) + bias + pixel-shuffle -> padded bf16 ubf ----------------
// ubf layout: [b][ec=4][h'=66][w'=130][e%32] bf16, borders (h'=0,65; w'=0,129) pre-zeroed.
__global__ __launch_bounds__(256) void k_lin(const float* __restrict__ yo, const float* __restrict__ lw,
                                             const float* __restrict__ lb, ushort* __restrict__ ubf){
  __shared__ __align__(16) float As[16][68];
  __shared__ __align__(16) float Bs[16][68];
  int r0 = blockIdx.x * 64;     // rows = (b,e)
  int n0 = blockIdx.y * 64;     // m
  int tid = threadIdx.x;
  int tm = tid >> 4, tn = tid & 15;
  int rl = tid & 63, ks = tid >> 6;
  int lm = tid >> 2, kq = tid & 3;
  float acc[4][4] = {};
  int arow = r0 + rl;
  int ab = arow >> 7, ae = arow & 127;
  const float* Wbase = lw + (size_t)(n0 + lm)*512 + kq*4;
  for (int k0 = 0; k0 < 512; k0 += 16) {
    #pragma unroll
    for (int s = 0; s < 4; ++s) {
      int kk = ks*4 + s;
      As[kk][rl] = yo[((size_t)ab*512 + k0 + kk)*128 + ae];
    }
    float4 bv = *reinterpret_cast<const float4*>(Wbase + k0);
    Bs[kq*4+0][lm]=bv.x; Bs[kq*4+1][lm]=bv.y; Bs[kq*4+2][lm]=bv.z; Bs[kq*4+3][lm]=bv.w;
    __syncthreads();
    #pragma unroll
    for (int kk = 0; kk < 16; ++kk) {
      float4 a = *reinterpret_cast<const float4*>(&As[kk][tm*4]);
      float4 b = *reinterpret_cast<const float4*>(&Bs[kk][tn*4]);
      float ar[4] = {a.x,a.y,a.z,a.w};
      float br[4] = {b.x,b.y,b.z,b.w};
      #pragma unroll
      for (int i = 0; i < 4; ++i)
        #pragma unroll
        for (int j = 0; j < 4; ++j)
          acc[i][j] = fmaf(ar[i], br[j], acc[i][j]);
    }
    __syncthreads();
  }
  #pragma unroll
  for (int i = 0; i < 4; ++i) {
    int rr = r0 + tm*4 + i;
    int bb = rr >> 7, e = rr & 127;
    int mm = n0 + tn*4;                    // m..m+3 share hp,wp,p1
    int p1 = (mm >> 2) & 3, wp = (mm >> 4) & 31, hp = mm >> 9;
    int hh = hp*4 + p1, wwp = wp*4;
    size_t base = ((((size_t)bb*4 + (e>>5))*66 + (hh+1))*130 + (wwp+1))*32 + (e&31);
    #pragma unroll
    for (int j = 0; j < 4; ++j)
      ubf[base + (size_t)j*32] = bf16rne(acc[i][j] + lb[mm+j]);
  }
}

// ---------------- conv3x3 via bf16 MFMA implicit GEMM + bias + pixel-shuffle + gelu -> d_out ----------------
__global__ __launch_bounds__(512) void k_conv3m(const ushort* __restrict__ ubf, const ushort* __restrict__ wbf,
                                                const float* __restrict__ cb, float* __restrict__ out){
  extern __shared__ ushort smu[];
  ushort* ubuf = smu;           // [4 rows][130 w'][32 e] stride 4160
  ushort* wlds = smu + 16640;   // [9 tap][128 o][32 e]
  int h2 = blockIdx.x;          // 0..31 (pair of output rows pre-shuffle)
  int bz = blockIdx.y;
  int bb = bz >> 2, oc = bz & 3;
  int tid = threadIdx.x;
  int l   = tid & 63;
  int wv  = tid >> 6;
  int wo  = wv & 1;             // o half (64)
  int wsp = wv >> 1;
  int hr  = wsp >> 1;           // row within pair
  int wseg = (wsp & 1) * 64;    // w half
  int lj = l & 15, lg = l >> 4;

  f32x4 acc[4][4];
  #pragma unroll
  for (int i = 0; i < 4; ++i)
    #pragma unroll
    for (int j = 0; j < 4; ++j)
      acc[i][j] = (f32x4){0.f, 0.f, 0.f, 0.f};

  for (int ec = 0; ec < 4; ++ec) {
    __syncthreads();
    const uint4* sA = reinterpret_cast<const uint4*>(wbf) + (size_t)(oc*4 + ec)*4608;
    uint4* dA = reinterpret_cast<uint4*>(wlds);
    for (int i = tid; i < 4608; i += 512) dA[i] = sA[i];
    const uint4* sB = reinterpret_cast<const uint4*>(ubf) + ((size_t)(bb*4 + ec)*66 + 2*h2)*520;
    uint4* dB = reinterpret_cast<uint4*>(ubuf);
    for (int i = tid; i < 2080; i += 512) dB[i] = sB[i];
    __syncthreads();

    #pragma unroll
    for (int ki = 0; ki < 3; ++ki) {
      const ushort* brow = ubuf + (hr + ki)*4160 + lg*8;
      #pragma unroll
      for (int kj = 0; kj < 3; ++kj) {
        const ushort* wrow = wlds + (ki*3 + kj)*4096 + (wo*64 + lj)*32 + lg*8;
        short8v af[4], bfr[4];
        #pragma unroll
        for (int f = 0; f < 4; ++f)
          af[f] = *reinterpret_cast<const short8v*>(wrow + f*512);
        #pragma unroll
        for (int f = 0; f < 4; ++f)
          bfr[f] = *reinterpret_cast<const short8v*>(brow + (wseg + f*16 + lj + kj)*32);
        #pragma unroll
        for (int fo = 0; fo < 4; ++fo)
          #pragma unroll
          for (int fj = 0; fj < 4; ++fj)
            acc[fo][fj] = __builtin_amdgcn_mfma_f32_16x16x32_bf16(af[fo], bfr[fj], acc[fo][fj], 0, 0, 0);
      }
    }
  }

  int row = h2*2 + hr;              // pre-shuffle output row, 0..63
  #pragma unroll
  for (int fo = 0; fo < 4; ++fo) {
    int obase = oc*128 + wo*64 + fo*16 + lg*4;   // + q
    int g = obase >> 2;
    float b0 = cb[obase], b1 = cb[obase+1], b2 = cb[obase+2], b3 = cb[obase+3];
    size_t rbase0 = (((size_t)bb*128 + g)*128 + 2*row)*256;
    size_t rbase1 = rbase0 + 256;
    #pragma unroll
    for (int fj = 0; fj < 4; ++fj) {
      int w = wseg + fj*16 + lj;
      f32x4 a = acc[fo][fj];
      float2 v0 = make_float2(geluf(a.x + b0), geluf(a.y + b1));
      float2 v1 = make_float2(geluf(a.z + b2), geluf(a.w + b3));
      *reinterpret_cast<float2*>(out + rbase0 + 2*w) = v0;
      *reinterpret_cast<float2*>(out + rbase1 + 2*w) = v1;
    }
  }
}

// ---------------- FFN via bf16 MFMA: io = c + W2 @ gelu(W1 @ c + b1) + b2 (in-place) ----------------
// block: 128 px of one b, all 128 ch. 512 thr = 8 waves (wc 0..1 ch-half, wp 0..3 px-quarter).
__global__ __launch_bounds__(512) void k_ffnm(const ushort* __restrict__ wpad, const float* __restrict__ b1,
                                              const float* __restrict__ b2, float* __restrict__ io){
  extern __shared__ ushort sm[];
  ushort* cT = sm;              // [128 px][136] bf16, then f1 in same place
  ushort* wl = sm + 128*136;    // [128 e][136] bf16 (W1, then W2)
  int pix0 = blockIdx.x * 128;
  int bb = pix0 >> 15;
  int hw0 = pix0 & 32767;
  int tid = threadIdx.x;
  int l = tid & 63, wv = tid >> 6;
  int wc = wv >> 2, wp = wv & 3;
  int lj = l & 15, lg = l >> 4;
  int r = tid & 1, hpair = tid >> 1;      // for c staging
  const float* cbase = io + (size_t)bb*128*HW2 + hw0;

  // stage c transposed to bf16 [px][ch] via paired float2 + shfl_xor(1)
  for (int it = 0; it < 16; ++it) {
    int flat = it*256 + hpair;            // 0..4095
    int pp = flat & 63;                   // px-pair
    int cpair = flat >> 6;                // ch-pair
    int ch = cpair*2 + r;
    float2 v = *reinterpret_cast<const float2*>(cbase + (size_t)ch*HW2 + pp*2);
    float oa = __shfl_xor(v.x, 1);
    float ob = __shfl_xor(v.y, 1);
    ushort lo = r ? bf16rne(ob) : bf16rne(v.x);
    ushort hi = r ? bf16rne(v.y) : bf16rne(oa);
    *reinterpret_cast<uint*>(&cT[(pp*2 + r)*136 + cpair*2]) = (uint)lo | ((uint)hi << 16);
  }
  // stage W1 (pre-padded bf16 [128][136])
  {
    const uint4* src = reinterpret_cast<const uint4*>(wpad);
    uint4* dst = reinterpret_cast<uint4*>(wl);
    for (int i = tid; i < 2176; i += 512) dst[i] = src[i];
  }
  __syncthreads();

  f32x4 acc[4][2];
  #pragma unroll
  for (int fo = 0; fo < 4; ++fo)
    #pragma unroll
    for (int fj = 0; fj < 2; ++fj)
      acc[fo][fj] = (f32x4){0.f,0.f,0.f,0.f};

  // GEMM1: f1[e][px] = sum_c W1[e][c] * c[c][px]
  #pragma unroll
  for (int kc = 0; kc < 4; ++kc) {
    short8v af[4], bq[2];
    #pragma unroll
    for (int fo = 0; fo < 4; ++fo)
      af[fo] = *reinterpret_cast<const short8v*>(&wl[(wc*64 + fo*16 + lj)*136 + kc*32 + lg*8]);
    #pragma unroll
    for (int fj = 0; fj < 2; ++fj)
      bq[fj] = *reinterpret_cast<const short8v*>(&cT[(wp*32 + fj*16 + lj)*136 + kc*32 + lg*8]);
    #pragma unroll
    for (int fo = 0; fo < 4; ++fo)
      #pragma unroll
      for (int fj = 0; fj < 2; ++fj)
        acc[fo][fj] = __builtin_amdgcn_mfma_f32_16x16x32_bf16(af[fo], bq[fj], acc[fo][fj], 0, 0, 0);
  }
  __syncthreads();

  // f1 = gelu(acc + b1) -> cT (bf16, packed dword writes); stage W2 over W1
  #pragma unroll
  for (int fo = 0; fo < 4; ++fo) {
    int ch0 = wc*64 + fo*16 + lg*4;
    float c0 = b1[ch0], c1 = b1[ch0+1], c2 = b1[ch0+2], c3 = b1[ch0+3];
    #pragma unroll
    for (int fj = 0; fj < 2; ++fj) {
      int px = wp*32 + fj*16 + lj;
      f32x4 a = acc[fo][fj];
      uint2 u;
      u.x = (uint)bf16rne(geluf(a.x + c0)) | ((uint)bf16rne(geluf(a.y + c1)) << 16);
      u.y = (uint)bf16rne(geluf(a.z + c2)) | ((uint)bf16rne(geluf(a.w + c3)) << 16);
      *reinterpret_cast<uint2*>(&cT[px*136 + ch0]) = u;
    }
  }
  {
    const uint4* src = reinterpret_cast<const uint4*>(wpad) + 2176;
    uint4* dst = reinterpret_cast<uint4*>(wl);
    for (int i = tid; i < 2176; i += 512) dst[i] = src[i];
  }
  __syncthreads();

  #pragma unroll
  for (int fo = 0; fo < 4; ++fo)
    #pragma unroll
    for (int fj = 0; fj < 2; ++fj)
      acc[fo][fj] = (f32x4){0.f,0.f,0.f,0.f};

  // GEMM2: f2[ch][px] = sum_e W2[ch][e] * f1[e][px]
  #pragma unroll
  for (int kc = 0; kc < 4; ++kc) {
    short8v af[4], bq[2];
    #pragma unroll
    for (int fo = 0; fo < 4; ++fo)
      af[fo] = *reinterpret_cast<const short8v*>(&wl[(wc*64 + fo*16 + lj)*136 + kc*32 + lg*8]);
    #pragma unroll
    for (int fj = 0; fj < 2; ++fj)
      bq[fj] = *reinterpret_cast<const short8v*>(&cT[(wp*32 + fj*16 + lj)*136 + kc*32 + lg*8]);
    #pragma unroll
    for (int fo = 0; fo < 4; ++fo)
      #pragma unroll
      for (int fj = 0; fj < 2; ++fj)
        acc[fo][fj] = __builtin_amdgcn_mfma_f32_16x16x32_bf16(af[fo], bq[fj], acc[fo][fj], 0, 0, 0);
  }

  // epilogue: io += f2 + b2 (residual c still in io)
  #pragma unroll
  for (int fo = 0; fo < 4; ++fo) {
    int ch0 = wc*64 + fo*16 + lg*4;
    float d0 = b2[ch0], d1 = b2[ch0+1], d2 = b2[ch0+2], d3 = b2[ch0+3];
    #pragma unroll
    for (int fj = 0; fj < 2; ++fj) {
      int px = wp*32 + fj*16 + lj;
      f32x4 a = acc[fo][fj];
      float* p0 = (float*)io + (size_t)bb*128*HW2 + (size_t)ch0*HW2 + hw0 + px;
      p0[0]          += a.x + d0;
      p0[HW2]        += a.y + d1;
      p0[2*HW2]      += a.z + d2;
      p0[3*(size_t)HW2] += a.w + d3;
    }
  }
}

extern "C" void kernel_launch(void* const* d_in, const int* in_sizes, int n_in,
                              void* d_out, int out_size, void* d_ws, size_t ws_size,
                              hipStream_t stream) {
  const float* x          = (const float*)d_in[0];
  const float* patch_w    = (const float*)d_in[1];
  const float* patch_b    = (const float*)d_in[2];
  const float* in_proj_w  = (const float*)d_in[3];
  const float* conv1d_w   = (const float*)d_in[4];
  const float* conv1d_b   = (const float*)d_in[5];
  const float* x_proj_w   = (const float*)d_in[6];
  const float* dt_proj_w  = (const float*)d_in[7];
  const float* dt_proj_b  = (const float*)d_in[8];
  const float* A_log      = (const float*)d_in[9];
  const float* D_param    = (const float*)d_in[10];
  const float* out_proj_w = (const float*)d_in[11];
  const float* lin_w      = (const float*)d_in[12];
  const float* lin_b      = (const float*)d_in[13];
  const float* conv_w     = (const float*)d_in[14];
  const float* conv_b     = (const float*)d_in[15];
  const float* ffn_w1     = (const float*)d_in[16];
  const float* ffn_b1     = (const float*)d_in[17];
  const float* ffn_w2     = (const float*)d_in[18];
  const float* ffn_b2     = (const float*)d_in[19];
  float* out = (float*)d_out;
  float* ws  = (float*)d_ws;

  float* t   = ws;                 // 524288   (B*N, E)
  float* xz  = t   + 524288;       // 2097152  (B*N, 512)
  float* xc  = xz  + 2097152;      // 1048576  (B*N, 256)
  float* dbl = xc  + 1048576;      // 163840   (B*N, 40)
  float* dt  = dbl + 163840;       // 1048576  (B*N, 256)
  float* y   = dt  + 1048576;      // 1048576  (B*N, 256)
  float* yo  = y   + 1048576;      // 524288   (B*N, 128)
  ushort* ubf  = (ushort*)(yo + 524288);  // 10982400 bf16: [8][4][66][130][32]
  ushort* wbf  = ubf + 10982400;          // 589824 bf16:   [4][4][9][128][32]
  ushort* wpad = wbf + 589824;            // 34816 bf16:    [2][128][136]

  k_zero4 <<<dim3(5363), dim3(256), 0, stream>>>((uint4*)ubf, 1372800);
  k_wprep <<<dim3(2304), dim3(256), 0, stream>>>(conv_w, wbf);
  k_wffn  <<<dim3(136), dim3(256), 0, stream>>>(ffn_w1, ffn_w2, wpad);
  k_init_t<<<dim3(2048), dim3(256), 0, stream>>>(t, patch_b);
  k_patch <<<dim3(64, 2, 4), dim3(256), 0, stream>>>(x, patch_w, t);
  k_gemm  <<<dim3(64, 8), dim3(256), 0, stream>>>(t, in_proj_w, xz, 4096, 512, 128);
  k_conv1d<<<dim3(4096), dim3(256), 0, stream>>>(xz, conv1d_w, conv1d_b, xc);
  k_xproj <<<dim3(4096), dim3(256), 0, stream>>>(xc, x_proj_w, dt_proj_w, dt_proj_b, dbl, dt);
  k_scan  <<<dim3(128), dim3(256), 0, stream>>>(dt, dbl, xc, xz, A_log, D_param, y);
  k_gemm  <<<dim3(64, 2), dim3(256), 0, stream>>>(y, out_proj_w, yo, 4096, 128, 256);
  k_lin   <<<dim3(16, 128), dim3(256), 0, stream>>>(yo, lin_w, lin_b, ubf);
  k_conv3m<<<dim3(32, 32), dim3(512), (size_t)53504*sizeof(ushort), stream>>>(ubf, wbf, conv_b, out);
  k_ffnm  <<<dim3(2048), dim3(512), (size_t)(2*128*136)*sizeof(ushort), stream>>>(wpad, ffn_b1, ffn_b2, out);
}

// Round 4
// 434.690 us; speedup vs baseline: 6.6993x; 2.0088x over previous
//
#include <hip/hip_runtime.h>
#include <hip/hip_bf16.h>

// Shapes (fixed): B=8,C=256,H=64,W=128,P=4,E=DM=128,N=512,DI=256,DS=16,DC=4,DR=8,NG=128,S=2
#define HW2 32768   // 128*256 output spatial per (b,channel)

typedef __attribute__((ext_vector_type(8))) short short8v;
typedef __attribute__((ext_vector_type(4))) float f32x4;

__device__ __forceinline__ float siluf(float x){ return x / (1.f + __expf(-x)); }
__device__ __forceinline__ float geluf(float v){
  float t = 0.7978845608028654f * fmaf(0.044715f*v*v, v, v);
  t = fminf(fmaxf(t, -15.f), 15.f);
  float e = __expf(2.f*t);
  return 0.5f*v*(1.f + (e-1.f)/(e+1.f));
}
__device__ __forceinline__ ushort bf16rne(float f){
  unsigned u = __float_as_uint(f);
  unsigned r = (u + 0x7fffu + ((u >> 16) & 1u)) >> 16;
  return (ushort)r;
}

// ---------------- zero-fill (uint4 granularity) ----------------
__global__ __launch_bounds__(256) void k_zero4(uint4* __restrict__ p, int n){
  int i = blockIdx.x*256 + threadIdx.x;
  if (i < n) p[i] = make_uint4(0,0,0,0);
}

// ---------------- conv weights fp32 -> bf16, layout [oc4][ec4][tap9][o128][e32] ----------------
__global__ __launch_bounds__(256) void k_wprep(const float* __restrict__ cw, ushort* __restrict__ wbf){
  int idx = blockIdx.x*256 + threadIdx.x;   // 589824
  int e   = idx & 31;
  int o   = (idx >> 5) & 127;
  int t9  = (idx >> 12) % 9;
  int ece = idx / (4096*9);                 // oc*4+ec
  int oc  = ece >> 2, ec = ece & 3;
  float v = cw[(((size_t)oc*128 + o)*128 + ec*32 + e)*9 + t9];
  wbf[idx] = bf16rne(v);
}

// ---------------- FFN weights fp32 -> bf16 padded [2][128][136] ----------------
__global__ __launch_bounds__(256) void k_wffn(const float* __restrict__ w1, const float* __restrict__ w2,
                                              ushort* __restrict__ wpad){
  int idx = blockIdx.x*256 + threadIdx.x;   // 34816
  int which = idx / 17408;
  int rem = idx - which*17408;
  int e = rem / 136, k = rem - e*136;
  const float* s = which ? w2 : w1;
  wpad[idx] = (k < 128) ? bf16rne(s[e*128 + k]) : (ushort)0;
}

// ---------------- lin weights fp32 -> bf16 (same [m][n] layout) ----------------
__global__ __launch_bounds__(256) void k_wlin(const float* __restrict__ lw, ushort* __restrict__ lwbf){
  int i = blockIdx.x*256 + threadIdx.x;     // 1048576 float4s
  float4 v = reinterpret_cast<const float4*>(lw)[i];
  uint2 u;
  u.x = (uint)bf16rne(v.x) | ((uint)bf16rne(v.y) << 16);
  u.y = (uint)bf16rne(v.z) | ((uint)bf16rne(v.w) << 16);
  reinterpret_cast<uint2*>(lwbf)[i] = u;
}

// ---------------- yo (4096 x 128 fp32) -> ybfT [b][e128][n512] bf16 ----------------
__global__ __launch_bounds__(256) void k_ytr(const float* __restrict__ yo, ushort* __restrict__ ybfT){
  __shared__ float tile[32][132];
  int b = blockIdx.x, n0 = blockIdx.y*32;
  int tid = threadIdx.x;
  for (int it = 0; it < 16; ++it) {
    int idx = it*256 + tid;
    int row = idx >> 7, e = idx & 127;
    tile[row][e] = yo[((size_t)(b*512 + n0 + row))*128 + e];
  }
  __syncthreads();
  int e = tid >> 1, half = tid & 1;
  uint* dst = reinterpret_cast<uint*>(ybfT + ((size_t)b*128 + e)*512 + n0 + half*16);
  #pragma unroll
  for (int j = 0; j < 8; ++j) {
    int n = half*16 + j*2;
    dst[j] = (uint)bf16rne(tile[n][e]) | ((uint)bf16rne(tile[n+1][e]) << 16);
  }
}

// ---------------- t init with patch bias ----------------
__global__ __launch_bounds__(256) void k_init_t(float* __restrict__ t, const float* __restrict__ pb){
  int i = blockIdx.x*256 + threadIdx.x;   // 524288 total
  t[i] = pb[i & 127];
}

// ---------------- patch-embed GEMM (im2col, split-K=4, atomic) ----------------
__global__ __launch_bounds__(256) void k_patch(const float* __restrict__ x, const float* __restrict__ pw,
                                               float* __restrict__ t){
  __shared__ __align__(16) float As[16][68];
  __shared__ __align__(16) float Bs[16][68];
  int m0 = blockIdx.x * 64;
  int n0 = blockIdx.y * 64;
  int kbase = blockIdx.z * 1024;
  int tid = threadIdx.x;
  int tm = tid >> 4, tn = tid & 15;
  int lm = tid >> 2, kq = tid & 3;
  float acc[4][4] = {};
  int m = m0 + lm;
  int bb = m >> 9;
  int l  = m & 511;
  int hp = l >> 5, wp = l & 31;
  const float* wbase = pw + (n0 + lm)*4096 + kq*4;
  for (int k0 = kbase; k0 < kbase + 1024; k0 += 16) {
    int k  = k0 + kq*4;
    int c  = k >> 4;
    int i2 = (k >> 2) & 3;
    float4 av = *reinterpret_cast<const float4*>(x + (((bb*256 + c)*64 + hp*4 + i2)*128 + wp*4));
    float4 bv = *reinterpret_cast<const float4*>(wbase + k0);
    As[kq*4+0][lm]=av.x; As[kq*4+1][lm]=av.y; As[kq*4+2][lm]=av.z; As[kq*4+3][lm]=av.w;
    Bs[kq*4+0][lm]=bv.x; Bs[kq*4+1][lm]=bv.y; Bs[kq*4+2][lm]=bv.z; Bs[kq*4+3][lm]=bv.w;
    __syncthreads();
    #pragma unroll
    for (int kk = 0; kk < 16; ++kk) {
      float4 a = *reinterpret_cast<const float4*>(&As[kk][tm*4]);
      float4 b = *reinterpret_cast<const float4*>(&Bs[kk][tn*4]);
      float ar[4] = {a.x,a.y,a.z,a.w};
      float br[4] = {b.x,b.y,b.z,b.w};
      #pragma unroll
      for (int i = 0; i < 4; ++i)
        #pragma unroll
        for (int j = 0; j < 4; ++j)
          acc[i][j] = fmaf(ar[i], br[j], acc[i][j]);
    }
    __syncthreads();
  }
  #pragma unroll
  for (int i = 0; i < 4; ++i)
    #pragma unroll
    for (int j = 0; j < 4; ++j)
      atomicAdd(&t[(m0 + tm*4 + i)*128 + (n0 + tn*4 + j)], acc[i][j]);
}

// ---------------- generic tiled GEMM: C(M,N) = A(M,K) @ W(N,K)^T ----------------
__global__ __launch_bounds__(256) void k_gemm(const float* __restrict__ A, const float* __restrict__ W,
                                              float* __restrict__ C, int M, int N, int K){
  __shared__ __align__(16) float As[16][68];
  __shared__ __align__(16) float Bs[16][68];
  int m0 = blockIdx.x * 64, n0 = blockIdx.y * 64;
  int tid = threadIdx.x;
  int tm = tid >> 4, tn = tid & 15;
  int lm = tid >> 2, kq = tid & 3;
  float acc[4][4] = {};
  const float* Abase = A + (size_t)(m0 + lm)*K + kq*4;
  const float* Wbase = W + (size_t)(n0 + lm)*K + kq*4;
  for (int k0 = 0; k0 < K; k0 += 16) {
    float4 av = *reinterpret_cast<const float4*>(Abase + k0);
    float4 bv = *reinterpret_cast<const float4*>(Wbase + k0);
    As[kq*4+0][lm]=av.x; As[kq*4+1][lm]=av.y; As[kq*4+2][lm]=av.z; As[kq*4+3][lm]=av.w;
    Bs[kq*4+0][lm]=bv.x; Bs[kq*4+1][lm]=bv.y; Bs[kq*4+2][lm]=bv.z; Bs[kq*4+3][lm]=bv.w;
    __syncthreads();
    #pragma unroll
    for (int kk = 0; kk < 16; ++kk) {
      float4 a = *reinterpret_cast<const float4*>(&As[kk][tm*4]);
      float4 b = *reinterpret_cast<const float4*>(&Bs[kk][tn*4]);
      float ar[4] = {a.x,a.y,a.z,a.w};
      float br[4] = {b.x,b.y,b.z,b.w};
      #pragma unroll
      for (int i = 0; i < 4; ++i)
        #pragma unroll
        for (int j = 0; j < 4; ++j)
          acc[i][j] = fmaf(ar[i], br[j], acc[i][j]);
    }
    __syncthreads();
  }
  #pragma unroll
  for (int i = 0; i < 4; ++i) {
    float4 ov = make_float4(acc[i][0], acc[i][1], acc[i][2], acc[i][3]);
    *reinterpret_cast<float4*>(C + (size_t)(m0 + tm*4 + i)*N + n0 + tn*4) = ov;
  }
}

// ---------------- causal conv1d (DC=4) + silu ----------------
__global__ __launch_bounds__(256) void k_conv1d(const float* __restrict__ xz, const float* __restrict__ w,
                                                const float* __restrict__ bias, float* __restrict__ xc){
  int idx = blockIdx.x*256 + threadIdx.x;   // over 8*512*256
  int d = idx & 255;
  int l = (idx >> 8) & 511;
  int bb = idx >> 17;
  const float* base = xz + (size_t)bb*512*512 + d;   // xin = xz[...,:256]
  float s = bias[d];
  #pragma unroll
  for (int k = 0; k < 4; ++k) {
    int ls = l - 3 + k;
    if (ls >= 0) s = fmaf(base[(size_t)ls*512], w[d*4+k], s);
  }
  xc[idx] = s / (1.f + __expf(-s));
}

// ---------------- x_proj (40 outs) + dt_proj + softplus ----------------
__global__ __launch_bounds__(256) void k_xproj(const float* __restrict__ xc, const float* __restrict__ xpw,
                                               const float* __restrict__ dtw, const float* __restrict__ dtb,
                                               float* __restrict__ dbl, float* __restrict__ dt){
  __shared__ __align__(16) float sxc[256];
  __shared__ float sdbl[40];
  int bl = blockIdx.x;         // (b,l) 0..4095
  int tid = threadIdx.x;
  sxc[tid] = xc[(size_t)bl*256 + tid];
  __syncthreads();
  if (tid < 40) {
    const float4* wr = reinterpret_cast<const float4*>(xpw + tid*256);
    const float4* xr = reinterpret_cast<const float4*>(sxc);
    float s = 0.f;
    #pragma unroll 8
    for (int i = 0; i < 64; ++i) {
      float4 w = wr[i], xv = xr[i];
      s += w.x*xv.x + w.y*xv.y + w.z*xv.z + w.w*xv.w;
    }
    sdbl[tid] = s;
    dbl[(size_t)bl*40 + tid] = s;
  }
  __syncthreads();
  float s = dtb[tid];
  const float* wr = dtw + tid*8;
  #pragma unroll
  for (int r = 0; r < 8; ++r) s = fmaf(sdbl[r], wr[r], s);
  float sp = (s > 20.f) ? s : log1pf(__expf(s));
  dt[(size_t)bl*256 + tid] = sp;
}

// ---------------- chunk-parallel selective scan ----------------
// CH=16 chunks of T=32. Arrays aprod/hend/hstart: [(b*16+dgrp)*16 + ch][256] (tid = dloc*16+n)
__global__ __launch_bounds__(256) void k_scanA(const float* __restrict__ dt, const float* __restrict__ dbl,
                                               const float* __restrict__ xc, const float* __restrict__ A_log,
                                               float* __restrict__ aprod, float* __restrict__ hend){
  int tid = threadIdx.x;
  int n = tid & 15, dloc = tid >> 4;
  int bg = blockIdx.x;            // b*16 + dgrp
  int ch = blockIdx.y;
  int bb = bg >> 4, dgrp = bg & 15;
  int d = dgrp*16 + dloc;
  float Ac = -__expf(A_log[d*16 + n]);
  float a = 1.f, h = 0.f;
  int l0 = ch*32;
  for (int t = 0; t < 32; ++t) {
    int base = bb*512 + l0 + t;
    float dtv = dt[(size_t)base*256 + d];
    float xcv = xc[(size_t)base*256 + d];
    float Bv  = dbl[(size_t)base*40 + 8 + n];
    float dA = __expf(dtv*Ac);
    h = fmaf(dA, h, dtv*Bv*xcv);
    a *= dA;
  }
  aprod[(size_t)(bg*16 + ch)*256 + tid] = a;
  hend [(size_t)(bg*16 + ch)*256 + tid] = h;
}

__global__ __launch_bounds__(256) void k_scanB(const float* __restrict__ aprod, const float* __restrict__ hend,
                                               float* __restrict__ hstart){
  int tid = threadIdx.x;
  int bg = blockIdx.x;
  float hs = 0.f;
  #pragma unroll
  for (int ch = 0; ch < 16; ++ch) {
    size_t idx = (size_t)(bg*16 + ch)*256 + tid;
    hstart[idx] = hs;
    hs = fmaf(aprod[idx], hs, hend[idx]);
  }
}

__global__ __launch_bounds__(256) void k_scanC(const float* __restrict__ dt, const float* __restrict__ dbl,
                                               const float* __restrict__ xc, const float* __restrict__ xz,
                                               const float* __restrict__ A_log, const float* __restrict__ Dp,
                                               const float* __restrict__ hstart, float* __restrict__ y){
  int tid = threadIdx.x;
  int n = tid & 15, dloc = tid >> 4;
  int bg = blockIdx.x;
  int ch = blockIdx.y;
  int bb = bg >> 4, dgrp = bg & 15;
  int d = dgrp*16 + dloc;
  float Ac = -__expf(A_log[d*16 + n]);
  float Dv = Dp[d];
  float h = hstart[(size_t)(bg*16 + ch)*256 + tid];
  int l0 = ch*32;
  for (int t = 0; t < 32; ++t) {
    int base = bb*512 + l0 + t;
    float dtv = dt[(size_t)base*256 + d];
    float xcv = xc[(size_t)base*256 + d];
    float Bv  = dbl[(size_t)base*40 + 8  + n];
    float Cv  = dbl[(size_t)base*40 + 24 + n];
    float dA = __expf(dtv*Ac);
    h = fmaf(dA, h, dtv*Bv*xcv);
    float yp = h*Cv;
    yp += __shfl_xor(yp, 1, 16);
    yp += __shfl_xor(yp, 2, 16);
    yp += __shfl_xor(yp, 4, 16);
    yp += __shfl_xor(yp, 8, 16);
    if (n == 0) {
      float zv = xz[(size_t)base*512 + 256 + d];
      y[(size_t)base*256 + d] = (yp + Dv*xcv) * (zv / (1.f + __expf(-zv)));
    }
  }
}

// ---------------- lin via bf16 MFMA + bias + pixel-shuffle -> padded bf16 ubf ----------------
// grid (mtile=64, b=8), block 512 = 8 waves (we: e-half 64, wm: m-quarter 32).
__global__ __launch_bounds__(512) void k_linm(const ushort* __restrict__ ybfT, const ushort* __restrict__ lwbf,
                                              const float* __restrict__ lb, ushort* __restrict__ ubf){
  __shared__ ushort As[128*80];
  __shared__ ushort Bs[128*80];
  int m0 = blockIdx.x * 128;
  int b  = blockIdx.y;
  int tid = threadIdx.x;
  int l = tid & 63, wv = tid >> 6;
  int wm = wv & 3, we = wv >> 2;
  int lj = l & 15, lg = l >> 4;
  f32x4 acc[4][2];
  #pragma unroll
  for (int fo = 0; fo < 4; ++fo)
    #pragma unroll
    for (int fj = 0; fj < 2; ++fj)
      acc[fo][fj] = (f32x4){0.f,0.f,0.f,0.f};

  for (int k0 = 0; k0 < 512; k0 += 64) {
    __syncthreads();
    #pragma unroll
    for (int it = 0; it < 2; ++it) {
      int flat = it*512 + tid;        // 0..1023
      int e = flat >> 3, kc8 = flat & 7;
      *reinterpret_cast<uint4*>(&As[e*80 + kc8*8]) =
        *reinterpret_cast<const uint4*>(ybfT + ((size_t)b*128 + e)*512 + k0 + kc8*8);
      *reinterpret_cast<uint4*>(&Bs[e*80 + kc8*8]) =
        *reinterpret_cast<const uint4*>(lwbf + (size_t)(m0 + e)*512 + k0 + kc8*8);
    }
    __syncthreads();
    #pragma unroll
    for (int kc = 0; kc < 2; ++kc) {
      short8v af[4], bq[2];
      #pragma unroll
      for (int fo = 0; fo < 4; ++fo)
        af[fo] = *reinterpret_cast<const short8v*>(&As[(we*64 + fo*16 + lj)*80 + kc*32 + lg*8]);
      #pragma unroll
      for (int fj = 0; fj < 2; ++fj)
        bq[fj] = *reinterpret_cast<const short8v*>(&Bs[(wm*32 + fj*16 + lj)*80 + kc*32 + lg*8]);
      #pragma unroll
      for (int fo = 0; fo < 4; ++fo)
        #pragma unroll
        for (int fj = 0; fj < 2; ++fj)
          acc[fo][fj] = __builtin_amdgcn_mfma_f32_16x16x32_bf16(af[fo], bq[fj], acc[fo][fj], 0, 0, 0);
    }
  }
  // epilogue: D col = m (lane&15), row = e_local = lg*4+reg. 4 consecutive e per lane -> 8B store.
  #pragma unroll
  for (int fj = 0; fj < 2; ++fj) {
    int m = m0 + wm*32 + fj*16 + lj;
    float bias = lb[m];
    int hh = ((m >> 9) << 2) + ((m >> 2) & 3);
    int ww = (((m >> 4) & 31) << 2) + (m & 3);
    #pragma unroll
    for (int fo = 0; fo < 4; ++fo) {
      int eg = we*2 + (fo >> 1);
      int e5 = ((fo & 1) << 4) + (lg << 2);
      f32x4 a = acc[fo][fj];
      uint2 u;
      u.x = (uint)bf16rne(a.x + bias) | ((uint)bf16rne(a.y + bias) << 16);
      u.y = (uint)bf16rne(a.z + bias) | ((uint)bf16rne(a.w + bias) << 16);
      *reinterpret_cast<uint2*>(ubf + ((((size_t)b*4 + eg)*66 + hh + 1)*130 + ww + 1)*32 + e5) = u;
    }
  }
}

// ---------------- conv3x3 via bf16 MFMA implicit GEMM + bias + pixel-shuffle + gelu -> d_out ----------------
__global__ __launch_bounds__(512) void k_conv3m(const ushort* __restrict__ ubf, const ushort* __restrict__ wbf,
                                                const float* __restrict__ cb, float* __restrict__ out){
  extern __shared__ ushort smu[];
  ushort* ubuf = smu;           // [4 rows][130 w'][32 e] stride 4160
  ushort* wlds = smu + 16640;   // [9 tap][128 o][32 e]
  int h2 = blockIdx.x;          // 0..31 (pair of output rows pre-shuffle)
  int bz = blockIdx.y;
  int bb = bz >> 2, oc = bz & 3;
  int tid = threadIdx.x;
  int l   = tid & 63;
  int wv  = tid >> 6;
  int wo  = wv & 1;             // o half (64)
  int wsp = wv >> 1;
  int hr  = wsp >> 1;           // row within pair
  int wseg = (wsp & 1) * 64;    // w half
  int lj = l & 15, lg = l >> 4;

  f32x4 acc[4][4];
  #pragma unroll
  for (int i = 0; i < 4; ++i)
    #pragma unroll
    for (int j = 0; j < 4; ++j)
      acc[i][j] = (f32x4){0.f, 0.f, 0.f, 0.f};

  for (int ec = 0; ec < 4; ++ec) {
    __syncthreads();
    const uint4* sA = reinterpret_cast<const uint4*>(wbf) + (size_t)(oc*4 + ec)*4608;
    uint4* dA = reinterpret_cast<uint4*>(wlds);
    for (int i = tid; i < 4608; i += 512) dA[i] = sA[i];
    const uint4* sB = reinterpret_cast<const uint4*>(ubf) + ((size_t)(bb*4 + ec)*66 + 2*h2)*520;
    uint4* dB = reinterpret_cast<uint4*>(ubuf);
    for (int i = tid; i < 2080; i += 512) dB[i] = sB[i];
    __syncthreads();

    #pragma unroll
    for (int ki = 0; ki < 3; ++ki) {
      const ushort* brow = ubuf + (hr + ki)*4160 + lg*8;
      #pragma unroll
      for (int kj = 0; kj < 3; ++kj) {
        const ushort* wrow = wlds + (ki*3 + kj)*4096 + (wo*64 + lj)*32 + lg*8;
        short8v af[4], bfr[4];
        #pragma unroll
        for (int f = 0; f < 4; ++f)
          af[f] = *reinterpret_cast<const short8v*>(wrow + f*512);
        #pragma unroll
        for (int f = 0; f < 4; ++f)
          bfr[f] = *reinterpret_cast<const short8v*>(brow + (wseg + f*16 + lj + kj)*32);
        #pragma unroll
        for (int fo = 0; fo < 4; ++fo)
          #pragma unroll
          for (int fj = 0; fj < 4; ++fj)
            acc[fo][fj] = __builtin_amdgcn_mfma_f32_16x16x32_bf16(af[fo], bfr[fj], acc[fo][fj], 0, 0, 0);
      }
    }
  }

  int row = h2*2 + hr;              // pre-shuffle output row, 0..63
  #pragma unroll
  for (int fo = 0; fo < 4; ++fo) {
    int obase = oc*128 + wo*64 + fo*16 + lg*4;   // + q
    int g = obase >> 2;
    float b0 = cb[obase], b1 = cb[obase+1], b2 = cb[obase+2], b3 = cb[obase+3];
    size_t rbase0 = (((size_t)bb*128 + g)*128 + 2*row)*256;
    size_t rbase1 = rbase0 + 256;
    #pragma unroll
    for (int fj = 0; fj < 4; ++fj) {
      int w = wseg + fj*16 + lj;
      f32x4 a = acc[fo][fj];
      float2 v0 = make_float2(geluf(a.x + b0), geluf(a.y + b1));
      float2 v1 = make_float2(geluf(a.z + b2), geluf(a.w + b3));
      *reinterpret_cast<float2*>(out + rbase0 + 2*w) = v0;
      *reinterpret_cast<float2*>(out + rbase1 + 2*w) = v1;
    }
  }
}

// ---------------- FFN via bf16 MFMA: io = c + W2 @ gelu(W1 @ c + b1) + b2 (in-place) ----------------
__global__ __launch_bounds__(512) void k_ffnm(const ushort* __restrict__ wpad, const float* __restrict__ b1,
                                              const float* __restrict__ b2, float* __restrict__ io){
  extern __shared__ ushort sm[];
  ushort* cT = sm;              // [128 px][136] bf16, then f1 in same place
  ushort* wl = sm + 128*136;    // [128 e][136] bf16 (W1, then W2)
  int pix0 = blockIdx.x * 128;
  int bb = pix0 >> 15;
  int hw0 = pix0 & 32767;
  int tid = threadIdx.x;
  int l = tid & 63, wv = tid >> 6;
  int wc = wv >> 2, wp = wv & 3;
  int lj = l & 15, lg = l >> 4;
  int r = tid & 1, hpair = tid >> 1;      // for c staging
  const float* cbase = io + (size_t)bb*128*HW2 + hw0;

  for (int it = 0; it < 16; ++it) {
    int flat = it*256 + hpair;            // 0..4095
    int pp = flat & 63;                   // px-pair
    int cpair = flat >> 6;                // ch-pair
    int ch = cpair*2 + r;
    float2 v = *reinterpret_cast<const float2*>(cbase + (size_t)ch*HW2 + pp*2);
    float oa = __shfl_xor(v.x, 1);
    float ob = __shfl_xor(v.y, 1);
    ushort lo = r ? bf16rne(ob) : bf16rne(v.x);
    ushort hi = r ? bf16rne(v.y) : bf16rne(oa);
    *reinterpret_cast<uint*>(&cT[(pp*2 + r)*136 + cpair*2]) = (uint)lo | ((uint)hi << 16);
  }
  {
    const uint4* src = reinterpret_cast<const uint4*>(wpad);
    uint4* dst = reinterpret_cast<uint4*>(wl);
    for (int i = tid; i < 2176; i += 512) dst[i] = src[i];
  }
  __syncthreads();

  f32x4 acc[4][2];
  #pragma unroll
  for (int fo = 0; fo < 4; ++fo)
    #pragma unroll
    for (int fj = 0; fj < 2; ++fj)
      acc[fo][fj] = (f32x4){0.f,0.f,0.f,0.f};

  #pragma unroll
  for (int kc = 0; kc < 4; ++kc) {
    short8v af[4], bq[2];
    #pragma unroll
    for (int fo = 0; fo < 4; ++fo)
      af[fo] = *reinterpret_cast<const short8v*>(&wl[(wc*64 + fo*16 + lj)*136 + kc*32 + lg*8]);
    #pragma unroll
    for (int fj = 0; fj < 2; ++fj)
      bq[fj] = *reinterpret_cast<const short8v*>(&cT[(wp*32 + fj*16 + lj)*136 + kc*32 + lg*8]);
    #pragma unroll
    for (int fo = 0; fo < 4; ++fo)
      #pragma unroll
      for (int fj = 0; fj < 2; ++fj)
        acc[fo][fj] = __builtin_amdgcn_mfma_f32_16x16x32_bf16(af[fo], bq[fj], acc[fo][fj], 0, 0, 0);
  }
  __syncthreads();

  #pragma unroll
  for (int fo = 0; fo < 4; ++fo) {
    int ch0 = wc*64 + fo*16 + lg*4;
    float c0 = b1[ch0], c1 = b1[ch0+1], c2 = b1[ch0+2], c3 = b1[ch0+3];
    #pragma unroll
    for (int fj = 0; fj < 2; ++fj) {
      int px = wp*32 + fj*16 + lj;
      f32x4 a = acc[fo][fj];
      uint2 u;
      u.x = (uint)bf16rne(geluf(a.x + c0)) | ((uint)bf16rne(geluf(a.y + c1)) << 16);
      u.y = (uint)bf16rne(geluf(a.z + c2)) | ((uint)bf16rne(geluf(a.w + c3)) << 16);
      *reinterpret_cast<uint2*>(&cT[px*136 + ch0]) = u;
    }
  }
  {
    const uint4* src = reinterpret_cast<const uint4*>(wpad) + 2176;
    uint4* dst = reinterpret_cast<uint4*>(wl);
    for (int i = tid; i < 2176; i += 512) dst[i] = src[i];
  }
  __syncthreads();

  #pragma unroll
  for (int fo = 0; fo < 4; ++fo)
    #pragma unroll
    for (int fj = 0; fj < 2; ++fj)
      acc[fo][fj] = (f32x4){0.f,0.f,0.f,0.f};

  #pragma unroll
  for (int kc = 0; kc < 4; ++kc) {
    short8v af[4], bq[2];
    #pragma unroll
    for (int fo = 0; fo < 4; ++fo)
      af[fo] = *reinterpret_cast<const short8v*>(&wl[(wc*64 + fo*16 + lj)*136 + kc*32 + lg*8]);
    #pragma unroll
    for (int fj = 0; fj < 2; ++fj)
      bq[fj] = *reinterpret_cast<const short8v*>(&cT[(wp*32 + fj*16 + lj)*136 + kc*32 + lg*8]);
    #pragma unroll
    for (int fo = 0; fo < 4; ++fo)
      #pragma unroll
      for (int fj = 0; fj < 2; ++fj)
        acc[fo][fj] = __builtin_amdgcn_mfma_f32_16x16x32_bf16(af[fo], bq[fj], acc[fo][fj], 0, 0, 0);
  }

  #pragma unroll
  for (int fo = 0; fo < 4; ++fo) {
    int ch0 = wc*64 + fo*16 + lg*4;
    float d0 = b2[ch0], d1 = b2[ch0+1], d2 = b2[ch0+2], d3 = b2[ch0+3];
    #pragma unroll
    for (int fj = 0; fj < 2; ++fj) {
      int px = wp*32 + fj*16 + lj;
      f32x4 a = acc[fo][fj];
      float* p0 = (float*)io + (size_t)bb*128*HW2 + (size_t)ch0*HW2 + hw0 + px;
      p0[0]          += a.x + d0;
      p0[HW2]        += a.y + d1;
      p0[2*HW2]      += a.z + d2;
      p0[3*(size_t)HW2] += a.w + d3;
    }
  }
}

extern "C" void kernel_launch(void* const* d_in, const int* in_sizes, int n_in,
                              void* d_out, int out_size, void* d_ws, size_t ws_size,
                              hipStream_t stream) {
  const float* x          = (const float*)d_in[0];
  const float* patch_w    = (const float*)d_in[1];
  const float* patch_b    = (const float*)d_in[2];
  const float* in_proj_w  = (const float*)d_in[3];
  const float* conv1d_w   = (const float*)d_in[4];
  const float* conv1d_b   = (const float*)d_in[5];
  const float* x_proj_w   = (const float*)d_in[6];
  const float* dt_proj_w  = (const float*)d_in[7];
  const float* dt_proj_b  = (const float*)d_in[8];
  const float* A_log      = (const float*)d_in[9];
  const float* D_param    = (const float*)d_in[10];
  const float* out_proj_w = (const float*)d_in[11];
  const float* lin_w      = (const float*)d_in[12];
  const float* lin_b      = (const float*)d_in[13];
  const float* conv_w     = (const float*)d_in[14];
  const float* conv_b     = (const float*)d_in[15];
  const float* ffn_w1     = (const float*)d_in[16];
  const float* ffn_b1     = (const float*)d_in[17];
  const float* ffn_w2     = (const float*)d_in[18];
  const float* ffn_b2     = (const float*)d_in[19];
  float* out = (float*)d_out;
  float* ws  = (float*)d_ws;

  float* t    = ws;                 // 524288   (B*N, E)
  float* xz   = t    + 524288;      // 2097152  (B*N, 512)
  float* xc   = xz   + 2097152;     // 1048576  (B*N, 256)
  float* dbl  = xc   + 1048576;     // 163840   (B*N, 40)
  float* dt   = dbl  + 163840;      // 1048576  (B*N, 256)
  float* y    = dt   + 1048576;     // 1048576  (B*N, 256)
  float* yo   = y    + 1048576;     // 524288   (B*N, 128)
  float* apr  = yo   + 524288;      // 524288   [bg16][ch16][256]
  float* hend = apr  + 524288;      // 524288
  float* hst  = hend + 524288;      // 524288
  ushort* ubf  = (ushort*)(hst + 524288); // 10982400 bf16: [8][4][66][130][32]
  ushort* wbf  = ubf + 10982400;          // 589824 bf16:   [4][4][9][128][32]
  ushort* wpad = wbf + 589824;            // 34816 bf16:    [2][128][136]
  ushort* lwbf = wpad + 34816;            // 4194304 bf16:  [8192][512]
  ushort* ybfT = lwbf + 4194304;          // 524288 bf16:   [8][128][512]

  k_zero4 <<<dim3(5363), dim3(256), 0, stream>>>((uint4*)ubf, 1372800);
  k_wprep <<<dim3(2304), dim3(256), 0, stream>>>(conv_w, wbf);
  k_wffn  <<<dim3(136), dim3(256), 0, stream>>>(ffn_w1, ffn_w2, wpad);
  k_wlin  <<<dim3(4096), dim3(256), 0, stream>>>(lin_w, lwbf);
  k_init_t<<<dim3(2048), dim3(256), 0, stream>>>(t, patch_b);
  k_patch <<<dim3(64, 2, 4), dim3(256), 0, stream>>>(x, patch_w, t);
  k_gemm  <<<dim3(64, 8), dim3(256), 0, stream>>>(t, in_proj_w, xz, 4096, 512, 128);
  k_conv1d<<<dim3(4096), dim3(256), 0, stream>>>(xz, conv1d_w, conv1d_b, xc);
  k_xproj <<<dim3(4096), dim3(256), 0, stream>>>(xc, x_proj_w, dt_proj_w, dt_proj_b, dbl, dt);
  k_scanA <<<dim3(128, 16), dim3(256), 0, stream>>>(dt, dbl, xc, A_log, apr, hend);
  k_scanB <<<dim3(128), dim3(256), 0, stream>>>(apr, hend, hst);
  k_scanC <<<dim3(128, 16), dim3(256), 0, stream>>>(dt, dbl, xc, xz, A_log, D_param, hst, y);
  k_gemm  <<<dim3(64, 2), dim3(256), 0, stream>>>(y, out_proj_w, yo, 4096, 128, 256);
  k_ytr   <<<dim3(8, 16), dim3(256), 0, stream>>>(yo, ybfT);
  k_linm  <<<dim3(64, 8), dim3(512), 0, stream>>>(ybfT, lwbf, lin_b, ubf);
  k_conv3m<<<dim3(32, 32), dim3(512), (size_t)53504*sizeof(ushort), stream>>>(ubf, wbf, conv_b, out);
  k_ffnm  <<<dim3(2048), dim3(512), (size_t)(2*128*136)*sizeof(ushort), stream>>>(wpad, ffn_b1, ffn_b2, out);
}

// Round 5
// 418.766 us; speedup vs baseline: 6.9540x; 1.0380x over previous
//
#include <hip/hip_runtime.h>
#include <hip/hip_bf16.h>

// Shapes (fixed): B=8,C=256,H=64,W=128,P=4,E=DM=128,N=512,DI=256,DS=16,DC=4,DR=8,NG=128,S=2
#define HW2 32768   // 128*256 output spatial per (b,channel)

typedef __attribute__((ext_vector_type(8))) short short8v;
typedef __attribute__((ext_vector_type(4))) float f32x4;

__device__ __forceinline__ float siluf(float x){ return x / (1.f + __expf(-x)); }
__device__ __forceinline__ float geluf(float v){
  float t = 0.7978845608028654f * fmaf(0.044715f*v*v, v, v);
  t = fminf(fmaxf(t, -15.f), 15.f);
  float e = __expf(2.f*t);
  return 0.5f*v*(1.f + (e-1.f)/(e+1.f));
}
__device__ __forceinline__ ushort bf16rne(float f){
  unsigned u = __float_as_uint(f);
  unsigned r = (u + 0x7fffu + ((u >> 16) & 1u)) >> 16;
  return (ushort)r;
}
__device__ __forceinline__ float bf2f(ushort u){ return __uint_as_float(((unsigned)u) << 16); }

// ---------------- zero-fill (uint4 granularity) ----------------
__global__ __launch_bounds__(256) void k_zero4(uint4* __restrict__ p, int n){
  int i = blockIdx.x*256 + threadIdx.x;
  if (i < n) p[i] = make_uint4(0,0,0,0);
}

// ---------------- conv weights fp32 -> bf16, layout [ocg8][ec4][tap9][o64][e32] ----------------
__global__ __launch_bounds__(256) void k_wprep(const float* __restrict__ cw, ushort* __restrict__ wbf){
  int idx = blockIdx.x*256 + threadIdx.x;   // 589824
  int e   = idx & 31;
  int op  = (idx >> 5) & 63;
  int t9  = (idx >> 11) % 9;
  int rest = idx / (2048*9);                // ocg*4 + ec, 0..31
  int ec  = rest & 3;
  int ocg = rest >> 2;                      // oc*2 + oh
  float v = cw[(((size_t)(ocg*64 + op)*128) + ec*32 + e)*9 + t9];
  wbf[idx] = bf16rne(v);
}

// ---------------- FFN weights fp32 -> bf16 padded [2][128][136] ----------------
__global__ __launch_bounds__(256) void k_wffn(const float* __restrict__ w1, const float* __restrict__ w2,
                                              ushort* __restrict__ wpad){
  int idx = blockIdx.x*256 + threadIdx.x;   // 34816
  int which = idx / 17408;
  int rem = idx - which*17408;
  int e = rem / 136, k = rem - e*136;
  const float* s = which ? w2 : w1;
  wpad[idx] = (k < 128) ? bf16rne(s[e*128 + k]) : (ushort)0;
}

// ---------------- lin weights fp32 -> bf16 (same [m][n] layout) ----------------
__global__ __launch_bounds__(256) void k_wlin(const float* __restrict__ lw, ushort* __restrict__ lwbf){
  int i = blockIdx.x*256 + threadIdx.x;     // 1048576 float4s
  float4 v = reinterpret_cast<const float4*>(lw)[i];
  uint2 u;
  u.x = (uint)bf16rne(v.x) | ((uint)bf16rne(v.y) << 16);
  u.y = (uint)bf16rne(v.z) | ((uint)bf16rne(v.w) << 16);
  reinterpret_cast<uint2*>(lwbf)[i] = u;
}

// ---------------- yo (4096 x 128 fp32) -> ybfT [b][e128][n512] bf16 ----------------
__global__ __launch_bounds__(256) void k_ytr(const float* __restrict__ yo, ushort* __restrict__ ybfT){
  __shared__ float tile[32][132];
  int b = blockIdx.x, n0 = blockIdx.y*32;
  int tid = threadIdx.x;
  for (int it = 0; it < 16; ++it) {
    int idx = it*256 + tid;
    int row = idx >> 7, e = idx & 127;
    tile[row][e] = yo[((size_t)(b*512 + n0 + row))*128 + e];
  }
  __syncthreads();
  int e = tid >> 1, half = tid & 1;
  uint* dst = reinterpret_cast<uint*>(ybfT + ((size_t)b*128 + e)*512 + n0 + half*16);
  #pragma unroll
  for (int j = 0; j < 8; ++j) {
    int n = half*16 + j*2;
    dst[j] = (uint)bf16rne(tile[n][e]) | ((uint)bf16rne(tile[n+1][e]) << 16);
  }
}

// ---------------- t init with patch bias ----------------
__global__ __launch_bounds__(256) void k_init_t(float* __restrict__ t, const float* __restrict__ pb){
  int i = blockIdx.x*256 + threadIdx.x;   // 524288 total
  t[i] = pb[i & 127];
}

// ---------------- patch-embed GEMM (im2col, split-K=4, atomic) ----------------
__global__ __launch_bounds__(256) void k_patch(const float* __restrict__ x, const float* __restrict__ pw,
                                               float* __restrict__ t){
  __shared__ __align__(16) float As[16][68];
  __shared__ __align__(16) float Bs[16][68];
  int m0 = blockIdx.x * 64;
  int n0 = blockIdx.y * 64;
  int kbase = blockIdx.z * 1024;
  int tid = threadIdx.x;
  int tm = tid >> 4, tn = tid & 15;
  int lm = tid >> 2, kq = tid & 3;
  float acc[4][4] = {};
  int m = m0 + lm;
  int bb = m >> 9;
  int l  = m & 511;
  int hp = l >> 5, wp = l & 31;
  const float* wbase = pw + (n0 + lm)*4096 + kq*4;
  for (int k0 = kbase; k0 < kbase + 1024; k0 += 16) {
    int k  = k0 + kq*4;
    int c  = k >> 4;
    int i2 = (k >> 2) & 3;
    float4 av = *reinterpret_cast<const float4*>(x + (((bb*256 + c)*64 + hp*4 + i2)*128 + wp*4));
    float4 bv = *reinterpret_cast<const float4*>(wbase + k0);
    As[kq*4+0][lm]=av.x; As[kq*4+1][lm]=av.y; As[kq*4+2][lm]=av.z; As[kq*4+3][lm]=av.w;
    Bs[kq*4+0][lm]=bv.x; Bs[kq*4+1][lm]=bv.y; Bs[kq*4+2][lm]=bv.z; Bs[kq*4+3][lm]=bv.w;
    __syncthreads();
    #pragma unroll
    for (int kk = 0; kk < 16; ++kk) {
      float4 a = *reinterpret_cast<const float4*>(&As[kk][tm*4]);
      float4 b = *reinterpret_cast<const float4*>(&Bs[kk][tn*4]);
      float ar[4] = {a.x,a.y,a.z,a.w};
      float br[4] = {b.x,b.y,b.z,b.w};
      #pragma unroll
      for (int i = 0; i < 4; ++i)
        #pragma unroll
        for (int j = 0; j < 4; ++j)
          acc[i][j] = fmaf(ar[i], br[j], acc[i][j]);
    }
    __syncthreads();
  }
  #pragma unroll
  for (int i = 0; i < 4; ++i)
    #pragma unroll
    for (int j = 0; j < 4; ++j)
      atomicAdd(&t[(m0 + tm*4 + i)*128 + (n0 + tn*4 + j)], acc[i][j]);
}

// ---------------- generic tiled GEMM: C(M,N) = A(M,K) @ W(N,K)^T ----------------
__global__ __launch_bounds__(256) void k_gemm(const float* __restrict__ A, const float* __restrict__ W,
                                              float* __restrict__ C, int M, int N, int K){
  __shared__ __align__(16) float As[16][68];
  __shared__ __align__(16) float Bs[16][68];
  int m0 = blockIdx.x * 64, n0 = blockIdx.y * 64;
  int tid = threadIdx.x;
  int tm = tid >> 4, tn = tid & 15;
  int lm = tid >> 2, kq = tid & 3;
  float acc[4][4] = {};
  const float* Abase = A + (size_t)(m0 + lm)*K + kq*4;
  const float* Wbase = W + (size_t)(n0 + lm)*K + kq*4;
  for (int k0 = 0; k0 < K; k0 += 16) {
    float4 av = *reinterpret_cast<const float4*>(Abase + k0);
    float4 bv = *reinterpret_cast<const float4*>(Wbase + k0);
    As[kq*4+0][lm]=av.x; As[kq*4+1][lm]=av.y; As[kq*4+2][lm]=av.z; As[kq*4+3][lm]=av.w;
    Bs[kq*4+0][lm]=bv.x; Bs[kq*4+1][lm]=bv.y; Bs[kq*4+2][lm]=bv.z; Bs[kq*4+3][lm]=bv.w;
    __syncthreads();
    #pragma unroll
    for (int kk = 0; kk < 16; ++kk) {
      float4 a = *reinterpret_cast<const float4*>(&As[kk][tm*4]);
      float4 b = *reinterpret_cast<const float4*>(&Bs[kk][tn*4]);
      float ar[4] = {a.x,a.y,a.z,a.w};
      float br[4] = {b.x,b.y,b.z,b.w};
      #pragma unroll
      for (int i = 0; i < 4; ++i)
        #pragma unroll
        for (int j = 0; j < 4; ++j)
          acc[i][j] = fmaf(ar[i], br[j], acc[i][j]);
    }
    __syncthreads();
  }
  #pragma unroll
  for (int i = 0; i < 4; ++i) {
    float4 ov = make_float4(acc[i][0], acc[i][1], acc[i][2], acc[i][3]);
    *reinterpret_cast<float4*>(C + (size_t)(m0 + tm*4 + i)*N + n0 + tn*4) = ov;
  }
}

// ---------------- causal conv1d (DC=4) + silu ----------------
__global__ __launch_bounds__(256) void k_conv1d(const float* __restrict__ xz, const float* __restrict__ w,
                                                const float* __restrict__ bias, float* __restrict__ xc){
  int idx = blockIdx.x*256 + threadIdx.x;   // over 8*512*256
  int d = idx & 255;
  int l = (idx >> 8) & 511;
  int bb = idx >> 17;
  const float* base = xz + (size_t)bb*512*512 + d;   // xin = xz[...,:256]
  float s = bias[d];
  #pragma unroll
  for (int k = 0; k < 4; ++k) {
    int ls = l - 3 + k;
    if (ls >= 0) s = fmaf(base[(size_t)ls*512], w[d*4+k], s);
  }
  xc[idx] = s / (1.f + __expf(-s));
}

// ---------------- x_proj (40 outs) + dt_proj + softplus ----------------
__global__ __launch_bounds__(256) void k_xproj(const float* __restrict__ xc, const float* __restrict__ xpw,
                                               const float* __restrict__ dtw, const float* __restrict__ dtb,
                                               float* __restrict__ dbl, float* __restrict__ dt){
  __shared__ __align__(16) float sxc[256];
  __shared__ float sdbl[40];
  int bl = blockIdx.x;         // (b,l) 0..4095
  int tid = threadIdx.x;
  sxc[tid] = xc[(size_t)bl*256 + tid];
  __syncthreads();
  if (tid < 40) {
    const float4* wr = reinterpret_cast<const float4*>(xpw + tid*256);
    const float4* xr = reinterpret_cast<const float4*>(sxc);
    float s = 0.f;
    #pragma unroll 8
    for (int i = 0; i < 64; ++i) {
      float4 w = wr[i], xv = xr[i];
      s += w.x*xv.x + w.y*xv.y + w.z*xv.z + w.w*xv.w;
    }
    sdbl[tid] = s;
    dbl[(size_t)bl*40 + tid] = s;
  }
  __syncthreads();
  float s = dtb[tid];
  const float* wr = dtw + tid*8;
  #pragma unroll
  for (int r = 0; r < 8; ++r) s = fmaf(sdbl[r], wr[r], s);
  float sp = (s > 20.f) ? s : log1pf(__expf(s));
  dt[(size_t)bl*256 + tid] = sp;
}

// ---------------- chunk-parallel selective scan (LDS-preloaded) ----------------
__global__ __launch_bounds__(256) void k_scanA(const float* __restrict__ dt, const float* __restrict__ dbl,
                                               const float* __restrict__ xc, const float* __restrict__ A_log,
                                               float* __restrict__ aprod, float* __restrict__ hend){
  __shared__ float sdt[32][16], sxc[32][16], sB[32][16];
  int tid = threadIdx.x;
  int bg = blockIdx.x;            // b*16 + dgrp
  int ch = blockIdx.y;
  int bb = bg >> 4, dgrp = bg & 15;
  int l0 = ch*32;
  #pragma unroll
  for (int it = 0; it < 2; ++it) {
    int idx = it*256 + tid;       // 0..511
    int t = idx >> 4, dd = idx & 15;
    int base = bb*512 + l0 + t;
    sdt[t][dd] = dt[(size_t)base*256 + dgrp*16 + dd];
    sxc[t][dd] = xc[(size_t)base*256 + dgrp*16 + dd];
    sB [t][dd] = dbl[(size_t)base*40 + 8 + dd];
  }
  __syncthreads();
  int n = tid & 15, dloc = tid >> 4;
  float Ac = -__expf(A_log[(dgrp*16 + dloc)*16 + n]);
  float a = 1.f, h = 0.f;
  #pragma unroll
  for (int t = 0; t < 32; ++t) {
    float dtv = sdt[t][dloc], xcv = sxc[t][dloc], Bv = sB[t][n];
    float dA = __expf(dtv*Ac);
    h = fmaf(dA, h, dtv*Bv*xcv);
    a *= dA;
  }
  aprod[(size_t)(bg*16 + ch)*256 + tid] = a;
  hend [(size_t)(bg*16 + ch)*256 + tid] = h;
}

__global__ __launch_bounds__(256) void k_scanB(const float* __restrict__ aprod, const float* __restrict__ hend,
                                               float* __restrict__ hstart){
  int tid = threadIdx.x;
  int bg = blockIdx.x;
  float hs = 0.f;
  #pragma unroll
  for (int ch = 0; ch < 16; ++ch) {
    size_t idx = (size_t)(bg*16 + ch)*256 + tid;
    hstart[idx] = hs;
    hs = fmaf(aprod[idx], hs, hend[idx]);
  }
}

__global__ __launch_bounds__(256) void k_scanC(const float* __restrict__ dt, const float* __restrict__ dbl,
                                               const float* __restrict__ xc, const float* __restrict__ xz,
                                               const float* __restrict__ A_log, const float* __restrict__ Dp,
                                               const float* __restrict__ hstart, float* __restrict__ y){
  __shared__ float sdt[32][16], sxc[32][16], sB[32][16], sC[32][16], sz[32][16];
  int tid = threadIdx.x;
  int bg = blockIdx.x;
  int ch = blockIdx.y;
  int bb = bg >> 4, dgrp = bg & 15;
  int l0 = ch*32;
  #pragma unroll
  for (int it = 0; it < 2; ++it) {
    int idx = it*256 + tid;
    int t = idx >> 4, dd = idx & 15;
    int base = bb*512 + l0 + t;
    sdt[t][dd] = dt[(size_t)base*256 + dgrp*16 + dd];
    sxc[t][dd] = xc[(size_t)base*256 + dgrp*16 + dd];
    sB [t][dd] = dbl[(size_t)base*40 + 8  + dd];
    sC [t][dd] = dbl[(size_t)base*40 + 24 + dd];
    sz [t][dd] = xz[(size_t)base*512 + 256 + dgrp*16 + dd];
  }
  __syncthreads();
  int n = tid & 15, dloc = tid >> 4;
  int d = dgrp*16 + dloc;
  float Ac = -__expf(A_log[d*16 + n]);
  float Dv = Dp[d];
  float h = hstart[(size_t)(bg*16 + ch)*256 + tid];
  #pragma unroll 4
  for (int t = 0; t < 32; ++t) {
    float dtv = sdt[t][dloc], xcv = sxc[t][dloc];
    float Bv = sB[t][n], Cv = sC[t][n];
    float dA = __expf(dtv*Ac);
    h = fmaf(dA, h, dtv*Bv*xcv);
    float yp = h*Cv;
    yp += __shfl_xor(yp, 1, 16);
    yp += __shfl_xor(yp, 2, 16);
    yp += __shfl_xor(yp, 4, 16);
    yp += __shfl_xor(yp, 8, 16);
    if (n == 0) {
      float zv = sz[t][dloc];
      y[(size_t)(bb*512 + l0 + t)*256 + d] = (yp + Dv*xcv) * (zv / (1.f + __expf(-zv)));
    }
  }
}

// ---------------- lin via bf16 MFMA + bias + pixel-shuffle -> padded bf16 ubf ----------------
__global__ __launch_bounds__(512) void k_linm(const ushort* __restrict__ ybfT, const ushort* __restrict__ lwbf,
                                              const float* __restrict__ lb, ushort* __restrict__ ubf){
  __shared__ ushort As[128*80];
  __shared__ ushort Bs[128*80];
  int m0 = blockIdx.x * 128;
  int b  = blockIdx.y;
  int tid = threadIdx.x;
  int l = tid & 63, wv = tid >> 6;
  int wm = wv & 3, we = wv >> 2;
  int lj = l & 15, lg = l >> 4;
  f32x4 acc[4][2];
  #pragma unroll
  for (int fo = 0; fo < 4; ++fo)
    #pragma unroll
    for (int fj = 0; fj < 2; ++fj)
      acc[fo][fj] = (f32x4){0.f,0.f,0.f,0.f};

  for (int k0 = 0; k0 < 512; k0 += 64) {
    __syncthreads();
    #pragma unroll
    for (int it = 0; it < 2; ++it) {
      int flat = it*512 + tid;        // 0..1023
      int e = flat >> 3, kc8 = flat & 7;
      *reinterpret_cast<uint4*>(&As[e*80 + kc8*8]) =
        *reinterpret_cast<const uint4*>(ybfT + ((size_t)b*128 + e)*512 + k0 + kc8*8);
      *reinterpret_cast<uint4*>(&Bs[e*80 + kc8*8]) =
        *reinterpret_cast<const uint4*>(lwbf + (size_t)(m0 + e)*512 + k0 + kc8*8);
    }
    __syncthreads();
    #pragma unroll
    for (int kc = 0; kc < 2; ++kc) {
      short8v af[4], bq[2];
      #pragma unroll
      for (int fo = 0; fo < 4; ++fo)
        af[fo] = *reinterpret_cast<const short8v*>(&As[(we*64 + fo*16 + lj)*80 + kc*32 + lg*8]);
      #pragma unroll
      for (int fj = 0; fj < 2; ++fj)
        bq[fj] = *reinterpret_cast<const short8v*>(&Bs[(wm*32 + fj*16 + lj)*80 + kc*32 + lg*8]);
      #pragma unroll
      for (int fo = 0; fo < 4; ++fo)
        #pragma unroll
        for (int fj = 0; fj < 2; ++fj)
          acc[fo][fj] = __builtin_amdgcn_mfma_f32_16x16x32_bf16(af[fo], bq[fj], acc[fo][fj], 0, 0, 0);
    }
  }
  #pragma unroll
  for (int fj = 0; fj < 2; ++fj) {
    int m = m0 + wm*32 + fj*16 + lj;
    float bias = lb[m];
    int hh = ((m >> 9) << 2) + ((m >> 2) & 3);
    int ww = (((m >> 4) & 31) << 2) + (m & 3);
    #pragma unroll
    for (int fo = 0; fo < 4; ++fo) {
      int eg = we*2 + (fo >> 1);
      int e5 = ((fo & 1) << 4) + (lg << 2);
      f32x4 a = acc[fo][fj];
      uint2 u;
      u.x = (uint)bf16rne(a.x + bias) | ((uint)bf16rne(a.y + bias) << 16);
      u.y = (uint)bf16rne(a.z + bias) | ((uint)bf16rne(a.w + bias) << 16);
      *reinterpret_cast<uint2*>(ubf + ((((size_t)b*4 + eg)*66 + hh + 1)*130 + ww + 1)*32 + e5) = u;
    }
  }
}

// ---------------- conv3x3 via bf16 MFMA implicit GEMM (64-o blocks, 2 blocks/CU) ----------------
// grid (h2=32, bz=64: bb*8+ocg). 256 thr = 4 waves: hr = wv>>1, wseg = (wv&1)*64.
__global__ __launch_bounds__(256) void k_conv3m(const ushort* __restrict__ ubf, const ushort* __restrict__ wbf,
                                                const float* __restrict__ cb, float* __restrict__ out){
  extern __shared__ ushort smu[];
  ushort* wlds = smu;           // [9 tap][64 o][32 e] = 18432 ushorts
  ushort* ubuf = smu + 18432;   // [4 rows][130 w'][32 e] stride 4160 = 16640 ushorts
  int h2 = blockIdx.x;          // 0..31
  int bz = blockIdx.y;
  int bb = bz >> 3, ocg = bz & 7;   // ocg = oc*2 + oh (64-o group)
  int tid = threadIdx.x;
  int l   = tid & 63;
  int wv  = tid >> 6;
  int hr  = wv >> 1;            // row within pair
  int wseg = (wv & 1) * 64;     // w half
  int lj = l & 15, lg = l >> 4;

  f32x4 acc[4][4];
  #pragma unroll
  for (int i = 0; i < 4; ++i)
    #pragma unroll
    for (int j = 0; j < 4; ++j)
      acc[i][j] = (f32x4){0.f, 0.f, 0.f, 0.f};

  for (int ec = 0; ec < 4; ++ec) {
    __syncthreads();
    const uint4* sA = reinterpret_cast<const uint4*>(wbf) + (size_t)(ocg*4 + ec)*2304;
    uint4* dA = reinterpret_cast<uint4*>(wlds);
    for (int i = tid; i < 2304; i += 256) dA[i] = sA[i];
    const uint4* sB = reinterpret_cast<const uint4*>(ubf) + ((size_t)(bb*4 + ec)*66 + 2*h2)*520;
    uint4* dB = reinterpret_cast<uint4*>(ubuf);
    for (int i = tid; i < 2080; i += 256) dB[i] = sB[i];
    __syncthreads();

    #pragma unroll
    for (int ki = 0; ki < 3; ++ki) {
      const ushort* brow = ubuf + (hr + ki)*4160 + lg*8;
      #pragma unroll
      for (int kj = 0; kj < 3; ++kj) {
        const ushort* wrow = wlds + (ki*3 + kj)*2048 + lj*32 + lg*8;
        short8v af[4], bfr[4];
        #pragma unroll
        for (int f = 0; f < 4; ++f)
          af[f] = *reinterpret_cast<const short8v*>(wrow + f*512);
        #pragma unroll
        for (int f = 0; f < 4; ++f)
          bfr[f] = *reinterpret_cast<const short8v*>(brow + (wseg + f*16 + lj + kj)*32);
        #pragma unroll
        for (int fo = 0; fo < 4; ++fo)
          #pragma unroll
          for (int fj = 0; fj < 4; ++fj)
            acc[fo][fj] = __builtin_amdgcn_mfma_f32_16x16x32_bf16(af[fo], bfr[fj], acc[fo][fj], 0, 0, 0);
      }
    }
  }

  int row = h2*2 + hr;              // pre-shuffle output row, 0..63
  #pragma unroll
  for (int fo = 0; fo < 4; ++fo) {
    int obase = ocg*64 + fo*16 + lg*4;   // + q
    int g = obase >> 2;
    float b0 = cb[obase], b1 = cb[obase+1], b2 = cb[obase+2], b3 = cb[obase+3];
    size_t rbase0 = (((size_t)bb*128 + g)*128 + 2*row)*256;
    size_t rbase1 = rbase0 + 256;
    #pragma unroll
    for (int fj = 0; fj < 4; ++fj) {
      int w = wseg + fj*16 + lj;
      f32x4 a = acc[fo][fj];
      float2 v0 = make_float2(geluf(a.x + b0), geluf(a.y + b1));
      float2 v1 = make_float2(geluf(a.z + b2), geluf(a.w + b3));
      *reinterpret_cast<float2*>(out + rbase0 + 2*w) = v0;
      *reinterpret_cast<float2*>(out + rbase1 + 2*w) = v1;
    }
  }
}

// ---------------- FFN via bf16 MFMA: out = c + W2 @ gelu(W1 @ c + b1) + b2 (write-only epilogue) ----
// cT holds c tile for the whole kernel (residual read from LDS); f1 overwrites W1's slot; W2 from global.
__global__ __launch_bounds__(512) void k_ffnm(const ushort* __restrict__ wpad, const float* __restrict__ b1,
                                              const float* __restrict__ b2, float* __restrict__ io){
  extern __shared__ ushort sm[];
  ushort* cT = sm;              // [128 px][136] bf16 c tile (survives to epilogue)
  ushort* wl = sm + 128*136;    // [128][136] bf16: W1, then f1[px][e]
  int pix0 = blockIdx.x * 128;
  int bb = pix0 >> 15;
  int hw0 = pix0 & 32767;
  int tid = threadIdx.x;
  int l = tid & 63, wv = tid >> 6;
  int wc = wv >> 2, wp = wv & 3;
  int lj = l & 15, lg = l >> 4;
  int r = tid & 1, hpair = tid >> 1;      // for c staging
  const float* cbase = io + (size_t)bb*128*HW2 + hw0;

  // stage c transposed to bf16 [px][ch] via paired float2 + shfl_xor(1)
  for (int it = 0; it < 16; ++it) {
    int flat = it*256 + hpair;            // 0..4095
    int pp = flat & 63;                   // px-pair
    int cpair = flat >> 6;                // ch-pair
    int ch = cpair*2 + r;
    float2 v = *reinterpret_cast<const float2*>(cbase + (size_t)ch*HW2 + pp*2);
    float oa = __shfl_xor(v.x, 1);
    float ob = __shfl_xor(v.y, 1);
    ushort lo = r ? bf16rne(ob) : bf16rne(v.x);
    ushort hi = r ? bf16rne(v.y) : bf16rne(oa);
    *reinterpret_cast<uint*>(&cT[(pp*2 + r)*136 + cpair*2]) = (uint)lo | ((uint)hi << 16);
  }
  // stage W1 (pre-padded bf16 [128][136])
  {
    const uint4* src = reinterpret_cast<const uint4*>(wpad);
    uint4* dst = reinterpret_cast<uint4*>(wl);
    for (int i = tid; i < 2176; i += 512) dst[i] = src[i];
  }
  __syncthreads();

  f32x4 acc[4][2];
  #pragma unroll
  for (int fo = 0; fo < 4; ++fo)
    #pragma unroll
    for (int fj = 0; fj < 2; ++fj)
      acc[fo][fj] = (f32x4){0.f,0.f,0.f,0.f};

  // GEMM1: f1[e][px] = sum_c W1[e][c] * c[c][px]
  #pragma unroll
  for (int kc = 0; kc < 4; ++kc) {
    short8v af[4], bq[2];
    #pragma unroll
    for (int fo = 0; fo < 4; ++fo)
      af[fo] = *reinterpret_cast<const short8v*>(&wl[(wc*64 + fo*16 + lj)*136 + kc*32 + lg*8]);
    #pragma unroll
    for (int fj = 0; fj < 2; ++fj)
      bq[fj] = *reinterpret_cast<const short8v*>(&cT[(wp*32 + fj*16 + lj)*136 + kc*32 + lg*8]);
    #pragma unroll
    for (int fo = 0; fo < 4; ++fo)
      #pragma unroll
      for (int fj = 0; fj < 2; ++fj)
        acc[fo][fj] = __builtin_amdgcn_mfma_f32_16x16x32_bf16(af[fo], bq[fj], acc[fo][fj], 0, 0, 0);
  }
  __syncthreads();

  // prefetch W2 (kc=0) from global; f1 = gelu(acc + b1) -> wl (over W1)
  const ushort* w2g = wpad + 17408;
  short8v a2[4], a2n[4];
  #pragma unroll
  for (int fo = 0; fo < 4; ++fo)
    a2[fo] = *reinterpret_cast<const short8v*>(w2g + (size_t)(wc*64 + fo*16 + lj)*136 + lg*8);

  #pragma unroll
  for (int fo = 0; fo < 4; ++fo) {
    int ch0 = wc*64 + fo*16 + lg*4;
    float c0 = b1[ch0], c1 = b1[ch0+1], c2 = b1[ch0+2], c3 = b1[ch0+3];
    #pragma unroll
    for (int fj = 0; fj < 2; ++fj) {
      int px = wp*32 + fj*16 + lj;
      f32x4 a = acc[fo][fj];
      uint2 u;
      u.x = (uint)bf16rne(geluf(a.x + c0)) | ((uint)bf16rne(geluf(a.y + c1)) << 16);
      u.y = (uint)bf16rne(geluf(a.z + c2)) | ((uint)bf16rne(geluf(a.w + c3)) << 16);
      *reinterpret_cast<uint2*>(&wl[px*136 + ch0]) = u;
    }
  }
  __syncthreads();

  #pragma unroll
  for (int fo = 0; fo < 4; ++fo)
    #pragma unroll
    for (int fj = 0; fj < 2; ++fj)
      acc[fo][fj] = (f32x4){0.f,0.f,0.f,0.f};

  // GEMM2: f2[ch][px] = sum_e W2[ch][e] * f1[e][px]; A from global (pipelined), B from wl
  #pragma unroll
  for (int kc = 0; kc < 4; ++kc) {
    if (kc < 3) {
      #pragma unroll
      for (int fo = 0; fo < 4; ++fo)
        a2n[fo] = *reinterpret_cast<const short8v*>(w2g + (size_t)(wc*64 + fo*16 + lj)*136 + (kc+1)*32 + lg*8);
    }
    short8v bq[2];
    #pragma unroll
    for (int fj = 0; fj < 2; ++fj)
      bq[fj] = *reinterpret_cast<const short8v*>(&wl[(wp*32 + fj*16 + lj)*136 + kc*32 + lg*8]);
    #pragma unroll
    for (int fo = 0; fo < 4; ++fo)
      #pragma unroll
      for (int fj = 0; fj < 2; ++fj)
        acc[fo][fj] = __builtin_amdgcn_mfma_f32_16x16x32_bf16(a2[fo], bq[fj], acc[fo][fj], 0, 0, 0);
    #pragma unroll
    for (int fo = 0; fo < 4; ++fo) a2[fo] = a2n[fo];
  }

  // epilogue: out = c (from LDS, bf16) + f2 + b2 — pure write, no RMW
  #pragma unroll
  for (int fo = 0; fo < 4; ++fo) {
    int ch0 = wc*64 + fo*16 + lg*4;
    float d0 = b2[ch0], d1 = b2[ch0+1], d2 = b2[ch0+2], d3 = b2[ch0+3];
    #pragma unroll
    for (int fj = 0; fj < 2; ++fj) {
      int px = wp*32 + fj*16 + lj;
      f32x4 a = acc[fo][fj];
      uint2 cu = *reinterpret_cast<const uint2*>(&cT[px*136 + ch0]);
      float cv0 = __uint_as_float((cu.x & 0xffffu) << 16);
      float cv1 = __uint_as_float(cu.x & 0xffff0000u);
      float cv2 = __uint_as_float((cu.y & 0xffffu) << 16);
      float cv3 = __uint_as_float(cu.y & 0xffff0000u);
      float* p0 = io + (size_t)bb*128*HW2 + (size_t)ch0*HW2 + hw0 + px;
      p0[0]             = cv0 + a.x + d0;
      p0[HW2]           = cv1 + a.y + d1;
      p0[2*HW2]         = cv2 + a.z + d2;
      p0[3*(size_t)HW2] = cv3 + a.w + d3;
    }
  }
}

extern "C" void kernel_launch(void* const* d_in, const int* in_sizes, int n_in,
                              void* d_out, int out_size, void* d_ws, size_t ws_size,
                              hipStream_t stream) {
  const float* x          = (const float*)d_in[0];
  const float* patch_w    = (const float*)d_in[1];
  const float* patch_b    = (const float*)d_in[2];
  const float* in_proj_w  = (const float*)d_in[3];
  const float* conv1d_w   = (const float*)d_in[4];
  const float* conv1d_b   = (const float*)d_in[5];
  const float* x_proj_w   = (const float*)d_in[6];
  const float* dt_proj_w  = (const float*)d_in[7];
  const float* dt_proj_b  = (const float*)d_in[8];
  const float* A_log      = (const float*)d_in[9];
  const float* D_param    = (const float*)d_in[10];
  const float* out_proj_w = (const float*)d_in[11];
  const float* lin_w      = (const float*)d_in[12];
  const float* lin_b      = (const float*)d_in[13];
  const float* conv_w     = (const float*)d_in[14];
  const float* conv_b     = (const float*)d_in[15];
  const float* ffn_w1     = (const float*)d_in[16];
  const float* ffn_b1     = (const float*)d_in[17];
  const float* ffn_w2     = (const float*)d_in[18];
  const float* ffn_b2     = (const float*)d_in[19];
  float* out = (float*)d_out;
  float* ws  = (float*)d_ws;

  float* t    = ws;                 // 524288   (B*N, E)
  float* xz   = t    + 524288;      // 2097152  (B*N, 512)
  float* xc   = xz   + 2097152;     // 1048576  (B*N, 256)
  float* dbl  = xc   + 1048576;     // 163840   (B*N, 40)
  float* dt   = dbl  + 163840;      // 1048576  (B*N, 256)
  float* y    = dt   + 1048576;     // 1048576  (B*N, 256)
  float* yo   = y    + 1048576;     // 524288   (B*N, 128)
  float* apr  = yo   + 524288;      // 524288
  float* hend = apr  + 524288;      // 524288
  float* hst  = hend + 524288;      // 524288
  ushort* ubf  = (ushort*)(hst + 524288); // 10982400 bf16: [8][4][66][130][32]
  ushort* wbf  = ubf + 10982400;          // 589824 bf16:   [8 ocg][4 ec][9][64][32]
  ushort* wpad = wbf + 589824;            // 34816 bf16:    [2][128][136]
  ushort* lwbf = wpad + 34816;            // 4194304 bf16:  [8192][512]
  ushort* ybfT = lwbf + 4194304;          // 524288 bf16:   [8][128][512]

  k_zero4 <<<dim3(5363), dim3(256), 0, stream>>>((uint4*)ubf, 1372800);
  k_wprep <<<dim3(2304), dim3(256), 0, stream>>>(conv_w, wbf);
  k_wffn  <<<dim3(136), dim3(256), 0, stream>>>(ffn_w1, ffn_w2, wpad);
  k_wlin  <<<dim3(4096), dim3(256), 0, stream>>>(lin_w, lwbf);
  k_init_t<<<dim3(2048), dim3(256), 0, stream>>>(t, patch_b);
  k_patch <<<dim3(64, 2, 4), dim3(256), 0, stream>>>(x, patch_w, t);
  k_gemm  <<<dim3(64, 8), dim3(256), 0, stream>>>(t, in_proj_w, xz, 4096, 512, 128);
  k_conv1d<<<dim3(4096), dim3(256), 0, stream>>>(xz, conv1d_w, conv1d_b, xc);
  k_xproj <<<dim3(4096), dim3(256), 0, stream>>>(xc, x_proj_w, dt_proj_w, dt_proj_b, dbl, dt);
  k_scanA <<<dim3(128, 16), dim3(256), 0, stream>>>(dt, dbl, xc, A_log, apr, hend);
  k_scanB <<<dim3(128), dim3(256), 0, stream>>>(apr, hend, hst);
  k_scanC <<<dim3(128, 16), dim3(256), 0, stream>>>(dt, dbl, xc, xz, A_log, D_param, hst, y);
  k_gemm  <<<dim3(64, 2), dim3(256), 0, stream>>>(y, out_proj_w, yo, 4096, 128, 256);
  k_ytr   <<<dim3(8, 16), dim3(256), 0, stream>>>(yo, ybfT);
  k_linm  <<<dim3(64, 8), dim3(512), 0, stream>>>(ybfT, lwbf, lin_b, ubf);
  k_conv3m<<<dim3(32, 64), dim3(256), (size_t)35072*sizeof(ushort), stream>>>(ubf, wbf, conv_b, out);
  k_ffnm  <<<dim3(2048), dim3(512), (size_t)(2*128*136)*sizeof(ushort), stream>>>(wpad, ffn_b1, ffn_b2, out);
}

// Round 6
// 367.447 us; speedup vs baseline: 7.9252x; 1.1397x over previous
//
#include <hip/hip_runtime.h>
#include <hip/hip_bf16.h>

// Shapes (fixed): B=8,C=256,H=64,W=128,P=4,E=DM=128,N=512,DI=256,DS=16,DC=4,DR=8,NG=128,S=2
#define HW2 32768   // 128*256 output spatial per (b,channel)

typedef __attribute__((ext_vector_type(8))) short short8v;
typedef __attribute__((ext_vector_type(4))) float f32x4;

__device__ __forceinline__ float siluf(float x){ return x / (1.f + __expf(-x)); }
__device__ __forceinline__ float geluf(float v){
  float t = 0.7978845608028654f * fmaf(0.044715f*v*v, v, v);
  t = fminf(fmaxf(t, -15.f), 15.f);
  float e = __expf(2.f*t);
  return 0.5f*v*(1.f + (e-1.f)/(e+1.f));
}
__device__ __forceinline__ ushort bf16rne(float f){
  unsigned u = __float_as_uint(f);
  unsigned r = (u + 0x7fffu + ((u >> 16) & 1u)) >> 16;
  return (ushort)r;
}
__device__ __forceinline__ float bf2f(ushort u){ return __uint_as_float(((unsigned)u) << 16); }
__device__ __forceinline__ void split2(float v, ushort& h, ushort& lo){
  h = bf16rne(v);
  lo = bf16rne(v - bf2f(h));
}

// ---------------- zero-fill (uint4 granularity) ----------------
__global__ __launch_bounds__(256) void k_zero4(uint4* __restrict__ p, int n){
  int i = blockIdx.x*256 + threadIdx.x;
  if (i < n) p[i] = make_uint4(0,0,0,0);
}

// ---------------- conv weights fp32 -> bf16 FRAGMENT-LINEAR: [(ocg*4+ec)][tap9][f4][lane64][8e] --------
// lane l of frag f holds o = ocg*64 + f*16 + (l&15), e = ec*32 + (l>>4)*8 + j  (conflict-free ds_read)
__global__ __launch_bounds__(256) void k_wprep(const float* __restrict__ cw, ushort* __restrict__ wbf){
  int idx = blockIdx.x*256 + threadIdx.x;   // 589824
  int j    = idx & 7;
  int lane = (idx >> 3) & 63;
  int f    = (idx >> 9) & 3;
  int tap  = (idx >> 11) % 9;
  int rest = idx / 18432;                   // ocg*4 + ec, 0..31
  int ec = rest & 3, ocg = rest >> 2;
  int o = ocg*64 + f*16 + (lane & 15);
  int e = ec*32 + (lane >> 4)*8 + j;
  float v = cw[((size_t)o*128 + e)*9 + tap];
  wbf[idx] = bf16rne(v);
}

// ---------------- FFN weights fp32 -> bf16 padded [2][128][136] ----------------
__global__ __launch_bounds__(256) void k_wffn(const float* __restrict__ w1, const float* __restrict__ w2,
                                              ushort* __restrict__ wpad){
  int idx = blockIdx.x*256 + threadIdx.x;   // 34816
  int which = idx / 17408;
  int rem = idx - which*17408;
  int e = rem / 136, k = rem - e*136;
  const float* s = which ? w2 : w1;
  wpad[idx] = (k < 128) ? bf16rne(s[e*128 + k]) : (ushort)0;
}

// ---------------- lin weights fp32 -> bf16 (same [m][n] layout) ----------------
__global__ __launch_bounds__(256) void k_wlin(const float* __restrict__ lw, ushort* __restrict__ lwbf){
  int i = blockIdx.x*256 + threadIdx.x;     // 1048576 float4s
  float4 v = reinterpret_cast<const float4*>(lw)[i];
  uint2 u;
  u.x = (uint)bf16rne(v.x) | ((uint)bf16rne(v.y) << 16);
  u.y = (uint)bf16rne(v.z) | ((uint)bf16rne(v.w) << 16);
  reinterpret_cast<uint2*>(lwbf)[i] = u;
}

// ---------------- yo (4096 x 128 fp32) -> ybfT [b][e128][n512] bf16 ----------------
__global__ __launch_bounds__(256) void k_ytr(const float* __restrict__ yo, ushort* __restrict__ ybfT){
  __shared__ float tile[32][132];
  int b = blockIdx.x, n0 = blockIdx.y*32;
  int tid = threadIdx.x;
  for (int it = 0; it < 16; ++it) {
    int idx = it*256 + tid;
    int row = idx >> 7, e = idx & 127;
    tile[row][e] = yo[((size_t)(b*512 + n0 + row))*128 + e];
  }
  __syncthreads();
  int e = tid >> 1, half = tid & 1;
  uint* dst = reinterpret_cast<uint*>(ybfT + ((size_t)b*128 + e)*512 + n0 + half*16);
  #pragma unroll
  for (int j = 0; j < 8; ++j) {
    int n = half*16 + j*2;
    dst[j] = (uint)bf16rne(tile[n][e]) | ((uint)bf16rne(tile[n+1][e]) << 16);
  }
}

// ---------------- patch embed via bf16x3 MFMA, split-K=8 -> part[ks][4096][128] ----------------
// t[m][e] = sum_k x_im2col(m,k) * pw[e][k]; hi/lo split keeps fp32-level accuracy.
__global__ __launch_bounds__(256) void k_patchm(const float* __restrict__ x, const float* __restrict__ pw,
                                                float* __restrict__ part){
  __shared__ ushort Ah[4096], Al[4096], Wh[4096], Wl[4096];  // frag-linear per 32-k chunk
  int m0 = blockIdx.x * 128;
  int ks = blockIdx.y;
  int tid = threadIdx.x;
  int l = tid & 63, wv = tid >> 6;
  int wm = wv >> 1, we = wv & 1;
  int lj = l & 15, lg = l >> 4;
  f32x4 acc[4][4];
  #pragma unroll
  for (int a = 0; a < 4; ++a)
    #pragma unroll
    for (int b = 0; b < 4; ++b)
      acc[a][b] = (f32x4){0.f,0.f,0.f,0.f};
  int kbase = ks * 512;

  for (int it = 0; it < 16; ++it) {
    int k0 = kbase + it*32;
    __syncthreads();
    // stage A (x im2col rows): flat -> row = flat&127, kk4 = flat>>7 (coalesced: 64 lanes = 64 consecutive wp)
    #pragma unroll
    for (int q = 0; q < 4; ++q) {
      int flat = q*256 + tid;
      int row = flat & 127, kk4 = flat >> 7;
      int m = m0 + row;
      int bb = m >> 9, ll = m & 511;
      int hp = ll >> 5, wp = ll & 31;
      int k = k0 + kk4*4;
      int c = k >> 4, i2 = (k >> 2) & 3;
      float4 v = *reinterpret_cast<const float4*>(x + (((bb*256 + c)*64 + hp*4 + i2)*128 + wp*4));
      ushort h0,h1,h2,h3,q0,q1,q2,q3;
      split2(v.x,h0,q0); split2(v.y,h1,q1); split2(v.z,h2,q2); split2(v.w,h3,q3);
      uint2 uh, ul;
      uh.x = (uint)h0 | ((uint)h1 << 16); uh.y = (uint)h2 | ((uint)h3 << 16);
      ul.x = (uint)q0 | ((uint)q1 << 16); ul.y = (uint)q2 | ((uint)q3 << 16);
      int lane = ((kk4 >> 1) << 4) | (row & 15);
      int dst = ((row >> 4)*64 + lane)*8 + (kk4 & 1)*4;
      *reinterpret_cast<uint2*>(Ah + dst) = uh;
      *reinterpret_cast<uint2*>(Al + dst) = ul;
    }
    // stage W (pw): flat -> e = flat>>3, kk4 = flat&7 (8 threads cover 128B contiguous per e)
    #pragma unroll
    for (int q = 0; q < 4; ++q) {
      int flat = q*256 + tid;
      int e = flat >> 3, kk4 = flat & 7;
      float4 v = *reinterpret_cast<const float4*>(pw + (size_t)e*4096 + k0 + kk4*4);
      ushort h0,h1,h2,h3,q0,q1,q2,q3;
      split2(v.x,h0,q0); split2(v.y,h1,q1); split2(v.z,h2,q2); split2(v.w,h3,q3);
      uint2 uh, ul;
      uh.x = (uint)h0 | ((uint)h1 << 16); uh.y = (uint)h2 | ((uint)h3 << 16);
      ul.x = (uint)q0 | ((uint)q1 << 16); ul.y = (uint)q2 | ((uint)q3 << 16);
      int lane = ((kk4 >> 1) << 4) | (e & 15);
      int dst = ((e >> 4)*64 + lane)*8 + (kk4 & 1)*4;
      *reinterpret_cast<uint2*>(Wh + dst) = uh;
      *reinterpret_cast<uint2*>(Wl + dst) = ul;
    }
    __syncthreads();

    short8v ah[4], al_[4], wh[4], wl_[4];
    #pragma unroll
    for (int f = 0; f < 4; ++f) {
      ah[f]  = *reinterpret_cast<const short8v*>(Ah + ((wm*4 + f)*64 + l)*8);
      al_[f] = *reinterpret_cast<const short8v*>(Al + ((wm*4 + f)*64 + l)*8);
      wh[f]  = *reinterpret_cast<const short8v*>(Wh + ((we*4 + f)*64 + l)*8);
      wl_[f] = *reinterpret_cast<const short8v*>(Wl + ((we*4 + f)*64 + l)*8);
    }
    #pragma unroll
    for (int fo = 0; fo < 4; ++fo)
      #pragma unroll
      for (int fj = 0; fj < 4; ++fj) {
        acc[fo][fj] = __builtin_amdgcn_mfma_f32_16x16x32_bf16(ah[fo],  wh[fj],  acc[fo][fj], 0, 0, 0);
        acc[fo][fj] = __builtin_amdgcn_mfma_f32_16x16x32_bf16(ah[fo],  wl_[fj], acc[fo][fj], 0, 0, 0);
        acc[fo][fj] = __builtin_amdgcn_mfma_f32_16x16x32_bf16(al_[fo], wh[fj],  acc[fo][fj], 0, 0, 0);
      }
  }
  // epilogue: D row = m_local (fo*16 + lg*4 + reg), col = e (fj*16 + lj)
  float* pb = part + (size_t)ks*524288;
  #pragma unroll
  for (int fo = 0; fo < 4; ++fo) {
    int m = m0 + wm*64 + fo*16 + lg*4;
    #pragma unroll
    for (int fj = 0; fj < 4; ++fj) {
      int e = we*64 + fj*16 + lj;
      f32x4 a = acc[fo][fj];
      pb[(size_t)(m+0)*128 + e] = a.x;
      pb[(size_t)(m+1)*128 + e] = a.y;
      pb[(size_t)(m+2)*128 + e] = a.z;
      pb[(size_t)(m+3)*128 + e] = a.w;
    }
  }
}

// ---------------- reduce 8 K-split partials + bias -> t ----------------
__global__ __launch_bounds__(256) void k_tred(const float* __restrict__ part, const float* __restrict__ pb,
                                              float* __restrict__ t){
  int i = blockIdx.x*256 + threadIdx.x;    // 131072 float4s
  const float4* p4 = reinterpret_cast<const float4*>(part);
  float4 s = reinterpret_cast<const float4*>(pb)[i & 31];
  #pragma unroll
  for (int ks = 0; ks < 8; ++ks) {
    float4 v = p4[(size_t)ks*131072 + i];
    s.x += v.x; s.y += v.y; s.z += v.z; s.w += v.w;
  }
  reinterpret_cast<float4*>(t)[i] = s;
}

// ---------------- generic tiled GEMM: C(M,N) = A(M,K) @ W(N,K)^T ----------------
__global__ __launch_bounds__(256) void k_gemm(const float* __restrict__ A, const float* __restrict__ W,
                                              float* __restrict__ C, int M, int N, int K){
  __shared__ __align__(16) float As[16][68];
  __shared__ __align__(16) float Bs[16][68];
  int m0 = blockIdx.x * 64, n0 = blockIdx.y * 64;
  int tid = threadIdx.x;
  int tm = tid >> 4, tn = tid & 15;
  int lm = tid >> 2, kq = tid & 3;
  float acc[4][4] = {};
  const float* Abase = A + (size_t)(m0 + lm)*K + kq*4;
  const float* Wbase = W + (size_t)(n0 + lm)*K + kq*4;
  for (int k0 = 0; k0 < K; k0 += 16) {
    float4 av = *reinterpret_cast<const float4*>(Abase + k0);
    float4 bv = *reinterpret_cast<const float4*>(Wbase + k0);
    As[kq*4+0][lm]=av.x; As[kq*4+1][lm]=av.y; As[kq*4+2][lm]=av.z; As[kq*4+3][lm]=av.w;
    Bs[kq*4+0][lm]=bv.x; Bs[kq*4+1][lm]=bv.y; Bs[kq*4+2][lm]=bv.z; Bs[kq*4+3][lm]=bv.w;
    __syncthreads();
    #pragma unroll
    for (int kk = 0; kk < 16; ++kk) {
      float4 a = *reinterpret_cast<const float4*>(&As[kk][tm*4]);
      float4 b = *reinterpret_cast<const float4*>(&Bs[kk][tn*4]);
      float ar[4] = {a.x,a.y,a.z,a.w};
      float br[4] = {b.x,b.y,b.z,b.w};
      #pragma unroll
      for (int i = 0; i < 4; ++i)
        #pragma unroll
        for (int j = 0; j < 4; ++j)
          acc[i][j] = fmaf(ar[i], br[j], acc[i][j]);
    }
    __syncthreads();
  }
  #pragma unroll
  for (int i = 0; i < 4; ++i) {
    float4 ov = make_float4(acc[i][0], acc[i][1], acc[i][2], acc[i][3]);
    *reinterpret_cast<float4*>(C + (size_t)(m0 + tm*4 + i)*N + n0 + tn*4) = ov;
  }
}

// ---------------- causal conv1d (DC=4) + silu ----------------
__global__ __launch_bounds__(256) void k_conv1d(const float* __restrict__ xz, const float* __restrict__ w,
                                                const float* __restrict__ bias, float* __restrict__ xc){
  int idx = blockIdx.x*256 + threadIdx.x;   // over 8*512*256
  int d = idx & 255;
  int l = (idx >> 8) & 511;
  int bb = idx >> 17;
  const float* base = xz + (size_t)bb*512*512 + d;   // xin = xz[...,:256]
  float s = bias[d];
  #pragma unroll
  for (int k = 0; k < 4; ++k) {
    int ls = l - 3 + k;
    if (ls >= 0) s = fmaf(base[(size_t)ls*512], w[d*4+k], s);
  }
  xc[idx] = s / (1.f + __expf(-s));
}

// ---------------- x_proj (40 outs) + dt_proj + softplus ----------------
__global__ __launch_bounds__(256) void k_xproj(const float* __restrict__ xc, const float* __restrict__ xpw,
                                               const float* __restrict__ dtw, const float* __restrict__ dtb,
                                               float* __restrict__ dbl, float* __restrict__ dt){
  __shared__ __align__(16) float sxc[256];
  __shared__ float sdbl[40];
  int bl = blockIdx.x;         // (b,l) 0..4095
  int tid = threadIdx.x;
  sxc[tid] = xc[(size_t)bl*256 + tid];
  __syncthreads();
  if (tid < 40) {
    const float4* wr = reinterpret_cast<const float4*>(xpw + tid*256);
    const float4* xr = reinterpret_cast<const float4*>(sxc);
    float s = 0.f;
    #pragma unroll 8
    for (int i = 0; i < 64; ++i) {
      float4 w = wr[i], xv = xr[i];
      s += w.x*xv.x + w.y*xv.y + w.z*xv.z + w.w*xv.w;
    }
    sdbl[tid] = s;
    dbl[(size_t)bl*40 + tid] = s;
  }
  __syncthreads();
  float s = dtb[tid];
  const float* wr = dtw + tid*8;
  #pragma unroll
  for (int r = 0; r < 8; ++r) s = fmaf(sdbl[r], wr[r], s);
  float sp = (s > 20.f) ? s : log1pf(__expf(s));
  dt[(size_t)bl*256 + tid] = sp;
}

// ---------------- chunk-parallel selective scan (LDS-preloaded) ----------------
__global__ __launch_bounds__(256) void k_scanA(const float* __restrict__ dt, const float* __restrict__ dbl,
                                               const float* __restrict__ xc, const float* __restrict__ A_log,
                                               float* __restrict__ aprod, float* __restrict__ hend){
  __shared__ float sdt[32][16], sxc[32][16], sB[32][16];
  int tid = threadIdx.x;
  int bg = blockIdx.x;            // b*16 + dgrp
  int ch = blockIdx.y;
  int bb = bg >> 4, dgrp = bg & 15;
  int l0 = ch*32;
  #pragma unroll
  for (int it = 0; it < 2; ++it) {
    int idx = it*256 + tid;       // 0..511
    int t = idx >> 4, dd = idx & 15;
    int base = bb*512 + l0 + t;
    sdt[t][dd] = dt[(size_t)base*256 + dgrp*16 + dd];
    sxc[t][dd] = xc[(size_t)base*256 + dgrp*16 + dd];
    sB [t][dd] = dbl[(size_t)base*40 + 8 + dd];
  }
  __syncthreads();
  int n = tid & 15, dloc = tid >> 4;
  float Ac = -__expf(A_log[(dgrp*16 + dloc)*16 + n]);
  float a = 1.f, h = 0.f;
  #pragma unroll
  for (int t = 0; t < 32; ++t) {
    float dtv = sdt[t][dloc], xcv = sxc[t][dloc], Bv = sB[t][n];
    float dA = __expf(dtv*Ac);
    h = fmaf(dA, h, dtv*Bv*xcv);
    a *= dA;
  }
  aprod[(size_t)(bg*16 + ch)*256 + tid] = a;
  hend [(size_t)(bg*16 + ch)*256 + tid] = h;
}

__global__ __launch_bounds__(256) void k_scanB(const float* __restrict__ aprod, const float* __restrict__ hend,
                                               float* __restrict__ hstart){
  int tid = threadIdx.x;
  int bg = blockIdx.x;
  float hs = 0.f;
  #pragma unroll
  for (int ch = 0; ch < 16; ++ch) {
    size_t idx = (size_t)(bg*16 + ch)*256 + tid;
    hstart[idx] = hs;
    hs = fmaf(aprod[idx], hs, hend[idx]);
  }
}

__global__ __launch_bounds__(256) void k_scanC(const float* __restrict__ dt, const float* __restrict__ dbl,
                                               const float* __restrict__ xc, const float* __restrict__ xz,
                                               const float* __restrict__ A_log, const float* __restrict__ Dp,
                                               const float* __restrict__ hstart, float* __restrict__ y){
  __shared__ float sdt[32][16], sxc[32][16], sB[32][16], sC[32][16], sz[32][16];
  int tid = threadIdx.x;
  int bg = blockIdx.x;
  int ch = blockIdx.y;
  int bb = bg >> 4, dgrp = bg & 15;
  int l0 = ch*32;
  #pragma unroll
  for (int it = 0; it < 2; ++it) {
    int idx = it*256 + tid;
    int t = idx >> 4, dd = idx & 15;
    int base = bb*512 + l0 + t;
    sdt[t][dd] = dt[(size_t)base*256 + dgrp*16 + dd];
    sxc[t][dd] = xc[(size_t)base*256 + dgrp*16 + dd];
    sB [t][dd] = dbl[(size_t)base*40 + 8  + dd];
    sC [t][dd] = dbl[(size_t)base*40 + 24 + dd];
    sz [t][dd] = xz[(size_t)base*512 + 256 + dgrp*16 + dd];
  }
  __syncthreads();
  int n = tid & 15, dloc = tid >> 4;
  int d = dgrp*16 + dloc;
  float Ac = -__expf(A_log[d*16 + n]);
  float Dv = Dp[d];
  float h = hstart[(size_t)(bg*16 + ch)*256 + tid];
  #pragma unroll 4
  for (int t = 0; t < 32; ++t) {
    float dtv = sdt[t][dloc], xcv = sxc[t][dloc];
    float Bv = sB[t][n], Cv = sC[t][n];
    float dA = __expf(dtv*Ac);
    h = fmaf(dA, h, dtv*Bv*xcv);
    float yp = h*Cv;
    yp += __shfl_xor(yp, 1, 16);
    yp += __shfl_xor(yp, 2, 16);
    yp += __shfl_xor(yp, 4, 16);
    yp += __shfl_xor(yp, 8, 16);
    if (n == 0) {
      float zv = sz[t][dloc];
      y[(size_t)(bb*512 + l0 + t)*256 + d] = (yp + Dv*xcv) * (zv / (1.f + __expf(-zv)));
    }
  }
}

// ---------------- lin via bf16 MFMA + bias + pixel-shuffle -> padded bf16 ubf ----------------
__global__ __launch_bounds__(512) void k_linm(const ushort* __restrict__ ybfT, const ushort* __restrict__ lwbf,
                                              const float* __restrict__ lb, ushort* __restrict__ ubf){
  __shared__ ushort As[128*88];
  __shared__ ushort Bs[128*88];
  int m0 = blockIdx.x * 128;
  int b  = blockIdx.y;
  int tid = threadIdx.x;
  int l = tid & 63, wv = tid >> 6;
  int wm = wv & 3, we = wv >> 2;
  int lj = l & 15, lg = l >> 4;
  f32x4 acc[4][2];
  #pragma unroll
  for (int fo = 0; fo < 4; ++fo)
    #pragma unroll
    for (int fj = 0; fj < 2; ++fj)
      acc[fo][fj] = (f32x4){0.f,0.f,0.f,0.f};

  for (int k0 = 0; k0 < 512; k0 += 64) {
    __syncthreads();
    #pragma unroll
    for (int it = 0; it < 2; ++it) {
      int flat = it*512 + tid;        // 0..1023
      int e = flat >> 3, kc8 = flat & 7;
      *reinterpret_cast<uint4*>(&As[e*88 + kc8*8]) =
        *reinterpret_cast<const uint4*>(ybfT + ((size_t)b*128 + e)*512 + k0 + kc8*8);
      *reinterpret_cast<uint4*>(&Bs[e*88 + kc8*8]) =
        *reinterpret_cast<const uint4*>(lwbf + (size_t)(m0 + e)*512 + k0 + kc8*8);
    }
    __syncthreads();
    #pragma unroll
    for (int kc = 0; kc < 2; ++kc) {
      short8v af[4], bq[2];
      #pragma unroll
      for (int fo = 0; fo < 4; ++fo)
        af[fo] = *reinterpret_cast<const short8v*>(&As[(we*64 + fo*16 + lj)*88 + kc*32 + lg*8]);
      #pragma unroll
      for (int fj = 0; fj < 2; ++fj)
        bq[fj] = *reinterpret_cast<const short8v*>(&Bs[(wm*32 + fj*16 + lj)*88 + kc*32 + lg*8]);
      #pragma unroll
      for (int fo = 0; fo < 4; ++fo)
        #pragma unroll
        for (int fj = 0; fj < 2; ++fj)
          acc[fo][fj] = __builtin_amdgcn_mfma_f32_16x16x32_bf16(af[fo], bq[fj], acc[fo][fj], 0, 0, 0);
    }
  }
  #pragma unroll
  for (int fj = 0; fj < 2; ++fj) {
    int m = m0 + wm*32 + fj*16 + lj;
    float bias = lb[m];
    int hh = ((m >> 9) << 2) + ((m >> 2) & 3);
    int ww = (((m >> 4) & 31) << 2) + (m & 3);
    #pragma unroll
    for (int fo = 0; fo < 4; ++fo) {
      int eg = we*2 + (fo >> 1);
      int e5 = ((fo & 1) << 4) + (lg << 2);
      f32x4 a = acc[fo][fj];
      uint2 u;
      u.x = (uint)bf16rne(a.x + bias) | ((uint)bf16rne(a.y + bias) << 16);
      u.y = (uint)bf16rne(a.z + bias) | ((uint)bf16rne(a.w + bias) << 16);
      *reinterpret_cast<uint2*>(ubf + ((((size_t)b*4 + eg)*66 + hh + 1)*130 + ww + 1)*32 + e5) = u;
    }
  }
}

// ---------------- conv3x3 via bf16 MFMA implicit GEMM (conflict-free LDS) ----------------
// grid (h2=32, bz=64: bb*8+ocg). 256 thr = 4 waves: hr = wv>>1, wseg = (wv&1)*64.
// Weights frag-linear (conflict-free); input slot-XOR swizzled (2-way max, free).
__global__ __launch_bounds__(256) void k_conv3m(const ushort* __restrict__ ubf, const ushort* __restrict__ wbf,
                                                const float* __restrict__ cb, float* __restrict__ out){
  extern __shared__ ushort smu[];
  ushort* wlds = smu;           // [9 tap][4 f][64 lane][8 e] = 18432 ushorts
  ushort* ubuf = smu + 18432;   // [4 rows][130 w'][4 slot^][8 e] stride 4160 = 16640 ushorts
  int h2 = blockIdx.x;          // 0..31
  int bz = blockIdx.y;
  int bb = bz >> 3, ocg = bz & 7;   // ocg = oc*2 + oh (64-o group)
  int tid = threadIdx.x;
  int l   = tid & 63;
  int wv  = tid >> 6;
  int hr  = wv >> 1;            // row within pair
  int wseg = (wv & 1) * 64;     // w half
  int lj = l & 15, lg = l >> 4;

  f32x4 acc[4][4];
  #pragma unroll
  for (int i = 0; i < 4; ++i)
    #pragma unroll
    for (int j = 0; j < 4; ++j)
      acc[i][j] = (f32x4){0.f, 0.f, 0.f, 0.f};

  for (int ec = 0; ec < 4; ++ec) {
    __syncthreads();
    const uint4* sA = reinterpret_cast<const uint4*>(wbf) + (size_t)(ocg*4 + ec)*2304;
    uint4* dA = reinterpret_cast<uint4*>(wlds);
    for (int i = tid; i < 2304; i += 256) dA[i] = sA[i];
    const uint4* sB = reinterpret_cast<const uint4*>(ubf) + ((size_t)(bb*4 + ec)*66 + 2*h2)*520;
    uint4* dB = reinterpret_cast<uint4*>(ubuf);
    for (int i = tid; i < 2080; i += 256) {
      int w = (i >> 2) % 130;
      dB[(i & ~3) | ((i ^ (w >> 1)) & 3)] = sB[i];
    }
    __syncthreads();

    #pragma unroll
    for (int ki = 0; ki < 3; ++ki) {
      const ushort* brow = ubuf + (hr + ki)*4160;
      #pragma unroll
      for (int kj = 0; kj < 3; ++kj) {
        const ushort* wtap = wlds + (ki*3 + kj)*2048 + l*8;
        short8v af[4], bfr[4];
        #pragma unroll
        for (int f = 0; f < 4; ++f)
          af[f] = *reinterpret_cast<const short8v*>(wtap + f*512);
        #pragma unroll
        for (int f = 0; f < 4; ++f) {
          int wb = wseg + f*16 + lj + kj;
          bfr[f] = *reinterpret_cast<const short8v*>(brow + wb*32 + ((lg ^ (wb >> 1)) & 3)*8);
        }
        #pragma unroll
        for (int fo = 0; fo < 4; ++fo)
          #pragma unroll
          for (int fj = 0; fj < 4; ++fj)
            acc[fo][fj] = __builtin_amdgcn_mfma_f32_16x16x32_bf16(af[fo], bfr[fj], acc[fo][fj], 0, 0, 0);
      }
    }
  }

  int row = h2*2 + hr;              // pre-shuffle output row, 0..63
  #pragma unroll
  for (int fo = 0; fo < 4; ++fo) {
    int obase = ocg*64 + fo*16 + lg*4;   // + q
    int g = obase >> 2;
    float b0 = cb[obase], b1 = cb[obase+1], b2 = cb[obase+2], b3 = cb[obase+3];
    size_t rbase0 = (((size_t)bb*128 + g)*128 + 2*row)*256;
    size_t rbase1 = rbase0 + 256;
    #pragma unroll
    for (int fj = 0; fj < 4; ++fj) {
      int w = wseg + fj*16 + lj;
      f32x4 a = acc[fo][fj];
      float2 v0 = make_float2(geluf(a.x + b0), geluf(a.y + b1));
      float2 v1 = make_float2(geluf(a.z + b2), geluf(a.w + b3));
      *reinterpret_cast<float2*>(out + rbase0 + 2*w) = v0;
      *reinterpret_cast<float2*>(out + rbase1 + 2*w) = v1;
    }
  }
}

// ---------------- FFN via bf16 MFMA: out = c + W2 @ gelu(W1 @ c + b1) + b2 (write-only epilogue) ----
__global__ __launch_bounds__(512) void k_ffnm(const ushort* __restrict__ wpad, const float* __restrict__ b1,
                                              const float* __restrict__ b2, float* __restrict__ io){
  extern __shared__ ushort sm[];
  ushort* cT = sm;              // [128 px][136] bf16 c tile (survives to epilogue)
  ushort* wl = sm + 128*136;    // [128][136] bf16: W1, then f1[px][e]
  int pix0 = blockIdx.x * 128;
  int bb = pix0 >> 15;
  int hw0 = pix0 & 32767;
  int tid = threadIdx.x;
  int l = tid & 63, wv = tid >> 6;
  int wc = wv >> 2, wp = wv & 3;
  int lj = l & 15, lg = l >> 4;
  int r = tid & 1, hpair = tid >> 1;      // for c staging
  const float* cbase = io + (size_t)bb*128*HW2 + hw0;

  for (int it = 0; it < 16; ++it) {
    int flat = it*256 + hpair;            // 0..4095
    int pp = flat & 63;                   // px-pair
    int cpair = flat >> 6;                // ch-pair
    int ch = cpair*2 + r;
    float2 v = *reinterpret_cast<const float2*>(cbase + (size_t)ch*HW2 + pp*2);
    float oa = __shfl_xor(v.x, 1);
    float ob = __shfl_xor(v.y, 1);
    ushort lo = r ? bf16rne(ob) : bf16rne(v.x);
    ushort hi = r ? bf16rne(v.y) : bf16rne(oa);
    *reinterpret_cast<uint*>(&cT[(pp*2 + r)*136 + cpair*2]) = (uint)lo | ((uint)hi << 16);
  }
  {
    const uint4* src = reinterpret_cast<const uint4*>(wpad);
    uint4* dst = reinterpret_cast<uint4*>(wl);
    for (int i = tid; i < 2176; i += 512) dst[i] = src[i];
  }
  __syncthreads();

  f32x4 acc[4][2];
  #pragma unroll
  for (int fo = 0; fo < 4; ++fo)
    #pragma unroll
    for (int fj = 0; fj < 2; ++fj)
      acc[fo][fj] = (f32x4){0.f,0.f,0.f,0.f};

  #pragma unroll
  for (int kc = 0; kc < 4; ++kc) {
    short8v af[4], bq[2];
    #pragma unroll
    for (int fo = 0; fo < 4; ++fo)
      af[fo] = *reinterpret_cast<const short8v*>(&wl[(wc*64 + fo*16 + lj)*136 + kc*32 + lg*8]);
    #pragma unroll
    for (int fj = 0; fj < 2; ++fj)
      bq[fj] = *reinterpret_cast<const short8v*>(&cT[(wp*32 + fj*16 + lj)*136 + kc*32 + lg*8]);
    #pragma unroll
    for (int fo = 0; fo < 4; ++fo)
      #pragma unroll
      for (int fj = 0; fj < 2; ++fj)
        acc[fo][fj] = __builtin_amdgcn_mfma_f32_16x16x32_bf16(af[fo], bq[fj], acc[fo][fj], 0, 0, 0);
  }
  __syncthreads();

  const ushort* w2g = wpad + 17408;
  short8v a2[4], a2n[4];
  #pragma unroll
  for (int fo = 0; fo < 4; ++fo)
    a2[fo] = *reinterpret_cast<const short8v*>(w2g + (size_t)(wc*64 + fo*16 + lj)*136 + lg*8);

  #pragma unroll
  for (int fo = 0; fo < 4; ++fo) {
    int ch0 = wc*64 + fo*16 + lg*4;
    float c0 = b1[ch0], c1 = b1[ch0+1], c2 = b1[ch0+2], c3 = b1[ch0+3];
    #pragma unroll
    for (int fj = 0; fj < 2; ++fj) {
      int px = wp*32 + fj*16 + lj;
      f32x4 a = acc[fo][fj];
      uint2 u;
      u.x = (uint)bf16rne(geluf(a.x + c0)) | ((uint)bf16rne(geluf(a.y + c1)) << 16);
      u.y = (uint)bf16rne(geluf(a.z + c2)) | ((uint)bf16rne(geluf(a.w + c3)) << 16);
      *reinterpret_cast<uint2*>(&wl[px*136 + ch0]) = u;
    }
  }
  __syncthreads();

  #pragma unroll
  for (int fo = 0; fo < 4; ++fo)
    #pragma unroll
    for (int fj = 0; fj < 2; ++fj)
      acc[fo][fj] = (f32x4){0.f,0.f,0.f,0.f};

  #pragma unroll
  for (int kc = 0; kc < 4; ++kc) {
    if (kc < 3) {
      #pragma unroll
      for (int fo = 0; fo < 4; ++fo)
        a2n[fo] = *reinterpret_cast<const short8v*>(w2g + (size_t)(wc*64 + fo*16 + lj)*136 + (kc+1)*32 + lg*8);
    }
    short8v bq[2];
    #pragma unroll
    for (int fj = 0; fj < 2; ++fj)
      bq[fj] = *reinterpret_cast<const short8v*>(&wl[(wp*32 + fj*16 + lj)*136 + kc*32 + lg*8]);
    #pragma unroll
    for (int fo = 0; fo < 4; ++fo)
      #pragma unroll
      for (int fj = 0; fj < 2; ++fj)
        acc[fo][fj] = __builtin_amdgcn_mfma_f32_16x16x32_bf16(a2[fo], bq[fj], acc[fo][fj], 0, 0, 0);
    #pragma unroll
    for (int fo = 0; fo < 4; ++fo) a2[fo] = a2n[fo];
  }

  #pragma unroll
  for (int fo = 0; fo < 4; ++fo) {
    int ch0 = wc*64 + fo*16 + lg*4;
    float d0 = b2[ch0], d1 = b2[ch0+1], d2 = b2[ch0+2], d3 = b2[ch0+3];
    #pragma unroll
    for (int fj = 0; fj < 2; ++fj) {
      int px = wp*32 + fj*16 + lj;
      f32x4 a = acc[fo][fj];
      uint2 cu = *reinterpret_cast<const uint2*>(&cT[px*136 + ch0]);
      float cv0 = __uint_as_float((cu.x & 0xffffu) << 16);
      float cv1 = __uint_as_float(cu.x & 0xffff0000u);
      float cv2 = __uint_as_float((cu.y & 0xffffu) << 16);
      float cv3 = __uint_as_float(cu.y & 0xffff0000u);
      float* p0 = io + (size_t)bb*128*HW2 + (size_t)ch0*HW2 + hw0 + px;
      p0[0]             = cv0 + a.x + d0;
      p0[HW2]           = cv1 + a.y + d1;
      p0[2*HW2]         = cv2 + a.z + d2;
      p0[3*(size_t)HW2] = cv3 + a.w + d3;
    }
  }
}

extern "C" void kernel_launch(void* const* d_in, const int* in_sizes, int n_in,
                              void* d_out, int out_size, void* d_ws, size_t ws_size,
                              hipStream_t stream) {
  const float* x          = (const float*)d_in[0];
  const float* patch_w    = (const float*)d_in[1];
  const float* patch_b    = (const float*)d_in[2];
  const float* in_proj_w  = (const float*)d_in[3];
  const float* conv1d_w   = (const float*)d_in[4];
  const float* conv1d_b   = (const float*)d_in[5];
  const float* x_proj_w   = (const float*)d_in[6];
  const float* dt_proj_w  = (const float*)d_in[7];
  const float* dt_proj_b  = (const float*)d_in[8];
  const float* A_log      = (const float*)d_in[9];
  const float* D_param    = (const float*)d_in[10];
  const float* out_proj_w = (const float*)d_in[11];
  const float* lin_w      = (const float*)d_in[12];
  const float* lin_b      = (const float*)d_in[13];
  const float* conv_w     = (const float*)d_in[14];
  const float* conv_b     = (const float*)d_in[15];
  const float* ffn_w1     = (const float*)d_in[16];
  const float* ffn_b1     = (const float*)d_in[17];
  const float* ffn_w2     = (const float*)d_in[18];
  const float* ffn_b2     = (const float*)d_in[19];
  float* out = (float*)d_out;
  float* ws  = (float*)d_ws;

  float* t    = ws;                 // 524288   (B*N, E)
  float* xz   = t    + 524288;      // 2097152  (B*N, 512)
  float* xc   = xz   + 2097152;     // 1048576  (B*N, 256)
  float* dbl  = xc   + 1048576;     // 163840   (B*N, 40)
  float* dt   = dbl  + 163840;      // 1048576  (B*N, 256)
  float* y    = dt   + 1048576;     // 1048576  (B*N, 256)
  float* yo   = y    + 1048576;     // 524288   (B*N, 128)
  float* apr  = yo   + 524288;      // 524288
  float* hend = apr  + 524288;      // 524288
  float* hst  = hend + 524288;      // 524288
  ushort* ubf  = (ushort*)(hst + 524288); // 10982400 bf16: [8][4][66][130][32]
  ushort* wbf  = ubf + 10982400;          // 589824 bf16 frag-linear conv weights
  ushort* wpad = wbf + 589824;            // 34816 bf16:    [2][128][136]
  ushort* lwbf = wpad + 34816;            // 4194304 bf16:  [8192][512]
  ushort* ybfT = lwbf + 4194304;          // 524288 bf16:   [8][128][512]
  float* part = xz;                       // 4194304 floats scratch (xz..dt region), consumed before xz written

  k_zero4 <<<dim3(5363), dim3(256), 0, stream>>>((uint4*)ubf, 1372800);
  k_wprep <<<dim3(2304), dim3(256), 0, stream>>>(conv_w, wbf);
  k_wffn  <<<dim3(136), dim3(256), 0, stream>>>(ffn_w1, ffn_w2, wpad);
  k_wlin  <<<dim3(4096), dim3(256), 0, stream>>>(lin_w, lwbf);
  k_patchm<<<dim3(32, 8), dim3(256), 0, stream>>>(x, patch_w, part);
  k_tred  <<<dim3(512), dim3(256), 0, stream>>>(part, patch_b, t);
  k_gemm  <<<dim3(64, 8), dim3(256), 0, stream>>>(t, in_proj_w, xz, 4096, 512, 128);
  k_conv1d<<<dim3(4096), dim3(256), 0, stream>>>(xz, conv1d_w, conv1d_b, xc);
  k_xproj <<<dim3(4096), dim3(256), 0, stream>>>(xc, x_proj_w, dt_proj_w, dt_proj_b, dbl, dt);
  k_scanA <<<dim3(128, 16), dim3(256), 0, stream>>>(dt, dbl, xc, A_log, apr, hend);
  k_scanB <<<dim3(128), dim3(256), 0, stream>>>(apr, hend, hst);
  k_scanC <<<dim3(128, 16), dim3(256), 0, stream>>>(dt, dbl, xc, xz, A_log, D_param, hst, y);
  k_gemm  <<<dim3(64, 2), dim3(256), 0, stream>>>(y, out_proj_w, yo, 4096, 128, 256);
  k_ytr   <<<dim3(8, 16), dim3(256), 0, stream>>>(yo, ybfT);
  k_linm  <<<dim3(64, 8), dim3(512), 0, stream>>>(ybfT, lwbf, lin_b, ubf);
  k_conv3m<<<dim3(32, 64), dim3(256), (size_t)35072*sizeof(ushort), stream>>>(ubf, wbf, conv_b, out);
  k_ffnm  <<<dim3(2048), dim3(512), (size_t)(2*128*136)*sizeof(ushort), stream>>>(wpad, ffn_b1, ffn_b2, out);
}

// Round 7
// 344.899 us; speedup vs baseline: 8.4434x; 1.0654x over previous
//
#include <hip/hip_runtime.h>
#include <hip/hip_bf16.h>

// Shapes (fixed): B=8,C=256,H=64,W=128,P=4,E=DM=128,N=512,DI=256,DS=16,DC=4,DR=8,NG=128,S=2
#define HW2 32768   // 128*256 output spatial per (b,channel)

typedef __attribute__((ext_vector_type(8))) short short8v;
typedef __attribute__((ext_vector_type(4))) float f32x4;

__device__ __forceinline__ float siluf(float x){ return x / (1.f + __expf(-x)); }
__device__ __forceinline__ float geluf(float v){
  float t = 0.7978845608028654f * fmaf(0.044715f*v*v, v, v);
  t = fminf(fmaxf(t, -15.f), 15.f);
  float e = __expf(2.f*t);
  return 0.5f*v*(1.f + (e-1.f)/(e+1.f));
}
__device__ __forceinline__ ushort bf16rne(float f){
  unsigned u = __float_as_uint(f);
  unsigned r = (u + 0x7fffu + ((u >> 16) & 1u)) >> 16;
  return (ushort)r;
}
__device__ __forceinline__ float bf2f(ushort u){ return __uint_as_float(((unsigned)u) << 16); }
__device__ __forceinline__ void split2(float v, ushort& h, ushort& lo){
  h = bf16rne(v);
  lo = bf16rne(v - bf2f(h));
}

// ---------------- zero-fill (uint4 granularity) ----------------
__global__ __launch_bounds__(256) void k_zero4(uint4* __restrict__ p, int n){
  int i = blockIdx.x*256 + threadIdx.x;
  if (i < n) p[i] = make_uint4(0,0,0,0);
}

// ---------------- conv weights fp32 -> bf16 FRAGMENT-LINEAR: [(ocg*4+ec)][tap9][f4][lane64][8e] --------
__global__ __launch_bounds__(256) void k_wprep(const float* __restrict__ cw, ushort* __restrict__ wbf){
  int idx = blockIdx.x*256 + threadIdx.x;   // 589824
  int j    = idx & 7;
  int lane = (idx >> 3) & 63;
  int f    = (idx >> 9) & 3;
  int tap  = (idx >> 11) % 9;
  int rest = idx / 18432;                   // ocg*4 + ec, 0..31
  int ec = rest & 3, ocg = rest >> 2;
  int o = ocg*64 + f*16 + (lane & 15);
  int e = ec*32 + (lane >> 4)*8 + j;
  float v = cw[((size_t)o*128 + e)*9 + tap];
  wbf[idx] = bf16rne(v);
}

// ---------------- FFN weights fp32 -> bf16 padded [2][128][136] ----------------
__global__ __launch_bounds__(256) void k_wffn(const float* __restrict__ w1, const float* __restrict__ w2,
                                              ushort* __restrict__ wpad){
  int idx = blockIdx.x*256 + threadIdx.x;   // 34816
  int which = idx / 17408;
  int rem = idx - which*17408;
  int e = rem / 136, k = rem - e*136;
  const float* s = which ? w2 : w1;
  wpad[idx] = (k < 128) ? bf16rne(s[e*128 + k]) : (ushort)0;
}

// ---------------- lin weights fp32 -> bf16 (same [m][n] layout) ----------------
__global__ __launch_bounds__(256) void k_wlin(const float* __restrict__ lw, ushort* __restrict__ lwbf){
  int i = blockIdx.x*256 + threadIdx.x;     // 1048576 float4s
  float4 v = reinterpret_cast<const float4*>(lw)[i];
  uint2 u;
  u.x = (uint)bf16rne(v.x) | ((uint)bf16rne(v.y) << 16);
  u.y = (uint)bf16rne(v.z) | ((uint)bf16rne(v.w) << 16);
  reinterpret_cast<uint2*>(lwbf)[i] = u;
}

// ---------------- yo (4096 x 128 fp32) -> ybfT [b][e128][n512] bf16 ----------------
__global__ __launch_bounds__(256) void k_ytr(const float* __restrict__ yo, ushort* __restrict__ ybfT){
  __shared__ float tile[32][132];
  int b = blockIdx.x, n0 = blockIdx.y*32;
  int tid = threadIdx.x;
  for (int it = 0; it < 16; ++it) {
    int idx = it*256 + tid;
    int row = idx >> 7, e = idx & 127;
    tile[row][e] = yo[((size_t)(b*512 + n0 + row))*128 + e];
  }
  __syncthreads();
  int e = tid >> 1, half = tid & 1;
  uint* dst = reinterpret_cast<uint*>(ybfT + ((size_t)b*128 + e)*512 + n0 + half*16);
  #pragma unroll
  for (int j = 0; j < 8; ++j) {
    int n = half*16 + j*2;
    dst[j] = (uint)bf16rne(tile[n][e]) | ((uint)bf16rne(tile[n+1][e]) << 16);
  }
}

// ---------------- patch embed via bf16x3 MFMA, split-K=8 -> part[ks][4096][128] ----------------
__global__ __launch_bounds__(256) void k_patchm(const float* __restrict__ x, const float* __restrict__ pw,
                                                float* __restrict__ part){
  __shared__ ushort Ah[4096], Al[4096], Wh[4096], Wl[4096];  // frag-linear per 32-k chunk
  int m0 = blockIdx.x * 128;
  int ks = blockIdx.y;
  int tid = threadIdx.x;
  int l = tid & 63, wv = tid >> 6;
  int wm = wv >> 1, we = wv & 1;
  int lj = l & 15, lg = l >> 4;
  f32x4 acc[4][4];
  #pragma unroll
  for (int a = 0; a < 4; ++a)
    #pragma unroll
    for (int b = 0; b < 4; ++b)
      acc[a][b] = (f32x4){0.f,0.f,0.f,0.f};
  int kbase = ks * 512;

  for (int it = 0; it < 16; ++it) {
    int k0 = kbase + it*32;
    __syncthreads();
    #pragma unroll
    for (int q = 0; q < 4; ++q) {
      int flat = q*256 + tid;
      int row = flat & 127, kk4 = flat >> 7;
      int m = m0 + row;
      int bb = m >> 9, ll = m & 511;
      int hp = ll >> 5, wp = ll & 31;
      int k = k0 + kk4*4;
      int c = k >> 4, i2 = (k >> 2) & 3;
      float4 v = *reinterpret_cast<const float4*>(x + (((bb*256 + c)*64 + hp*4 + i2)*128 + wp*4));
      ushort h0,h1,h2,h3,q0,q1,q2,q3;
      split2(v.x,h0,q0); split2(v.y,h1,q1); split2(v.z,h2,q2); split2(v.w,h3,q3);
      uint2 uh, ul;
      uh.x = (uint)h0 | ((uint)h1 << 16); uh.y = (uint)h2 | ((uint)h3 << 16);
      ul.x = (uint)q0 | ((uint)q1 << 16); ul.y = (uint)q2 | ((uint)q3 << 16);
      int lane = ((kk4 >> 1) << 4) | (row & 15);
      int dst = ((row >> 4)*64 + lane)*8 + (kk4 & 1)*4;
      *reinterpret_cast<uint2*>(Ah + dst) = uh;
      *reinterpret_cast<uint2*>(Al + dst) = ul;
    }
    #pragma unroll
    for (int q = 0; q < 4; ++q) {
      int flat = q*256 + tid;
      int e = flat >> 3, kk4 = flat & 7;
      float4 v = *reinterpret_cast<const float4*>(pw + (size_t)e*4096 + k0 + kk4*4);
      ushort h0,h1,h2,h3,q0,q1,q2,q3;
      split2(v.x,h0,q0); split2(v.y,h1,q1); split2(v.z,h2,q2); split2(v.w,h3,q3);
      uint2 uh, ul;
      uh.x = (uint)h0 | ((uint)h1 << 16); uh.y = (uint)h2 | ((uint)h3 << 16);
      ul.x = (uint)q0 | ((uint)q1 << 16); ul.y = (uint)q2 | ((uint)q3 << 16);
      int lane = ((kk4 >> 1) << 4) | (e & 15);
      int dst = ((e >> 4)*64 + lane)*8 + (kk4 & 1)*4;
      *reinterpret_cast<uint2*>(Wh + dst) = uh;
      *reinterpret_cast<uint2*>(Wl + dst) = ul;
    }
    __syncthreads();

    short8v ah[4], al_[4], wh[4], wl_[4];
    #pragma unroll
    for (int f = 0; f < 4; ++f) {
      ah[f]  = *reinterpret_cast<const short8v*>(Ah + ((wm*4 + f)*64 + l)*8);
      al_[f] = *reinterpret_cast<const short8v*>(Al + ((wm*4 + f)*64 + l)*8);
      wh[f]  = *reinterpret_cast<const short8v*>(Wh + ((we*4 + f)*64 + l)*8);
      wl_[f] = *reinterpret_cast<const short8v*>(Wl + ((we*4 + f)*64 + l)*8);
    }
    #pragma unroll
    for (int fo = 0; fo < 4; ++fo)
      #pragma unroll
      for (int fj = 0; fj < 4; ++fj) {
        acc[fo][fj] = __builtin_amdgcn_mfma_f32_16x16x32_bf16(ah[fo],  wh[fj],  acc[fo][fj], 0, 0, 0);
        acc[fo][fj] = __builtin_amdgcn_mfma_f32_16x16x32_bf16(ah[fo],  wl_[fj], acc[fo][fj], 0, 0, 0);
        acc[fo][fj] = __builtin_amdgcn_mfma_f32_16x16x32_bf16(al_[fo], wh[fj],  acc[fo][fj], 0, 0, 0);
      }
  }
  float* pb = part + (size_t)ks*524288;
  #pragma unroll
  for (int fo = 0; fo < 4; ++fo) {
    int m = m0 + wm*64 + fo*16 + lg*4;
    #pragma unroll
    for (int fj = 0; fj < 4; ++fj) {
      int e = we*64 + fj*16 + lj;
      f32x4 a = acc[fo][fj];
      pb[(size_t)(m+0)*128 + e] = a.x;
      pb[(size_t)(m+1)*128 + e] = a.y;
      pb[(size_t)(m+2)*128 + e] = a.z;
      pb[(size_t)(m+3)*128 + e] = a.w;
    }
  }
}

// ---------------- reduce 8 K-split partials + bias -> t ----------------
__global__ __launch_bounds__(256) void k_tred(const float* __restrict__ part, const float* __restrict__ pb,
                                              float* __restrict__ t){
  int i = blockIdx.x*256 + threadIdx.x;    // 131072 float4s
  const float4* p4 = reinterpret_cast<const float4*>(part);
  float4 s = reinterpret_cast<const float4*>(pb)[i & 31];
  #pragma unroll
  for (int ks = 0; ks < 8; ++ks) {
    float4 v = p4[(size_t)ks*131072 + i];
    s.x += v.x; s.y += v.y; s.z += v.z; s.w += v.w;
  }
  reinterpret_cast<float4*>(t)[i] = s;
}

// ---------------- generic tiled GEMM: C(M,N) = A(M,K) @ W(N,K)^T ----------------
__global__ __launch_bounds__(256) void k_gemm(const float* __restrict__ A, const float* __restrict__ W,
                                              float* __restrict__ C, int M, int N, int K){
  __shared__ __align__(16) float As[16][68];
  __shared__ __align__(16) float Bs[16][68];
  int m0 = blockIdx.x * 64, n0 = blockIdx.y * 64;
  int tid = threadIdx.x;
  int tm = tid >> 4, tn = tid & 15;
  int lm = tid >> 2, kq = tid & 3;
  float acc[4][4] = {};
  const float* Abase = A + (size_t)(m0 + lm)*K + kq*4;
  const float* Wbase = W + (size_t)(n0 + lm)*K + kq*4;
  for (int k0 = 0; k0 < K; k0 += 16) {
    float4 av = *reinterpret_cast<const float4*>(Abase + k0);
    float4 bv = *reinterpret_cast<const float4*>(Wbase + k0);
    As[kq*4+0][lm]=av.x; As[kq*4+1][lm]=av.y; As[kq*4+2][lm]=av.z; As[kq*4+3][lm]=av.w;
    Bs[kq*4+0][lm]=bv.x; Bs[kq*4+1][lm]=bv.y; Bs[kq*4+2][lm]=bv.z; Bs[kq*4+3][lm]=bv.w;
    __syncthreads();
    #pragma unroll
    for (int kk = 0; kk < 16; ++kk) {
      float4 a = *reinterpret_cast<const float4*>(&As[kk][tm*4]);
      float4 b = *reinterpret_cast<const float4*>(&Bs[kk][tn*4]);
      float ar[4] = {a.x,a.y,a.z,a.w};
      float br[4] = {b.x,b.y,b.z,b.w};
      #pragma unroll
      for (int i = 0; i < 4; ++i)
        #pragma unroll
        for (int j = 0; j < 4; ++j)
          acc[i][j] = fmaf(ar[i], br[j], acc[i][j]);
    }
    __syncthreads();
  }
  #pragma unroll
  for (int i = 0; i < 4; ++i) {
    float4 ov = make_float4(acc[i][0], acc[i][1], acc[i][2], acc[i][3]);
    *reinterpret_cast<float4*>(C + (size_t)(m0 + tm*4 + i)*N + n0 + tn*4) = ov;
  }
}

// ---------------- causal conv1d (DC=4) + silu ----------------
__global__ __launch_bounds__(256) void k_conv1d(const float* __restrict__ xz, const float* __restrict__ w,
                                                const float* __restrict__ bias, float* __restrict__ xc){
  int idx = blockIdx.x*256 + threadIdx.x;   // over 8*512*256
  int d = idx & 255;
  int l = (idx >> 8) & 511;
  int bb = idx >> 17;
  const float* base = xz + (size_t)bb*512*512 + d;   // xin = xz[...,:256]
  float s = bias[d];
  #pragma unroll
  for (int k = 0; k < 4; ++k) {
    int ls = l - 3 + k;
    if (ls >= 0) s = fmaf(base[(size_t)ls*512], w[d*4+k], s);
  }
  xc[idx] = s / (1.f + __expf(-s));
}

// ---------------- x_proj (40 outs) + dt_proj + softplus ----------------
__global__ __launch_bounds__(256) void k_xproj(const float* __restrict__ xc, const float* __restrict__ xpw,
                                               const float* __restrict__ dtw, const float* __restrict__ dtb,
                                               float* __restrict__ dbl, float* __restrict__ dt){
  __shared__ __align__(16) float sxc[256];
  __shared__ float sdbl[40];
  int bl = blockIdx.x;         // (b,l) 0..4095
  int tid = threadIdx.x;
  sxc[tid] = xc[(size_t)bl*256 + tid];
  __syncthreads();
  if (tid < 40) {
    const float4* wr = reinterpret_cast<const float4*>(xpw + tid*256);
    const float4* xr = reinterpret_cast<const float4*>(sxc);
    float s = 0.f;
    #pragma unroll 8
    for (int i = 0; i < 64; ++i) {
      float4 w = wr[i], xv = xr[i];
      s += w.x*xv.x + w.y*xv.y + w.z*xv.z + w.w*xv.w;
    }
    sdbl[tid] = s;
    dbl[(size_t)bl*40 + tid] = s;
  }
  __syncthreads();
  float s = dtb[tid];
  const float* wr = dtw + tid*8;
  #pragma unroll
  for (int r = 0; r < 8; ++r) s = fmaf(sdbl[r], wr[r], s);
  float sp = (s > 20.f) ? s : log1pf(__expf(s));
  dt[(size_t)bl*256 + tid] = sp;
}

// ---------------- chunk-parallel selective scan (LDS-preloaded) ----------------
__global__ __launch_bounds__(256) void k_scanA(const float* __restrict__ dt, const float* __restrict__ dbl,
                                               const float* __restrict__ xc, const float* __restrict__ A_log,
                                               float* __restrict__ aprod, float* __restrict__ hend){
  __shared__ float sdt[32][16], sxc[32][16], sB[32][16];
  int tid = threadIdx.x;
  int bg = blockIdx.x;            // b*16 + dgrp
  int ch = blockIdx.y;
  int bb = bg >> 4, dgrp = bg & 15;
  int l0 = ch*32;
  #pragma unroll
  for (int it = 0; it < 2; ++it) {
    int idx = it*256 + tid;       // 0..511
    int t = idx >> 4, dd = idx & 15;
    int base = bb*512 + l0 + t;
    sdt[t][dd] = dt[(size_t)base*256 + dgrp*16 + dd];
    sxc[t][dd] = xc[(size_t)base*256 + dgrp*16 + dd];
    sB [t][dd] = dbl[(size_t)base*40 + 8 + dd];
  }
  __syncthreads();
  int n = tid & 15, dloc = tid >> 4;
  float Ac = -__expf(A_log[(dgrp*16 + dloc)*16 + n]);
  float a = 1.f, h = 0.f;
  #pragma unroll
  for (int t = 0; t < 32; ++t) {
    float dtv = sdt[t][dloc], xcv = sxc[t][dloc], Bv = sB[t][n];
    float dA = __expf(dtv*Ac);
    h = fmaf(dA, h, dtv*Bv*xcv);
    a *= dA;
  }
  aprod[(size_t)(bg*16 + ch)*256 + tid] = a;
  hend [(size_t)(bg*16 + ch)*256 + tid] = h;
}

__global__ __launch_bounds__(256) void k_scanB(const float* __restrict__ aprod, const float* __restrict__ hend,
                                               float* __restrict__ hstart){
  int tid = threadIdx.x;
  int bg = blockIdx.x;
  float hs = 0.f;
  #pragma unroll
  for (int ch = 0; ch < 16; ++ch) {
    size_t idx = (size_t)(bg*16 + ch)*256 + tid;
    hstart[idx] = hs;
    hs = fmaf(aprod[idx], hs, hend[idx]);
  }
}

__global__ __launch_bounds__(256) void k_scanC(const float* __restrict__ dt, const float* __restrict__ dbl,
                                               const float* __restrict__ xc, const float* __restrict__ xz,
                                               const float* __restrict__ A_log, const float* __restrict__ Dp,
                                               const float* __restrict__ hstart, float* __restrict__ y){
  __shared__ float sdt[32][16], sxc[32][16], sB[32][16], sC[32][16], sz[32][16];
  int tid = threadIdx.x;
  int bg = blockIdx.x;
  int ch = blockIdx.y;
  int bb = bg >> 4, dgrp = bg & 15;
  int l0 = ch*32;
  #pragma unroll
  for (int it = 0; it < 2; ++it) {
    int idx = it*256 + tid;
    int t = idx >> 4, dd = idx & 15;
    int base = bb*512 + l0 + t;
    sdt[t][dd] = dt[(size_t)base*256 + dgrp*16 + dd];
    sxc[t][dd] = xc[(size_t)base*256 + dgrp*16 + dd];
    sB [t][dd] = dbl[(size_t)base*40 + 8  + dd];
    sC [t][dd] = dbl[(size_t)base*40 + 24 + dd];
    sz [t][dd] = xz[(size_t)base*512 + 256 + dgrp*16 + dd];
  }
  __syncthreads();
  int n = tid & 15, dloc = tid >> 4;
  int d = dgrp*16 + dloc;
  float Ac = -__expf(A_log[d*16 + n]);
  float Dv = Dp[d];
  float h = hstart[(size_t)(bg*16 + ch)*256 + tid];
  #pragma unroll 4
  for (int t = 0; t < 32; ++t) {
    float dtv = sdt[t][dloc], xcv = sxc[t][dloc];
    float Bv = sB[t][n], Cv = sC[t][n];
    float dA = __expf(dtv*Ac);
    h = fmaf(dA, h, dtv*Bv*xcv);
    float yp = h*Cv;
    yp += __shfl_xor(yp, 1, 16);
    yp += __shfl_xor(yp, 2, 16);
    yp += __shfl_xor(yp, 4, 16);
    yp += __shfl_xor(yp, 8, 16);
    if (n == 0) {
      float zv = sz[t][dloc];
      y[(size_t)(bb*512 + l0 + t)*256 + d] = (yp + Dv*xcv) * (zv / (1.f + __expf(-zv)));
    }
  }
}

// ---------------- lin via bf16 MFMA + bias + pixel-shuffle -> padded bf16 ubf ----------------
__global__ __launch_bounds__(512) void k_linm(const ushort* __restrict__ ybfT, const ushort* __restrict__ lwbf,
                                              const float* __restrict__ lb, ushort* __restrict__ ubf){
  __shared__ ushort As[128*88];
  __shared__ ushort Bs[128*88];
  int m0 = blockIdx.x * 128;
  int b  = blockIdx.y;
  int tid = threadIdx.x;
  int l = tid & 63, wv = tid >> 6;
  int wm = wv & 3, we = wv >> 2;
  int lj = l & 15, lg = l >> 4;
  f32x4 acc[4][2];
  #pragma unroll
  for (int fo = 0; fo < 4; ++fo)
    #pragma unroll
    for (int fj = 0; fj < 2; ++fj)
      acc[fo][fj] = (f32x4){0.f,0.f,0.f,0.f};

  for (int k0 = 0; k0 < 512; k0 += 64) {
    __syncthreads();
    #pragma unroll
    for (int it = 0; it < 2; ++it) {
      int flat = it*512 + tid;        // 0..1023
      int e = flat >> 3, kc8 = flat & 7;
      *reinterpret_cast<uint4*>(&As[e*88 + kc8*8]) =
        *reinterpret_cast<const uint4*>(ybfT + ((size_t)b*128 + e)*512 + k0 + kc8*8);
      *reinterpret_cast<uint4*>(&Bs[e*88 + kc8*8]) =
        *reinterpret_cast<const uint4*>(lwbf + (size_t)(m0 + e)*512 + k0 + kc8*8);
    }
    __syncthreads();
    #pragma unroll
    for (int kc = 0; kc < 2; ++kc) {
      short8v af[4], bq[2];
      #pragma unroll
      for (int fo = 0; fo < 4; ++fo)
        af[fo] = *reinterpret_cast<const short8v*>(&As[(we*64 + fo*16 + lj)*88 + kc*32 + lg*8]);
      #pragma unroll
      for (int fj = 0; fj < 2; ++fj)
        bq[fj] = *reinterpret_cast<const short8v*>(&Bs[(wm*32 + fj*16 + lj)*88 + kc*32 + lg*8]);
      #pragma unroll
      for (int fo = 0; fo < 4; ++fo)
        #pragma unroll
        for (int fj = 0; fj < 2; ++fj)
          acc[fo][fj] = __builtin_amdgcn_mfma_f32_16x16x32_bf16(af[fo], bq[fj], acc[fo][fj], 0, 0, 0);
    }
  }
  #pragma unroll
  for (int fj = 0; fj < 2; ++fj) {
    int m = m0 + wm*32 + fj*16 + lj;
    float bias = lb[m];
    int hh = ((m >> 9) << 2) + ((m >> 2) & 3);
    int ww = (((m >> 4) & 31) << 2) + (m & 3);
    #pragma unroll
    for (int fo = 0; fo < 4; ++fo) {
      int eg = we*2 + (fo >> 1);
      int e5 = ((fo & 1) << 4) + (lg << 2);
      f32x4 a = acc[fo][fj];
      uint2 u;
      u.x = (uint)bf16rne(a.x + bias) | ((uint)bf16rne(a.y + bias) << 16);
      u.y = (uint)bf16rne(a.z + bias) | ((uint)bf16rne(a.w + bias) << 16);
      *reinterpret_cast<uint2*>(ubf + ((((size_t)b*4 + eg)*66 + hh + 1)*130 + ww + 1)*32 + e5) = u;
    }
  }
}

// ---------------- conv3x3 via bf16 MFMA: weights-only LDS (36.9 KB), inputs direct from L2 ----------------
// grid (h2=32, bz=64: bb*8+ocg). 256 thr = 4 waves: hr = wv>>1, wseg = (wv&1)*64.
__global__ __launch_bounds__(256, 3) void k_conv3m(const ushort* __restrict__ ubf, const ushort* __restrict__ wbf,
                                                   const float* __restrict__ cb, float* __restrict__ out){
  __shared__ ushort wlds[18432];    // [9 tap][4 f][64 lane][8 e] for current ec
  int h2 = blockIdx.x;              // 0..31
  int bz = blockIdx.y;
  int bb = bz >> 3, ocg = bz & 7;   // ocg = oc*2 + oh (64-o group)
  int tid = threadIdx.x;
  int l   = tid & 63;
  int wv  = tid >> 6;
  int hr  = wv >> 1;                // row within pair
  int wseg = (wv & 1) * 64;         // w half
  int lj = l & 15, lg = l >> 4;

  f32x4 acc[4][4];
  #pragma unroll
  for (int i = 0; i < 4; ++i)
    #pragma unroll
    for (int j = 0; j < 4; ++j)
      acc[i][j] = (f32x4){0.f, 0.f, 0.f, 0.f};

  for (int ec = 0; ec < 4; ++ec) {
    __syncthreads();
    const uint4* sA = reinterpret_cast<const uint4*>(wbf) + (size_t)(ocg*4 + ec)*2304;
    uint4* dA = reinterpret_cast<uint4*>(wlds);
    #pragma unroll
    for (int q = 0; q < 9; ++q) dA[q*256 + tid] = sA[q*256 + tid];
    __syncthreads();

    // per-lane input base: row = 2*h2 + hr (+ki), col base = wseg + lj, e-slice = lg*8
    const ushort* ub_ec = ubf + (((size_t)(bb*4 + ec)*66 + 2*h2 + hr)*130 + wseg + lj)*32 + lg*8;
    #pragma unroll
    for (int ki = 0; ki < 3; ++ki) {
      const ushort* bbase = ub_ec + (size_t)ki*4160;   // +row stride 130*32
      #pragma unroll
      for (int kj = 0; kj < 3; ++kj) {
        const ushort* wtap = wlds + (ki*3 + kj)*2048 + l*8;
        short8v af[4], bfr[4];
        #pragma unroll
        for (int f = 0; f < 4; ++f)
          af[f] = *reinterpret_cast<const short8v*>(wtap + f*512);
        #pragma unroll
        for (int f = 0; f < 4; ++f)
          bfr[f] = *reinterpret_cast<const short8v*>(bbase + (f*16 + kj)*32);
        #pragma unroll
        for (int fo = 0; fo < 4; ++fo)
          #pragma unroll
          for (int fj = 0; fj < 4; ++fj)
            acc[fo][fj] = __builtin_amdgcn_mfma_f32_16x16x32_bf16(af[fo], bfr[fj], acc[fo][fj], 0, 0, 0);
      }
    }
  }

  int row = h2*2 + hr;              // pre-shuffle output row, 0..63
  #pragma unroll
  for (int fo = 0; fo < 4; ++fo) {
    int obase = ocg*64 + fo*16 + lg*4;   // + q
    int g = obase >> 2;
    float b0 = cb[obase], b1 = cb[obase+1], b2 = cb[obase+2], b3 = cb[obase+3];
    size_t rbase0 = (((size_t)bb*128 + g)*128 + 2*row)*256;
    size_t rbase1 = rbase0 + 256;
    #pragma unroll
    for (int fj = 0; fj < 4; ++fj) {
      int w = wseg + fj*16 + lj;
      f32x4 a = acc[fo][fj];
      float2 v0 = make_float2(geluf(a.x + b0), geluf(a.y + b1));
      float2 v1 = make_float2(geluf(a.z + b2), geluf(a.w + b3));
      *reinterpret_cast<float2*>(out + rbase0 + 2*w) = v0;
      *reinterpret_cast<float2*>(out + rbase1 + 2*w) = v1;
    }
  }
}

// ---------------- FFN via bf16 MFMA: out = c + W2 @ gelu(W1 @ c + b1) + b2 (write-only epilogue) ----
__global__ __launch_bounds__(512) void k_ffnm(const ushort* __restrict__ wpad, const float* __restrict__ b1,
                                              const float* __restrict__ b2, float* __restrict__ io){
  extern __shared__ ushort sm[];
  ushort* cT = sm;              // [128 px][136] bf16 c tile (survives to epilogue)
  ushort* wl = sm + 128*136;    // [128][136] bf16: W1, then f1[px][e]
  int pix0 = blockIdx.x * 128;
  int bb = pix0 >> 15;
  int hw0 = pix0 & 32767;
  int tid = threadIdx.x;
  int l = tid & 63, wv = tid >> 6;
  int wc = wv >> 2, wp = wv & 3;
  int lj = l & 15, lg = l >> 4;
  int r = tid & 1, hpair = tid >> 1;      // for c staging
  const float* cbase = io + (size_t)bb*128*HW2 + hw0;

  for (int it = 0; it < 16; ++it) {
    int flat = it*256 + hpair;            // 0..4095
    int pp = flat & 63;                   // px-pair
    int cpair = flat >> 6;                // ch-pair
    int ch = cpair*2 + r;
    float2 v = *reinterpret_cast<const float2*>(cbase + (size_t)ch*HW2 + pp*2);
    float oa = __shfl_xor(v.x, 1);
    float ob = __shfl_xor(v.y, 1);
    ushort lo = r ? bf16rne(ob) : bf16rne(v.x);
    ushort hi = r ? bf16rne(v.y) : bf16rne(oa);
    *reinterpret_cast<uint*>(&cT[(pp*2 + r)*136 + cpair*2]) = (uint)lo | ((uint)hi << 16);
  }
  {
    const uint4* src = reinterpret_cast<const uint4*>(wpad);
    uint4* dst = reinterpret_cast<uint4*>(wl);
    for (int i = tid; i < 2176; i += 512) dst[i] = src[i];
  }
  __syncthreads();

  f32x4 acc[4][2];
  #pragma unroll
  for (int fo = 0; fo < 4; ++fo)
    #pragma unroll
    for (int fj = 0; fj < 2; ++fj)
      acc[fo][fj] = (f32x4){0.f,0.f,0.f,0.f};

  #pragma unroll
  for (int kc = 0; kc < 4; ++kc) {
    short8v af[4], bq[2];
    #pragma unroll
    for (int fo = 0; fo < 4; ++fo)
      af[fo] = *reinterpret_cast<const short8v*>(&wl[(wc*64 + fo*16 + lj)*136 + kc*32 + lg*8]);
    #pragma unroll
    for (int fj = 0; fj < 2; ++fj)
      bq[fj] = *reinterpret_cast<const short8v*>(&cT[(wp*32 + fj*16 + lj)*136 + kc*32 + lg*8]);
    #pragma unroll
    for (int fo = 0; fo < 4; ++fo)
      #pragma unroll
      for (int fj = 0; fj < 2; ++fj)
        acc[fo][fj] = __builtin_amdgcn_mfma_f32_16x16x32_bf16(af[fo], bq[fj], acc[fo][fj], 0, 0, 0);
  }
  __syncthreads();

  const ushort* w2g = wpad + 17408;
  short8v a2[4], a2n[4];
  #pragma unroll
  for (int fo = 0; fo < 4; ++fo)
    a2[fo] = *reinterpret_cast<const short8v*>(w2g + (size_t)(wc*64 + fo*16 + lj)*136 + lg*8);

  #pragma unroll
  for (int fo = 0; fo < 4; ++fo) {
    int ch0 = wc*64 + fo*16 + lg*4;
    float c0 = b1[ch0], c1 = b1[ch0+1], c2 = b1[ch0+2], c3 = b1[ch0+3];
    #pragma unroll
    for (int fj = 0; fj < 2; ++fj) {
      int px = wp*32 + fj*16 + lj;
      f32x4 a = acc[fo][fj];
      uint2 u;
      u.x = (uint)bf16rne(geluf(a.x + c0)) | ((uint)bf16rne(geluf(a.y + c1)) << 16);
      u.y = (uint)bf16rne(geluf(a.z + c2)) | ((uint)bf16rne(geluf(a.w + c3)) << 16);
      *reinterpret_cast<uint2*>(&wl[px*136 + ch0]) = u;
    }
  }
  __syncthreads();

  #pragma unroll
  for (int fo = 0; fo < 4; ++fo)
    #pragma unroll
    for (int fj = 0; fj < 2; ++fj)
      acc[fo][fj] = (f32x4){0.f,0.f,0.f,0.f};

  #pragma unroll
  for (int kc = 0; kc < 4; ++kc) {
    if (kc < 3) {
      #pragma unroll
      for (int fo = 0; fo < 4; ++fo)
        a2n[fo] = *reinterpret_cast<const short8v*>(w2g + (size_t)(wc*64 + fo*16 + lj)*136 + (kc+1)*32 + lg*8);
    }
    short8v bq[2];
    #pragma unroll
    for (int fj = 0; fj < 2; ++fj)
      bq[fj] = *reinterpret_cast<const short8v*>(&wl[(wp*32 + fj*16 + lj)*136 + kc*32 + lg*8]);
    #pragma unroll
    for (int fo = 0; fo < 4; ++fo)
      #pragma unroll
      for (int fj = 0; fj < 2; ++fj)
        acc[fo][fj] = __builtin_amdgcn_mfma_f32_16x16x32_bf16(a2[fo], bq[fj], acc[fo][fj], 0, 0, 0);
    #pragma unroll
    for (int fo = 0; fo < 4; ++fo) a2[fo] = a2n[fo];
  }

  #pragma unroll
  for (int fo = 0; fo < 4; ++fo) {
    int ch0 = wc*64 + fo*16 + lg*4;
    float d0 = b2[ch0], d1 = b2[ch0+1], d2 = b2[ch0+2], d3 = b2[ch0+3];
    #pragma unroll
    for (int fj = 0; fj < 2; ++fj) {
      int px = wp*32 + fj*16 + lj;
      f32x4 a = acc[fo][fj];
      uint2 cu = *reinterpret_cast<const uint2*>(&cT[px*136 + ch0]);
      float cv0 = __uint_as_float((cu.x & 0xffffu) << 16);
      float cv1 = __uint_as_float(cu.x & 0xffff0000u);
      float cv2 = __uint_as_float((cu.y & 0xffffu) << 16);
      float cv3 = __uint_as_float(cu.y & 0xffff0000u);
      float* p0 = io + (size_t)bb*128*HW2 + (size_t)ch0*HW2 + hw0 + px;
      p0[0]             = cv0 + a.x + d0;
      p0[HW2]           = cv1 + a.y + d1;
      p0[2*HW2]         = cv2 + a.z + d2;
      p0[3*(size_t)HW2] = cv3 + a.w + d3;
    }
  }
}

extern "C" void kernel_launch(void* const* d_in, const int* in_sizes, int n_in,
                              void* d_out, int out_size, void* d_ws, size_t ws_size,
                              hipStream_t stream) {
  const float* x          = (const float*)d_in[0];
  const float* patch_w    = (const float*)d_in[1];
  const float* patch_b    = (const float*)d_in[2];
  const float* in_proj_w  = (const float*)d_in[3];
  const float* conv1d_w   = (const float*)d_in[4];
  const float* conv1d_b   = (const float*)d_in[5];
  const float* x_proj_w   = (const float*)d_in[6];
  const float* dt_proj_w  = (const float*)d_in[7];
  const float* dt_proj_b  = (const float*)d_in[8];
  const float* A_log      = (const float*)d_in[9];
  const float* D_param    = (const float*)d_in[10];
  const float* out_proj_w = (const float*)d_in[11];
  const float* lin_w      = (const float*)d_in[12];
  const float* lin_b      = (const float*)d_in[13];
  const float* conv_w     = (const float*)d_in[14];
  const float* conv_b     = (const float*)d_in[15];
  const float* ffn_w1     = (const float*)d_in[16];
  const float* ffn_b1     = (const float*)d_in[17];
  const float* ffn_w2     = (const float*)d_in[18];
  const float* ffn_b2     = (const float*)d_in[19];
  float* out = (float*)d_out;
  float* ws  = (float*)d_ws;

  float* t    = ws;                 // 524288   (B*N, E)
  float* xz   = t    + 524288;      // 2097152  (B*N, 512)
  float* xc   = xz   + 2097152;     // 1048576  (B*N, 256)
  float* dbl  = xc   + 1048576;     // 163840   (B*N, 40)
  float* dt   = dbl  + 163840;      // 1048576  (B*N, 256)
  float* y    = dt   + 1048576;     // 1048576  (B*N, 256)
  float* yo   = y    + 1048576;     // 524288   (B*N, 128)
  float* apr  = yo   + 524288;      // 524288
  float* hend = apr  + 524288;      // 524288
  float* hst  = hend + 524288;      // 524288
  ushort* ubf  = (ushort*)(hst + 524288); // 10982400 bf16: [8][4][66][130][32]
  ushort* wbf  = ubf + 10982400;          // 589824 bf16 frag-linear conv weights
  ushort* wpad = wbf + 589824;            // 34816 bf16:    [2][128][136]
  ushort* lwbf = wpad + 34816;            // 4194304 bf16:  [8192][512]
  ushort* ybfT = lwbf + 4194304;          // 524288 bf16:   [8][128][512]
  float* part = xz;                       // 4194304 floats scratch (xz..dt region), consumed before xz written

  k_zero4 <<<dim3(5363), dim3(256), 0, stream>>>((uint4*)ubf, 1372800);
  k_wprep <<<dim3(2304), dim3(256), 0, stream>>>(conv_w, wbf);
  k_wffn  <<<dim3(136), dim3(256), 0, stream>>>(ffn_w1, ffn_w2, wpad);
  k_wlin  <<<dim3(4096), dim3(256), 0, stream>>>(lin_w, lwbf);
  k_patchm<<<dim3(32, 8), dim3(256), 0, stream>>>(x, patch_w, part);
  k_tred  <<<dim3(512), dim3(256), 0, stream>>>(part, patch_b, t);
  k_gemm  <<<dim3(64, 8), dim3(256), 0, stream>>>(t, in_proj_w, xz, 4096, 512, 128);
  k_conv1d<<<dim3(4096), dim3(256), 0, stream>>>(xz, conv1d_w, conv1d_b, xc);
  k_xproj <<<dim3(4096), dim3(256), 0, stream>>>(xc, x_proj_w, dt_proj_w, dt_proj_b, dbl, dt);
  k_scanA <<<dim3(128, 16), dim3(256), 0, stream>>>(dt, dbl, xc, A_log, apr, hend);
  k_scanB <<<dim3(128), dim3(256), 0, stream>>>(apr, hend, hst);
  k_scanC <<<dim3(128, 16), dim3(256), 0, stream>>>(dt, dbl, xc, xz, A_log, D_param, hst, y);
  k_gemm  <<<dim3(64, 2), dim3(256), 0, stream>>>(y, out_proj_w, yo, 4096, 128, 256);
  k_ytr   <<<dim3(8, 16), dim3(256), 0, stream>>>(yo, ybfT);
  k_linm  <<<dim3(64, 8), dim3(512), 0, stream>>>(ybfT, lwbf, lin_b, ubf);
  k_conv3m<<<dim3(32, 64), dim3(256), 0, stream>>>(ubf, wbf, conv_b, out);
  k_ffnm  <<<dim3(2048), dim3(512), (size_t)(2*128*136)*sizeof(ushort), stream>>>(wpad, ffn_b1, ffn_b2, out);
}